// Round 9
// baseline (694.269 us; speedup 1.0000x reference)
//
#include <hip/hip_runtime.h>
#include <math.h>

#define HWSZ 16384
#define WID 128
#define HEI 128
#define CCH 192
#define BB 4

typedef short v8s __attribute__((ext_vector_type(8)));
typedef float f32x4 __attribute__((ext_vector_type(4)));

__device__ __constant__ float c_lo[6] = {0.035226291882100656f, -0.08544127388224149f, -0.13501102001039084f,
                                         0.4598775021193313f, 0.8068915093133388f, 0.3326705529509569f};
__device__ __constant__ float c_hi[6] = {-0.3326705529509569f, 0.8068915093133388f, -0.4598775021193313f,
                                         -0.13501102001039084f, 0.08544127388224149f, 0.035226291882100656f};

__device__ __forceinline__ float b2f(unsigned short h) { return __uint_as_float(((unsigned int)h) << 16); }
__device__ __forceinline__ unsigned short f2b(float f) {
    unsigned int u = __float_as_uint(f);
    return (unsigned short)((u + 0x7fffu + ((u >> 16) & 1u)) >> 16);
}
__device__ __forceinline__ unsigned int pk2(float a, float b) {
    return (unsigned int)f2b(a) | ((unsigned int)f2b(b) << 16);
}

// ---------------- weight fp32 -> bf16 with row/col zero-pad ----------------
__global__ __launch_bounds__(256) void k_wconv(const float* __restrict__ src,
    unsigned short* __restrict__ dst, int rows, int cols, int dcols, int total)
{
    int i = blockIdx.x * 256 + threadIdx.x;
    if (i >= total) return;
    int r = i / dcols, c = i - r * dcols;
    float v = (c < cols && r < rows) ? src[r * cols + c] : 0.f;
    dst[i] = f2b(v);
}

// ---------------- LayerNorm over channel dim ----------------
template<int WRITE_SP>
__global__ __launch_bounds__(256) void k_ln(const float* __restrict__ x,
    const float* __restrict__ g, const float* __restrict__ bta,
    unsigned short* __restrict__ xsp, unsigned short* __restrict__ xT)
{
    int pg = blockIdx.x * 256 + threadIdx.x;
    int b = pg >> 14, p = pg & 16383;
    const float* xp = x + (size_t)b * CCH * HWSZ + p;
    float s = 0.f, s2 = 0.f;
    for (int c = 0; c < CCH; ++c) {
        float v = xp[(size_t)c * HWSZ];
        s += v; s2 += v * v;
    }
    float mu = s * (1.f / CCH);
    float var = s2 * (1.f / CCH) - mu * mu;
    float rs = rsqrtf(var + 1e-5f);
    unsigned short* tr = xT + ((size_t)b * HWSZ + p) * CCH;
    unsigned short* sp = xsp + (size_t)b * CCH * HWSZ + p;
    for (int c0 = 0; c0 < CCH; c0 += 8) {
        float vv[8];
#pragma unroll
        for (int i = 0; i < 8; ++i) {
            float v = xp[(size_t)(c0 + i) * HWSZ];
            v = (v - mu) * rs * g[c0 + i] + bta[c0 + i];
            vv[i] = v;
            if (WRITE_SP) sp[(size_t)(c0 + i) * HWSZ] = f2b(v);
        }
        uint4 u;
        u.x = pk2(vv[0], vv[1]); u.y = pk2(vv[2], vv[3]);
        u.z = pk2(vv[4], vv[5]); u.w = pk2(vv[6], vv[7]);
        *(uint4*)(tr + c0) = u;
    }
}

// ---------------- streaming GEMM: wave = 32px x 64co, grid (HW/128, M/64, B) ----------------
template<int OUT_BF16, int ADD, int K, int LDW>
__global__ __launch_bounds__(256) void k_gemmS(
    const unsigned short* __restrict__ X, const unsigned short* __restrict__ W,
    void* __restrict__ outp, const float* __restrict__ addsrc,
    int Mtot, int wstrideB)
{
    __shared__ float lds[4][64 * 33];
    int lane = threadIdx.x & 63, wv = threadIdx.x >> 6;
    int b = blockIdx.z;
    int r = lane & 15, koct = lane >> 4;
    int pxb = blockIdx.x * 128 + wv * 32;
    int co0 = blockIdx.y * 64;
    const unsigned short* xb = X + ((size_t)b * HWSZ + pxb + r) * K + koct * 8;
    const unsigned short* wb = W + (size_t)b * wstrideB + (size_t)(co0 + r) * LDW + koct * 8;
    f32x4 z = {0.f, 0.f, 0.f, 0.f};
    f32x4 acc[4][2];
#pragma unroll
    for (int i = 0; i < 4; ++i) { acc[i][0] = z; acc[i][1] = z; }

#pragma unroll 4
    for (int ks = 0; ks < K / 32; ++ks) {
        v8s b0 = *(const v8s*)(xb + ks * 32);
        v8s b1 = *(const v8s*)(xb + 16 * K + ks * 32);
        v8s a0 = *(const v8s*)(wb + ks * 32);
        v8s a1 = *(const v8s*)(wb + 16 * LDW + ks * 32);
        v8s a2 = *(const v8s*)(wb + 32 * LDW + ks * 32);
        v8s a3 = *(const v8s*)(wb + 48 * LDW + ks * 32);
        acc[0][0] = __builtin_amdgcn_mfma_f32_16x16x32_bf16(a0, b0, acc[0][0], 0, 0, 0);
        acc[0][1] = __builtin_amdgcn_mfma_f32_16x16x32_bf16(a0, b1, acc[0][1], 0, 0, 0);
        acc[1][0] = __builtin_amdgcn_mfma_f32_16x16x32_bf16(a1, b0, acc[1][0], 0, 0, 0);
        acc[1][1] = __builtin_amdgcn_mfma_f32_16x16x32_bf16(a1, b1, acc[1][1], 0, 0, 0);
        acc[2][0] = __builtin_amdgcn_mfma_f32_16x16x32_bf16(a2, b0, acc[2][0], 0, 0, 0);
        acc[2][1] = __builtin_amdgcn_mfma_f32_16x16x32_bf16(a2, b1, acc[2][1], 0, 0, 0);
        acc[3][0] = __builtin_amdgcn_mfma_f32_16x16x32_bf16(a3, b0, acc[3][0], 0, 0, 0);
        acc[3][1] = __builtin_amdgcn_mfma_f32_16x16x32_bf16(a3, b1, acc[3][1], 0, 0, 0);
    }

    // epilogue: acc -> per-wave LDS [64co][33] -> 8co x 32px vectorized stores
    float* lw = lds[wv];
#pragma unroll
    for (int i = 0; i < 4; ++i)
#pragma unroll
        for (int j = 0; j < 2; ++j)
#pragma unroll
            for (int jj = 0; jj < 4; ++jj)
                lw[(i * 16 + koct * 4 + jj) * 33 + j * 16 + r] = acc[i][j][jj];
    __syncthreads();
    int cl = lane >> 3, p4 = (lane & 7) * 4;
    size_t obase = ((size_t)b * Mtot + co0) * HWSZ + pxb;
#pragma unroll
    for (int cg = 0; cg < 8; ++cg) {
        int co_l = cg * 8 + cl;
        const float* lrow = lw + co_l * 33 + p4;
        float v0 = lrow[0], v1 = lrow[1], v2 = lrow[2], v3 = lrow[3];
        size_t oi = obase + (size_t)co_l * HWSZ + p4;
        if (ADD) {
            float4 a = *(const float4*)(addsrc + oi);
            v0 += a.x; v1 += a.y; v2 += a.z; v3 += a.w;
        }
        if (OUT_BF16) {
            uint2 u;
            u.x = pk2(v0, v1); u.y = pk2(v2, v3);
            *(uint2*)((unsigned short*)outp + oi) = u;
        } else {
            float4 f = {v0, v1, v2, v3};
            *(float4*)((float*)outp + oi) = f;
        }
    }
}

// ---------------- depthwise helpers ----------------
__device__ __forceinline__ void dw_load_tile(const unsigned short* __restrict__ ip,
    int r0, float (&tile)[18][132], int tid)
{
    for (int e = tid; e < 576; e += 256) {
        int r = e >> 5, q4 = e & 31;
        int gr = r0 - 1 + r;
        float v0 = 0.f, v1 = 0.f, v2 = 0.f, v3 = 0.f;
        if (gr >= 0 && gr < HEI) {
            uint2 u = *(const uint2*)(ip + gr * WID + q4 * 4);
            const unsigned short* pu = (const unsigned short*)&u;
            v0 = b2f(pu[0]); v1 = b2f(pu[1]); v2 = b2f(pu[2]); v3 = b2f(pu[3]);
        }
        int cb = 1 + q4 * 4;
        tile[r][cb] = v0; tile[r][cb + 1] = v1; tile[r][cb + 2] = v2; tile[r][cb + 3] = v3;
    }
    if (tid < 18) { tile[tid][0] = 0.f; tile[tid][129] = 0.f; }
}

__device__ __forceinline__ void dw_compute8(const float (&tile)[18][132],
    const float* wr, int rl, int px0, float (&o)[8])
{
    float r0[10], r1[10], r2[10];
#pragma unroll
    for (int i = 0; i < 10; ++i) {
        r0[i] = tile[rl][px0 + i];
        r1[i] = tile[rl + 1][px0 + i];
        r2[i] = tile[rl + 2][px0 + i];
    }
#pragma unroll
    for (int j = 0; j < 8; ++j) {
        o[j] = r0[j] * wr[0] + r0[j + 1] * wr[1] + r0[j + 2] * wr[2]
             + r1[j] * wr[3] + r1[j + 1] * wr[4] + r1[j + 2] * wr[5]
             + r2[j] * wr[6] + r2[j + 1] * wr[7] + r2[j + 2] * wr[8];
    }
}

// ---------------- depthwise 3x3 bf16; opt k^2 reduce ----------------
template<int REDUCE>
__global__ __launch_bounds__(256) void k_dw8(const unsigned short* __restrict__ in,
    const float* __restrict__ w, unsigned short* __restrict__ out, float* __restrict__ red,
    int inCtot, int inCoff, int outCtot, int outCoff)
{
    __shared__ float tile[18][132];
    int g = blockIdx.x, c = blockIdx.y, b = blockIdx.z;
    int tid = threadIdx.x;
    const unsigned short* ip = in + (size_t)(b * inCtot + inCoff + c) * HWSZ;
    dw_load_tile(ip, g * 16, tile, tid);
    float wr[9];
#pragma unroll
    for (int j = 0; j < 9; ++j) wr[j] = w[c * 9 + j];
    __syncthreads();
    int rl = tid >> 4, px0 = (tid & 15) * 8;
    float o[8];
    dw_compute8(tile, wr, rl, px0, o);
    unsigned short* op = out + (size_t)(b * outCtot + outCoff + c) * HWSZ + (g * 16 + rl) * WID + px0;
    uint4 u;
    u.x = pk2(o[0], o[1]); u.y = pk2(o[2], o[3]); u.z = pk2(o[4], o[5]); u.w = pk2(o[6], o[7]);
    *(uint4*)op = u;
    if (REDUCE) {
        float s = 0.f;
#pragma unroll
        for (int j = 0; j < 8; ++j) s += o[j] * o[j];
        for (int off = 32; off; off >>= 1) s += __shfl_down(s, off, 64);
        __shared__ float w4[4];
        if ((tid & 63) == 0) w4[tid >> 6] = s;
        __syncthreads();
        if (tid == 0) atomicAdd(red + b * CCH + c, w4[0] + w4[1] + w4[2] + w4[3]);
    }
}

// ---------------- fused FFN: dw3x3(y1), dw3x3(y2), gelu(a)*b ----------------
__global__ __launch_bounds__(256) void k_dw8gate(const unsigned short* __restrict__ y12,
    const float* __restrict__ w1, const float* __restrict__ w2,
    unsigned short* __restrict__ out, int validc)
{
    __shared__ float t1[18][132];
    __shared__ float t2[18][132];
    int g = blockIdx.x, c = blockIdx.y, b = blockIdx.z;
    int tid = threadIdx.x;
    const unsigned short* i1 = y12 + (size_t)(b * 512 + c) * HWSZ;
    const unsigned short* i2 = y12 + (size_t)(b * 512 + 256 + c) * HWSZ;
    dw_load_tile(i1, g * 16, t1, tid);
    dw_load_tile(i2, g * 16, t2, tid);
    bool vc = (c < validc);
    float wr1[9], wr2[9];
#pragma unroll
    for (int j = 0; j < 9; ++j) {
        wr1[j] = vc ? w1[c * 9 + j] : 0.f;
        wr2[j] = vc ? w2[c * 9 + j] : 0.f;
    }
    __syncthreads();
    int rl = tid >> 4, px0 = (tid & 15) * 8;
    float a[8], bg[8];
    dw_compute8(t1, wr1, rl, px0, a);
    dw_compute8(t2, wr2, rl, px0, bg);
    float o[8];
#pragma unroll
    for (int j = 0; j < 8; ++j)
        o[j] = 0.5f * a[j] * (1.f + erff(a[j] * 0.70710678118654752f)) * bg[j];
    unsigned short* op = out + (size_t)(b * 256 + c) * HWSZ + (g * 16 + rl) * WID + px0;
    uint4 u;
    u.x = pk2(o[0], o[1]); u.y = pk2(o[2], o[3]); u.z = pk2(o[4], o[5]); u.w = pk2(o[6], o[7]);
    *(uint4*)op = u;
}

// ---------------- transpose [b][*][HW] -> [b][px][ldo] bf16, XOR swizzle ----------------
template<int CT>
__global__ __launch_bounds__(256) void k_transT(const unsigned short* __restrict__ in,
    unsigned short* __restrict__ outT, int inCtot, int inCoff, int ldo, int coff)
{
    __shared__ unsigned short lt[64 * CT];
    const int NG = CT / 8;
    int px0 = blockIdx.x * 64, b = blockIdx.z;
    for (int idx = threadIdx.x; idx < 8 * CT; idx += 256) {
        int ch = idx >> 3, chunk = idx & 7;
        uint4 u = *(const uint4*)(in + ((size_t)(b * inCtot + inCoff + ch)) * HWSZ + px0 + chunk * 8);
        const unsigned short* pu = (const unsigned short*)&u;
        int gq = ch >> 3, j = ch & 7;
#pragma unroll
        for (int i = 0; i < 8; ++i) {
            int row = chunk * 8 + i;
            int gs = gq ^ (row >> 3);
            lt[row * CT + gs * 8 + j] = pu[i];
        }
    }
    __syncthreads();
    for (int idx = threadIdx.x; idx < 8 * CT; idx += 256) {
        int px = idx / NG, cc = idx - px * NG;
        int gs = cc ^ (px >> 3);
        uint4 v = *(const uint4*)&lt[px * CT + gs * 8];
        *(uint4*)(outT + ((size_t)b * HWSZ + px0 + px) * ldo + coff + cc * 8) = v;
    }
}

// ---------------- DWT row pass (bf16 in/out, 72-padded rows) ----------------
__global__ __launch_bounds__(256) void k_dwt_row(const unsigned short* __restrict__ xnb,
    unsigned short* __restrict__ rowbuf)
{
    int bc = blockIdx.x;
    const unsigned short* ip = xnb + (size_t)bc * HWSZ;
    unsigned short* lo = rowbuf + (size_t)bc * 9216;
    unsigned short* hi = rowbuf + (size_t)(768 + bc) * 9216;
    for (int idx = threadIdx.x; idx < 128 * 66; idx += 256) {
        int row = idx / 66, ow = idx - row * 66;
        const unsigned short* rp = ip + row * 128;
        int base = 2 * ow - 4;
        float v[6];
#pragma unroll
        for (int j = 0; j < 6; ++j) {
            int iw = base + j;
            v[j] = (iw >= 0 && iw < 128) ? b2f(rp[iw]) : 0.f;
        }
        float lv = 0.f, hv = 0.f;
#pragma unroll
        for (int j = 0; j < 6; ++j) {
            lv += v[j] * c_lo[5 - j];
            hv += v[j] * c_hi[5 - j];
        }
        lo[row * 72 + ow] = f2b(lv); hi[row * 72 + ow] = f2b(hv);
    }
}

// ---------------- DWT col pass + band 3x3 dwconv ----------------
__global__ __launch_bounds__(256) void k_dwt_colconv(const unsigned short* __restrict__ rowbuf,
    const float* __restrict__ w5, const float* __restrict__ w7, const float* __restrict__ w9,
    unsigned short* __restrict__ bfilt)
{
    __shared__ unsigned short rb[136][72];
    __shared__ float bnd[68][68];
    int h = blockIdx.x, c = blockIdx.y, b = blockIdx.z;
    int tid = threadIdx.x;
    int bc = b * CCH + c;
    const unsigned short* src = rowbuf + (size_t)(h * 768 + bc) * 9216;
    for (int e = tid; e < 1224; e += 256) {
        int r = e / 9, qd = e - r * 9;
        int gr = r - 4;
        uint4 u = make_uint4(0, 0, 0, 0);
        if (gr >= 0 && gr < 128) u = *(const uint4*)(src + gr * 72 + qd * 8);
        *(uint4*)&rb[r][qd * 8] = u;
    }
    for (int e = tid; e < 268; e += 256) {
        int rr, cc;
        if (e < 68) { rr = 0; cc = e; }
        else if (e < 136) { rr = 67; cc = e - 68; }
        else if (e < 202) { rr = e - 135; cc = 0; }
        else { rr = e - 201; cc = 67; }
        bnd[rr][cc] = 0.f;
    }
    __syncthreads();
    for (int fs = 0; fs < 2; ++fs) {
        int band = fs * 2 + h;
        const float* fa = fs ? c_hi : c_lo;
        float f5[6];
#pragma unroll
        for (int j = 0; j < 6; ++j) f5[j] = fa[5 - j];
        for (int i = tid; i < 4356; i += 256) {
            int oh = i / 66, ow = i - oh * 66;
            float a = 0.f;
#pragma unroll
            for (int ki = 0; ki < 6; ++ki)
                a += f5[ki] * b2f(rb[oh * 2 + ki][ow]);
            bnd[oh + 1][ow + 1] = a;
        }
        __syncthreads();
        const float* wsel = (band < 2) ? w5 : (band == 2 ? w7 : w9);
        float wr[9];
#pragma unroll
        for (int j = 0; j < 9; ++j) wr[j] = wsel[c * 9 + j];
        unsigned short* op = bfilt + ((size_t)bc * 4 + band) * 4356;
        for (int i = tid; i < 2178; i += 256) {
            int oh = i / 33, p2 = i - oh * 33;
            int ow0 = p2 * 2;
            float t[3][4];
#pragma unroll
            for (int dy = 0; dy < 3; ++dy)
#pragma unroll
                for (int dx = 0; dx < 4; ++dx)
                    t[dy][dx] = bnd[oh + dy][ow0 + dx];
            float o0 = t[0][0] * wr[0] + t[0][1] * wr[1] + t[0][2] * wr[2]
                     + t[1][0] * wr[3] + t[1][1] * wr[4] + t[1][2] * wr[5]
                     + t[2][0] * wr[6] + t[2][1] * wr[7] + t[2][2] * wr[8];
            float o1 = t[0][1] * wr[0] + t[0][2] * wr[1] + t[0][3] * wr[2]
                     + t[1][1] * wr[3] + t[1][2] * wr[4] + t[1][3] * wr[5]
                     + t[2][1] * wr[6] + t[2][2] * wr[7] + t[2][3] * wr[8];
            *(unsigned int*)(op + oh * 66 + ow0) = pk2(o0, o1);
        }
        __syncthreads();
    }
}

// ---------------- fused IDWT over 4 bands + q^2 reduce ----------------
__global__ __launch_bounds__(256) void k_idwt2(const unsigned short* __restrict__ bfilt,
    unsigned short* __restrict__ q, float* __restrict__ rq2)
{
    __shared__ float L[4][10][68];
    __shared__ float w4[4];
    int g = blockIdx.x;
    int c = blockIdx.y, b = blockIdx.z;
    int tid = threadIdx.x;
    int bc = b * CCH + c;
    const unsigned short* bp = bfilt + (size_t)bc * 4 * 4356;
    for (int e = tid; e < 1320; e += 256) {
        int idx = e * 2;
        int band = idx / 660, rem = idx - band * 660;
        int rr = rem / 66, cc = rem - rr * 66;
        unsigned int u = *(const unsigned int*)(bp + band * 4356 + (8 * g + rr) * 66 + cc);
        L[band][rr][cc] = b2f((unsigned short)(u & 0xffffu));
        L[band][rr][cc + 1] = b2f((unsigned short)(u >> 16));
    }
    __syncthreads();
    int rl = tid >> 4, px0 = (tid & 15) * 8;
    int oh = 16 * g + rl;
    int Tl = rl >> 1, pr = rl & 1;
    int mb = px0 >> 1;
    float acc[8];
#pragma unroll
    for (int j = 0; j < 8; ++j) acc[j] = 0.f;
#pragma unroll
    for (int band = 0; band < 4; ++band) {
        const float* fv = (band < 2) ? c_lo : c_hi;
        const float* fh = (band & 1) ? c_hi : c_lo;
        float fv3[3] = {fv[1 - pr], fv[3 - pr], fv[5 - pr]};
        float fhe[3] = {fh[1], fh[3], fh[5]};
        float fho[3] = {fh[0], fh[2], fh[4]};
#pragma unroll
        for (int i = 0; i < 3; ++i) {
            float r6[6];
#pragma unroll
            for (int m = 0; m < 6; ++m) r6[m] = L[band][Tl + i][mb + m];
#pragma unroll
            for (int jj = 0; jj < 4; ++jj) {
                float se = fhe[0] * r6[jj] + fhe[1] * r6[jj + 1] + fhe[2] * r6[jj + 2];
                float so = fho[0] * r6[jj] + fho[1] * r6[jj + 1] + fho[2] * r6[jj + 2];
                acc[2 * jj]     += fv3[i] * se;
                acc[2 * jj + 1] += fv3[i] * so;
            }
        }
    }
    unsigned short* op = q + (size_t)bc * HWSZ + oh * WID + px0;
    uint4 u;
    u.x = pk2(acc[0], acc[1]); u.y = pk2(acc[2], acc[3]);
    u.z = pk2(acc[4], acc[5]); u.w = pk2(acc[6], acc[7]);
    *(uint4*)op = u;
    float s = 0.f;
#pragma unroll
    for (int j = 0; j < 8; ++j) s += acc[j] * acc[j];
    for (int off = 32; off; off >>= 1) s += __shfl_down(s, off, 64);
    if ((tid & 63) == 0) w4[tid >> 6] = s;
    __syncthreads();
    if (tid == 0) atomicAdd(rq2 + bc, w4[0] + w4[1] + w4[2] + w4[3]);
}

// ---------------- finalize norms ----------------
__global__ __launch_bounds__(256) void k_fnorm(const float* __restrict__ rq2,
    const float* __restrict__ rk2, float* __restrict__ rq, float* __restrict__ rk)
{
    int i = blockIdx.x * 256 + threadIdx.x;
    if (i < 768) rq[i] = 1.f / fmaxf(sqrtf(rq2[i]), 1e-12f);
    else if (i < 1536) rk[i - 768] = 1.f / fmaxf(sqrtf(rk2[i - 768]), 1e-12f);
}

// ---------------- QK^T via MFMA ----------------
__global__ __launch_bounds__(256) void k_qk_mfma(const unsigned short* __restrict__ q,
    const unsigned short* __restrict__ kv, float* __restrict__ pS)
{
    __shared__ float red[4][2304];
    int slice = blockIdx.x, bh = blockIdx.y;
    int b = bh >> 2, h = bh & 3;
    int wv = threadIdx.x >> 6, lane = threadIdx.x & 63;
    int r = lane & 15, koct = lane >> 4;
    const unsigned short* qb = q + (size_t)(b * CCH + h * 48) * HWSZ;
    const unsigned short* kb = kv + (size_t)(b * 384 + h * 48) * HWSZ;
    int n0 = slice * 1024 + wv * 256 + koct * 8;
    f32x4 z = {0.f, 0.f, 0.f, 0.f};
    f32x4 acc[3][3];
#pragma unroll
    for (int i = 0; i < 3; ++i)
#pragma unroll
        for (int j = 0; j < 3; ++j) acc[i][j] = z;
#pragma unroll
    for (int step = 0; step < 8; ++step) {
        int n = n0 + step * 32;
        v8s qf[3], kf[3];
#pragma unroll
        for (int i = 0; i < 3; ++i) {
            qf[i] = *(const v8s*)(qb + (size_t)(16 * i + r) * HWSZ + n);
            kf[i] = *(const v8s*)(kb + (size_t)(16 * i + r) * HWSZ + n);
        }
#pragma unroll
        for (int i = 0; i < 3; ++i)
#pragma unroll
            for (int j = 0; j < 3; ++j)
                acc[i][j] = __builtin_amdgcn_mfma_f32_16x16x32_bf16(qf[i], kf[j], acc[i][j], 0, 0, 0);
    }
#pragma unroll
    for (int i = 0; i < 3; ++i)
#pragma unroll
        for (int j = 0; j < 3; ++j)
#pragma unroll
            for (int jj = 0; jj < 4; ++jj)
                red[wv][(16 * i + koct * 4 + jj) * 48 + 16 * j + r] = acc[i][j][jj];
    __syncthreads();
    float* ps = pS + (size_t)(slice * 16 + bh) * 2304;
    for (int e = threadIdx.x; e < 2304; e += 256)
        ps[e] = red[0][e] + red[1][e] + red[2][e] + red[3][e];
}

// ---------------- reduce partials, scale, softmax ----------------
__global__ __launch_bounds__(256) void k_attn_soft(const float* __restrict__ pS,
    const float* __restrict__ rq, const float* __restrict__ rk,
    const float* __restrict__ temp, float* __restrict__ attnw)
{
    int bh = blockIdx.x; int b = bh >> 2, h = bh & 3;
    __shared__ float S[48][49];
    int tid = threadIdx.x, dt = tid >> 4, et = tid & 15;
    float tv = temp[h];
#pragma unroll
    for (int i = 0; i < 3; ++i) {
#pragma unroll
        for (int j = 0; j < 3; ++j) {
            int d = dt + 16 * i, e = et + 16 * j;
            float s = 0.f;
            for (int sl = 0; sl < 16; ++sl)
                s += pS[(size_t)(sl * 16 + bh) * 2304 + d * 48 + e];
            S[d][e] = s * tv * rq[b * CCH + h * 48 + d] * rk[b * CCH + h * 48 + e];
        }
    }
    __syncthreads();
    if (tid < 48) {
        float mx = -1e30f;
        for (int e = 0; e < 48; ++e) mx = fmaxf(mx, S[tid][e]);
        float sum = 0.f;
        for (int e = 0; e < 48; ++e) sum += expf(S[tid][e] - mx);
        float inv = 1.f / sum;
        for (int e = 0; e < 48; ++e)
            attnw[((size_t)bh * 48 + tid) * 48 + e] = expf(S[tid][e] - mx) * inv;
    }
}

// ---------------- fuse Wattn @ blockdiag(attn) ----------------
__global__ __launch_bounds__(192) void k_wfuse(const float* __restrict__ wattn,
    const float* __restrict__ attnw, unsigned short* __restrict__ wf)
{
    int co = blockIdx.x, b = blockIdx.y;
    int ce = threadIdx.x;
    int h = ce / 48, e = ce - h * 48;
    const float* wrow = wattn + (size_t)co * 192 + h * 48;
    const float* arow = attnw + ((size_t)(b * 4 + h) * 48) * 48 + e;
    float acc = 0.f;
#pragma unroll 8
    for (int d = 0; d < 48; ++d)
        acc += wrow[d] * arow[(size_t)d * 48];
    wf[((size_t)b * 192 + co) * 192 + ce] = f2b(acc);
}

// ---------------- launcher ----------------
extern "C" void kernel_launch(void* const* d_in, const int* in_sizes, int n_in,
                              void* d_out, int out_size, void* d_ws, size_t ws_size,
                              hipStream_t stream)
{
    const float* x     = (const float*)d_in[0];
    const float* ln1g  = (const float*)d_in[1];
    const float* ln1b  = (const float*)d_in[2];
    const float* ln2g  = (const float*)d_in[3];
    const float* ln2b  = (const float*)d_in[4];
    const float* temp  = (const float*)d_in[5];
    const float* wqkv  = (const float*)d_in[6];
    const float* wqkvd = (const float*)d_in[7];
    const float* w5    = (const float*)d_in[8];
    const float* w7    = (const float*)d_in[9];
    const float* w9    = (const float*)d_in[10];
    const float* wattn = (const float*)d_in[11];
    const float* wffni = (const float*)d_in[12];
    const float* wffnd = (const float*)d_in[13];
    const float* wffno = (const float*)d_in[14];
    float* out = (float*)d_out;

    char* ws = (char*)d_ws;
    unsigned short* xnT = (unsigned short*)(ws + 0);              // 25.2MB (later xn2T)
    unsigned short* xnb = (unsigned short*)(ws + 25165824);       // 25.2MB (later vT/y12)
    unsigned short* q = (unsigned short*)(ws + 75497472);         // 25.2MB
    unsigned short* kvb = (unsigned short*)(ws + 100663296);      // 50.3MB
    unsigned short* bfilt = (unsigned short*)(ws + 100663296);    // bf16 (dead before kvb)
    unsigned short* rowbuf = (unsigned short*)(ws + 154189824);   // 27MB bf16, 72-padded
    unsigned short* kvtmp384 = (unsigned short*)(ws + 154189824); // 50.3MB (rowbuf dead)
    const size_t SM = 226492416;
    float* rq2   = (float*)(ws + SM);
    float* rk2   = (float*)(ws + SM + 4096);
    float* rq    = (float*)(ws + SM + 8192);
    float* rk    = (float*)(ws + SM + 12288);
    float* pS    = (float*)(ws + SM + 16384);                     // aliased by attnw
    float* attnw = pS;
    unsigned short* wq_b  = (unsigned short*)(ws + SM + 2375680);
    unsigned short* wfi_b = (unsigned short*)(ws + SM + 2523136); // [y1ck0|y2ck0|y1ck1|y2ck1]
    unsigned short* wfo_b = (unsigned short*)(ws + SM + 2916352);
    unsigned short* wf_b  = (unsigned short*)(ws + SM + 3112960);
    const size_t NEED = SM + 3407872;
    if (ws_size < NEED) return;

    unsigned short* vT   = xnb;
    unsigned short* y12  = (unsigned short*)(ws + 25165824);
    unsigned short* gg   = (unsigned short*)(ws + 92274688);
    unsigned short* gTb  = (unsigned short*)(ws + 125829120);     // [b][px][512]

    dim3 blk(256);

    // 0. weights -> bf16; zero norm accumulators
    hipMemsetAsync(ws + SM, 0, 8192, stream);
    k_wconv<<<288, blk, 0, stream>>>(wqkv, wq_b, 384, 192, 192, 73728);
    k_wconv<<<192, blk, 0, stream>>>(wffni, wfi_b, 256, 192, 192, 49152);
    k_wconv<<<192, blk, 0, stream>>>(wffni + (size_t)510 * 192, wfi_b + 256 * 192, 256, 192, 192, 49152);
    k_wconv<<<192, blk, 0, stream>>>(wffni + (size_t)256 * 192, wfi_b + 512 * 192, 254, 192, 192, 49152);
    k_wconv<<<192, blk, 0, stream>>>(wffni + (size_t)766 * 192, wfi_b + 768 * 192, 254, 192, 192, 49152);
    k_wconv<<<384, blk, 0, stream>>>(wffno, wfo_b, 192, 510, 512, 98304);

    // 1. LN1 -> xnb bf16 spatial + xnT bf16 transposed
    k_ln<1><<<256, blk, 0, stream>>>(x, ln1g, ln1b, xnb, xnT);

    // 2. SSL
    k_dwt_row<<<768, blk, 0, stream>>>(xnb, rowbuf);
    k_dwt_colconv<<<dim3(2, CCH, BB), blk, 0, stream>>>(rowbuf, w5, w7, w9, bfilt);
    k_idwt2<<<dim3(8, CCH, BB), blk, 0, stream>>>(bfilt, q, rq2);

    // 3. kv = dw3x3(conv1x1(xn, w_qkv))
    k_gemmS<1, 0, 192, 192><<<dim3(128, 6, BB), blk, 0, stream>>>(xnT, wq_b, kvtmp384, nullptr, 384, 0);
    k_dw8<1><<<dim3(8, 192, BB), blk, 0, stream>>>(kvtmp384, wqkvd, kvb, rk2, 384, 0, 384, 0);
    k_dw8<0><<<dim3(8, 192, BB), blk, 0, stream>>>(kvtmp384, wqkvd + 192 * 9, kvb, nullptr, 384, 192, 384, 192);

    // 4. attention weights + fused output weight
    k_fnorm<<<6, blk, 0, stream>>>(rq2, rk2, rq, rk);
    k_qk_mfma<<<dim3(16, 16), blk, 0, stream>>>(q, kvb, pS);
    k_attn_soft<<<16, blk, 0, stream>>>(pS, rq, rk, temp, attnw);
    k_wfuse<<<dim3(192, 4), 192, 0, stream>>>(wattn, attnw, wf_b);

    // 5. d_out = x + (Wattn @ BDattn) @ V
    k_transT<192><<<dim3(256, 1, BB), blk, 0, stream>>>(kvb, vT, 384, 192, 192, 0);
    k_gemmS<0, 1, 192, 192><<<dim3(128, 3, BB), blk, 0, stream>>>(vT, wf_b, out, x, 192, 36864);

    // 6. xn2T = LN2(d_out)
    k_ln<0><<<256, blk, 0, stream>>>(out, ln2g, ln2b, nullptr, xnT);

    // 7. GDFN
    for (int ck = 0; ck < 2; ++ck) {
        int validc = (ck == 0) ? 256 : 254;
        k_gemmS<1, 0, 192, 192><<<dim3(128, 8, BB), blk, 0, stream>>>(xnT, wfi_b + (size_t)(ck * 512) * 192,
                                                                      y12, nullptr, 512, 0);
        k_dw8gate<<<dim3(8, 256, BB), blk, 0, stream>>>(y12, wffnd + (size_t)(ck * 256) * 9,
                                                        wffnd + (size_t)(510 + ck * 256) * 9, gg, validc);
        k_transT<256><<<dim3(256, 1, BB), blk, 0, stream>>>(gg, gTb, 256, 0, 512, ck * 256);
    }
    k_gemmS<0, 1, 512, 512><<<dim3(128, 3, BB), blk, 0, stream>>>(gTb, wfo_b, out, out, 192, 0);
}

// Round 10
// 641.292 us; speedup vs baseline: 1.0826x; 1.0826x over previous
//
#include <hip/hip_runtime.h>
#include <math.h>

#define HWSZ 16384
#define WID 128
#define HEI 128
#define CCH 192
#define BB 4

typedef short v8s __attribute__((ext_vector_type(8)));
typedef float f32x4 __attribute__((ext_vector_type(4)));

__device__ __constant__ float c_lo[6] = {0.035226291882100656f, -0.08544127388224149f, -0.13501102001039084f,
                                         0.4598775021193313f, 0.8068915093133388f, 0.3326705529509569f};
__device__ __constant__ float c_hi[6] = {-0.3326705529509569f, 0.8068915093133388f, -0.4598775021193313f,
                                         -0.13501102001039084f, 0.08544127388224149f, 0.035226291882100656f};

__device__ __forceinline__ float b2f(unsigned short h) { return __uint_as_float(((unsigned int)h) << 16); }
__device__ __forceinline__ unsigned short f2b(float f) {
    unsigned int u = __float_as_uint(f);
    return (unsigned short)((u + 0x7fffu + ((u >> 16) & 1u)) >> 16);
}
__device__ __forceinline__ unsigned int pk2(float a, float b) {
    return (unsigned int)f2b(a) | ((unsigned int)f2b(b) << 16);
}

// ---------------- weight fp32 -> bf16 with row/col zero-pad ----------------
__global__ __launch_bounds__(256) void k_wconv(const float* __restrict__ src,
    unsigned short* __restrict__ dst, int rows, int cols, int dcols, int total)
{
    int i = blockIdx.x * 256 + threadIdx.x;
    if (i >= total) return;
    int r = i / dcols, c = i - r * dcols;
    float v = (c < cols && r < rows) ? src[r * cols + c] : 0.f;
    dst[i] = f2b(v);
}

// ---------------- LayerNorm over channel dim ----------------
template<int WRITE_SP>
__global__ __launch_bounds__(256) void k_ln(const float* __restrict__ x,
    const float* __restrict__ g, const float* __restrict__ bta,
    unsigned short* __restrict__ xsp, unsigned short* __restrict__ xT)
{
    int pg = blockIdx.x * 256 + threadIdx.x;
    int b = pg >> 14, p = pg & 16383;
    const float* xp = x + (size_t)b * CCH * HWSZ + p;
    float s = 0.f, s2 = 0.f;
    for (int c = 0; c < CCH; ++c) {
        float v = xp[(size_t)c * HWSZ];
        s += v; s2 += v * v;
    }
    float mu = s * (1.f / CCH);
    float var = s2 * (1.f / CCH) - mu * mu;
    float rs = rsqrtf(var + 1e-5f);
    unsigned short* tr = xT + ((size_t)b * HWSZ + p) * CCH;
    unsigned short* sp = xsp + (size_t)b * CCH * HWSZ + p;
    for (int c0 = 0; c0 < CCH; c0 += 8) {
        float vv[8];
#pragma unroll
        for (int i = 0; i < 8; ++i) {
            float v = xp[(size_t)(c0 + i) * HWSZ];
            v = (v - mu) * rs * g[c0 + i] + bta[c0 + i];
            vv[i] = v;
            if (WRITE_SP) sp[(size_t)(c0 + i) * HWSZ] = f2b(v);
        }
        uint4 u;
        u.x = pk2(vv[0], vv[1]); u.y = pk2(vv[2], vv[3]);
        u.z = pk2(vv[4], vv[5]); u.w = pk2(vv[6], vv[7]);
        *(uint4*)(tr + c0) = u;
    }
}

// ---------------- GEMM: wave = 64px x 64co, grid (M/64 fastest, HW/256, B) ----------------
template<int OUT_BF16, int ADD, int K, int LDW>
__global__ __launch_bounds__(256) void k_gemmW(
    const unsigned short* __restrict__ X, const unsigned short* __restrict__ W,
    void* __restrict__ outp, const float* __restrict__ addsrc,
    int Mtot, int wstrideB)
{
    __shared__ float lds[4][64 * 33];
    int lane = threadIdx.x & 63, wv = threadIdx.x >> 6;
    int b = blockIdx.z;
    int r = lane & 15, koct = lane >> 4;
    int co0 = blockIdx.x * 64;
    int pxb = blockIdx.y * 256 + wv * 64;
    const unsigned short* xb = X + ((size_t)b * HWSZ + pxb + r) * K + koct * 8;
    const unsigned short* wb = W + (size_t)b * wstrideB + (size_t)(co0 + r) * LDW + koct * 8;
    f32x4 z = {0.f, 0.f, 0.f, 0.f};
    f32x4 acc[4][4];
#pragma unroll
    for (int i = 0; i < 4; ++i)
#pragma unroll
        for (int j = 0; j < 4; ++j) acc[i][j] = z;

#pragma unroll 4
    for (int ks = 0; ks < K / 32; ++ks) {
        v8s b0 = *(const v8s*)(xb + ks * 32);
        v8s b1 = *(const v8s*)(xb + 16 * K + ks * 32);
        v8s b2 = *(const v8s*)(xb + 32 * K + ks * 32);
        v8s b3 = *(const v8s*)(xb + 48 * K + ks * 32);
        v8s a0 = *(const v8s*)(wb + ks * 32);
        v8s a1 = *(const v8s*)(wb + 16 * LDW + ks * 32);
        v8s a2 = *(const v8s*)(wb + 32 * LDW + ks * 32);
        v8s a3 = *(const v8s*)(wb + 48 * LDW + ks * 32);
        acc[0][0] = __builtin_amdgcn_mfma_f32_16x16x32_bf16(a0, b0, acc[0][0], 0, 0, 0);
        acc[0][1] = __builtin_amdgcn_mfma_f32_16x16x32_bf16(a0, b1, acc[0][1], 0, 0, 0);
        acc[0][2] = __builtin_amdgcn_mfma_f32_16x16x32_bf16(a0, b2, acc[0][2], 0, 0, 0);
        acc[0][3] = __builtin_amdgcn_mfma_f32_16x16x32_bf16(a0, b3, acc[0][3], 0, 0, 0);
        acc[1][0] = __builtin_amdgcn_mfma_f32_16x16x32_bf16(a1, b0, acc[1][0], 0, 0, 0);
        acc[1][1] = __builtin_amdgcn_mfma_f32_16x16x32_bf16(a1, b1, acc[1][1], 0, 0, 0);
        acc[1][2] = __builtin_amdgcn_mfma_f32_16x16x32_bf16(a1, b2, acc[1][2], 0, 0, 0);
        acc[1][3] = __builtin_amdgcn_mfma_f32_16x16x32_bf16(a1, b3, acc[1][3], 0, 0, 0);
        acc[2][0] = __builtin_amdgcn_mfma_f32_16x16x32_bf16(a2, b0, acc[2][0], 0, 0, 0);
        acc[2][1] = __builtin_amdgcn_mfma_f32_16x16x32_bf16(a2, b1, acc[2][1], 0, 0, 0);
        acc[2][2] = __builtin_amdgcn_mfma_f32_16x16x32_bf16(a2, b2, acc[2][2], 0, 0, 0);
        acc[2][3] = __builtin_amdgcn_mfma_f32_16x16x32_bf16(a2, b3, acc[2][3], 0, 0, 0);
        acc[3][0] = __builtin_amdgcn_mfma_f32_16x16x32_bf16(a3, b0, acc[3][0], 0, 0, 0);
        acc[3][1] = __builtin_amdgcn_mfma_f32_16x16x32_bf16(a3, b1, acc[3][1], 0, 0, 0);
        acc[3][2] = __builtin_amdgcn_mfma_f32_16x16x32_bf16(a3, b2, acc[3][2], 0, 0, 0);
        acc[3][3] = __builtin_amdgcn_mfma_f32_16x16x32_bf16(a3, b3, acc[3][3], 0, 0, 0);
    }

    // epilogue: two 32-px passes through per-wave LDS [64co][33]
    float* lw = lds[wv];
#pragma unroll
    for (int p = 0; p < 2; ++p) {
        __syncthreads();
#pragma unroll
        for (int i = 0; i < 4; ++i)
#pragma unroll
            for (int jh = 0; jh < 2; ++jh)
#pragma unroll
                for (int jj = 0; jj < 4; ++jj)
                    lw[(i * 16 + koct * 4 + jj) * 33 + jh * 16 + r] = acc[i][p * 2 + jh][jj];
        __syncthreads();
        int cl = lane >> 3, p4 = (lane & 7) * 4;
        size_t obase = ((size_t)b * Mtot + co0) * HWSZ + pxb + p * 32;
#pragma unroll
        for (int cg = 0; cg < 8; ++cg) {
            int co_l = cg * 8 + cl;
            const float* lrow = lw + co_l * 33 + p4;
            float v0 = lrow[0], v1 = lrow[1], v2 = lrow[2], v3 = lrow[3];
            size_t oi = obase + (size_t)co_l * HWSZ + p4;
            if (ADD) {
                float4 a = *(const float4*)(addsrc + oi);
                v0 += a.x; v1 += a.y; v2 += a.z; v3 += a.w;
            }
            if (OUT_BF16) {
                uint2 u;
                u.x = pk2(v0, v1); u.y = pk2(v2, v3);
                *(uint2*)((unsigned short*)outp + oi) = u;
            } else {
                float4 f = {v0, v1, v2, v3};
                *(float4*)((float*)outp + oi) = f;
            }
        }
    }
}

// ---------------- depthwise helpers ----------------
__device__ __forceinline__ void dw_load_tile(const unsigned short* __restrict__ ip,
    int r0, float (&tile)[18][132], int tid)
{
    for (int e = tid; e < 576; e += 256) {
        int r = e >> 5, q4 = e & 31;
        int gr = r0 - 1 + r;
        float v0 = 0.f, v1 = 0.f, v2 = 0.f, v3 = 0.f;
        if (gr >= 0 && gr < HEI) {
            uint2 u = *(const uint2*)(ip + gr * WID + q4 * 4);
            const unsigned short* pu = (const unsigned short*)&u;
            v0 = b2f(pu[0]); v1 = b2f(pu[1]); v2 = b2f(pu[2]); v3 = b2f(pu[3]);
        }
        int cb = 1 + q4 * 4;
        tile[r][cb] = v0; tile[r][cb + 1] = v1; tile[r][cb + 2] = v2; tile[r][cb + 3] = v3;
    }
    if (tid < 18) { tile[tid][0] = 0.f; tile[tid][129] = 0.f; }
}

__device__ __forceinline__ void dw_compute8(const float (&tile)[18][132],
    const float* wr, int rl, int px0, float (&o)[8])
{
    float r0[10], r1[10], r2[10];
#pragma unroll
    for (int i = 0; i < 10; ++i) {
        r0[i] = tile[rl][px0 + i];
        r1[i] = tile[rl + 1][px0 + i];
        r2[i] = tile[rl + 2][px0 + i];
    }
#pragma unroll
    for (int j = 0; j < 8; ++j) {
        o[j] = r0[j] * wr[0] + r0[j + 1] * wr[1] + r0[j + 2] * wr[2]
             + r1[j] * wr[3] + r1[j + 1] * wr[4] + r1[j + 2] * wr[5]
             + r2[j] * wr[6] + r2[j + 1] * wr[7] + r2[j + 2] * wr[8];
    }
}

// ---------------- depthwise 3x3 bf16; opt k^2 reduce ----------------
template<int REDUCE>
__global__ __launch_bounds__(256) void k_dw8(const unsigned short* __restrict__ in,
    const float* __restrict__ w, unsigned short* __restrict__ out, float* __restrict__ red,
    int inCtot, int inCoff, int outCtot, int outCoff)
{
    __shared__ float tile[18][132];
    int g = blockIdx.x, c = blockIdx.y, b = blockIdx.z;
    int tid = threadIdx.x;
    const unsigned short* ip = in + (size_t)(b * inCtot + inCoff + c) * HWSZ;
    dw_load_tile(ip, g * 16, tile, tid);
    float wr[9];
#pragma unroll
    for (int j = 0; j < 9; ++j) wr[j] = w[c * 9 + j];
    __syncthreads();
    int rl = tid >> 4, px0 = (tid & 15) * 8;
    float o[8];
    dw_compute8(tile, wr, rl, px0, o);
    unsigned short* op = out + (size_t)(b * outCtot + outCoff + c) * HWSZ + (g * 16 + rl) * WID + px0;
    uint4 u;
    u.x = pk2(o[0], o[1]); u.y = pk2(o[2], o[3]); u.z = pk2(o[4], o[5]); u.w = pk2(o[6], o[7]);
    *(uint4*)op = u;
    if (REDUCE) {
        float s = 0.f;
#pragma unroll
        for (int j = 0; j < 8; ++j) s += o[j] * o[j];
        for (int off = 32; off; off >>= 1) s += __shfl_down(s, off, 64);
        __shared__ float w4[4];
        if ((tid & 63) == 0) w4[tid >> 6] = s;
        __syncthreads();
        if (tid == 0) atomicAdd(red + b * CCH + c, w4[0] + w4[1] + w4[2] + w4[3]);
    }
}

// ---------------- fused FFN: dw3x3(y1), dw3x3(y2), gelu(a)*b ----------------
__global__ __launch_bounds__(256) void k_dw8gate(const unsigned short* __restrict__ y12,
    const float* __restrict__ w1, const float* __restrict__ w2,
    unsigned short* __restrict__ out, int validc)
{
    __shared__ float t1[18][132];
    __shared__ float t2[18][132];
    int g = blockIdx.x, c = blockIdx.y, b = blockIdx.z;
    int tid = threadIdx.x;
    const unsigned short* i1 = y12 + (size_t)(b * 512 + c) * HWSZ;
    const unsigned short* i2 = y12 + (size_t)(b * 512 + 256 + c) * HWSZ;
    dw_load_tile(i1, g * 16, t1, tid);
    dw_load_tile(i2, g * 16, t2, tid);
    bool vc = (c < validc);
    float wr1[9], wr2[9];
#pragma unroll
    for (int j = 0; j < 9; ++j) {
        wr1[j] = vc ? w1[c * 9 + j] : 0.f;
        wr2[j] = vc ? w2[c * 9 + j] : 0.f;
    }
    __syncthreads();
    int rl = tid >> 4, px0 = (tid & 15) * 8;
    float a[8], bg[8];
    dw_compute8(t1, wr1, rl, px0, a);
    dw_compute8(t2, wr2, rl, px0, bg);
    float o[8];
#pragma unroll
    for (int j = 0; j < 8; ++j)
        o[j] = 0.5f * a[j] * (1.f + erff(a[j] * 0.70710678118654752f)) * bg[j];
    unsigned short* op = out + (size_t)(b * 256 + c) * HWSZ + (g * 16 + rl) * WID + px0;
    uint4 u;
    u.x = pk2(o[0], o[1]); u.y = pk2(o[2], o[3]); u.z = pk2(o[4], o[5]); u.w = pk2(o[6], o[7]);
    *(uint4*)op = u;
}

// ---------------- transpose [b][*][HW] -> [b][px][ldo] bf16, XOR swizzle ----------------
template<int CT>
__global__ __launch_bounds__(256) void k_transT(const unsigned short* __restrict__ in,
    unsigned short* __restrict__ outT, int inCtot, int inCoff, int ldo, int coff)
{
    __shared__ unsigned short lt[64 * CT];
    const int NG = CT / 8;
    int px0 = blockIdx.x * 64, b = blockIdx.z;
    for (int idx = threadIdx.x; idx < 8 * CT; idx += 256) {
        int ch = idx >> 3, chunk = idx & 7;
        uint4 u = *(const uint4*)(in + ((size_t)(b * inCtot + inCoff + ch)) * HWSZ + px0 + chunk * 8);
        const unsigned short* pu = (const unsigned short*)&u;
        int gq = ch >> 3, j = ch & 7;
#pragma unroll
        for (int i = 0; i < 8; ++i) {
            int row = chunk * 8 + i;
            int gs = gq ^ (row >> 3);
            lt[row * CT + gs * 8 + j] = pu[i];
        }
    }
    __syncthreads();
    for (int idx = threadIdx.x; idx < 8 * CT; idx += 256) {
        int px = idx / NG, cc = idx - px * NG;
        int gs = cc ^ (px >> 3);
        uint4 v = *(const uint4*)&lt[px * CT + gs * 8];
        *(uint4*)(outT + ((size_t)b * HWSZ + px0 + px) * ldo + coff + cc * 8) = v;
    }
}

// ---------------- DWT row pass (bf16 in/out, 72-padded rows) ----------------
__global__ __launch_bounds__(256) void k_dwt_row(const unsigned short* __restrict__ xnb,
    unsigned short* __restrict__ rowbuf)
{
    int bc = blockIdx.x;
    const unsigned short* ip = xnb + (size_t)bc * HWSZ;
    unsigned short* lo = rowbuf + (size_t)bc * 9216;
    unsigned short* hi = rowbuf + (size_t)(768 + bc) * 9216;
    for (int idx = threadIdx.x; idx < 128 * 66; idx += 256) {
        int row = idx / 66, ow = idx - row * 66;
        const unsigned short* rp = ip + row * 128;
        int base = 2 * ow - 4;
        float v[6];
#pragma unroll
        for (int j = 0; j < 6; ++j) {
            int iw = base + j;
            v[j] = (iw >= 0 && iw < 128) ? b2f(rp[iw]) : 0.f;
        }
        float lv = 0.f, hv = 0.f;
#pragma unroll
        for (int j = 0; j < 6; ++j) {
            lv += v[j] * c_lo[5 - j];
            hv += v[j] * c_hi[5 - j];
        }
        lo[row * 72 + ow] = f2b(lv); hi[row * 72 + ow] = f2b(hv);
    }
}

// ---------------- DWT col pass + band 3x3 dwconv ----------------
__global__ __launch_bounds__(256) void k_dwt_colconv(const unsigned short* __restrict__ rowbuf,
    const float* __restrict__ w5, const float* __restrict__ w7, const float* __restrict__ w9,
    unsigned short* __restrict__ bfilt)
{
    __shared__ unsigned short rb[136][72];
    __shared__ float bnd[68][68];
    int h = blockIdx.x, c = blockIdx.y, b = blockIdx.z;
    int tid = threadIdx.x;
    int bc = b * CCH + c;
    const unsigned short* src = rowbuf + (size_t)(h * 768 + bc) * 9216;
    for (int e = tid; e < 1224; e += 256) {
        int r = e / 9, qd = e - r * 9;
        int gr = r - 4;
        uint4 u = make_uint4(0, 0, 0, 0);
        if (gr >= 0 && gr < 128) u = *(const uint4*)(src + gr * 72 + qd * 8);
        *(uint4*)&rb[r][qd * 8] = u;
    }
    for (int e = tid; e < 268; e += 256) {
        int rr, cc;
        if (e < 68) { rr = 0; cc = e; }
        else if (e < 136) { rr = 67; cc = e - 68; }
        else if (e < 202) { rr = e - 135; cc = 0; }
        else { rr = e - 201; cc = 67; }
        bnd[rr][cc] = 0.f;
    }
    __syncthreads();
    for (int fs = 0; fs < 2; ++fs) {
        int band = fs * 2 + h;
        const float* fa = fs ? c_hi : c_lo;
        float f5[6];
#pragma unroll
        for (int j = 0; j < 6; ++j) f5[j] = fa[5 - j];
        for (int i = tid; i < 4356; i += 256) {
            int oh = i / 66, ow = i - oh * 66;
            float a = 0.f;
#pragma unroll
            for (int ki = 0; ki < 6; ++ki)
                a += f5[ki] * b2f(rb[oh * 2 + ki][ow]);
            bnd[oh + 1][ow + 1] = a;
        }
        __syncthreads();
        const float* wsel = (band < 2) ? w5 : (band == 2 ? w7 : w9);
        float wr[9];
#pragma unroll
        for (int j = 0; j < 9; ++j) wr[j] = wsel[c * 9 + j];
        unsigned short* op = bfilt + ((size_t)bc * 4 + band) * 4356;
        for (int i = tid; i < 2178; i += 256) {
            int oh = i / 33, p2 = i - oh * 33;
            int ow0 = p2 * 2;
            float t[3][4];
#pragma unroll
            for (int dy = 0; dy < 3; ++dy)
#pragma unroll
                for (int dx = 0; dx < 4; ++dx)
                    t[dy][dx] = bnd[oh + dy][ow0 + dx];
            float o0 = t[0][0] * wr[0] + t[0][1] * wr[1] + t[0][2] * wr[2]
                     + t[1][0] * wr[3] + t[1][1] * wr[4] + t[1][2] * wr[5]
                     + t[2][0] * wr[6] + t[2][1] * wr[7] + t[2][2] * wr[8];
            float o1 = t[0][1] * wr[0] + t[0][2] * wr[1] + t[0][3] * wr[2]
                     + t[1][1] * wr[3] + t[1][2] * wr[4] + t[1][3] * wr[5]
                     + t[2][1] * wr[6] + t[2][2] * wr[7] + t[2][3] * wr[8];
            *(unsigned int*)(op + oh * 66 + ow0) = pk2(o0, o1);
        }
        __syncthreads();
    }
}

// ---------------- fused IDWT over 4 bands + q^2 reduce ----------------
__global__ __launch_bounds__(256) void k_idwt2(const unsigned short* __restrict__ bfilt,
    unsigned short* __restrict__ q, float* __restrict__ rq2)
{
    __shared__ float L[4][10][68];
    __shared__ float w4[4];
    int g = blockIdx.x;
    int c = blockIdx.y, b = blockIdx.z;
    int tid = threadIdx.x;
    int bc = b * CCH + c;
    const unsigned short* bp = bfilt + (size_t)bc * 4 * 4356;
    for (int e = tid; e < 1320; e += 256) {
        int idx = e * 2;
        int band = idx / 660, rem = idx - band * 660;
        int rr = rem / 66, cc = rem - rr * 66;
        unsigned int u = *(const unsigned int*)(bp + band * 4356 + (8 * g + rr) * 66 + cc);
        L[band][rr][cc] = b2f((unsigned short)(u & 0xffffu));
        L[band][rr][cc + 1] = b2f((unsigned short)(u >> 16));
    }
    __syncthreads();
    int rl = tid >> 4, px0 = (tid & 15) * 8;
    int oh = 16 * g + rl;
    int Tl = rl >> 1, pr = rl & 1;
    int mb = px0 >> 1;
    float acc[8];
#pragma unroll
    for (int j = 0; j < 8; ++j) acc[j] = 0.f;
#pragma unroll
    for (int band = 0; band < 4; ++band) {
        const float* fv = (band < 2) ? c_lo : c_hi;
        const float* fh = (band & 1) ? c_hi : c_lo;
        float fv3[3] = {fv[1 - pr], fv[3 - pr], fv[5 - pr]};
        float fhe[3] = {fh[1], fh[3], fh[5]};
        float fho[3] = {fh[0], fh[2], fh[4]};
#pragma unroll
        for (int i = 0; i < 3; ++i) {
            float r6[6];
#pragma unroll
            for (int m = 0; m < 6; ++m) r6[m] = L[band][Tl + i][mb + m];
#pragma unroll
            for (int jj = 0; jj < 4; ++jj) {
                float se = fhe[0] * r6[jj] + fhe[1] * r6[jj + 1] + fhe[2] * r6[jj + 2];
                float so = fho[0] * r6[jj] + fho[1] * r6[jj + 1] + fho[2] * r6[jj + 2];
                acc[2 * jj]     += fv3[i] * se;
                acc[2 * jj + 1] += fv3[i] * so;
            }
        }
    }
    unsigned short* op = q + (size_t)bc * HWSZ + oh * WID + px0;
    uint4 u;
    u.x = pk2(acc[0], acc[1]); u.y = pk2(acc[2], acc[3]);
    u.z = pk2(acc[4], acc[5]); u.w = pk2(acc[6], acc[7]);
    *(uint4*)op = u;
    float s = 0.f;
#pragma unroll
    for (int j = 0; j < 8; ++j) s += acc[j] * acc[j];
    for (int off = 32; off; off >>= 1) s += __shfl_down(s, off, 64);
    if ((tid & 63) == 0) w4[tid >> 6] = s;
    __syncthreads();
    if (tid == 0) atomicAdd(rq2 + bc, w4[0] + w4[1] + w4[2] + w4[3]);
}

// ---------------- finalize norms ----------------
__global__ __launch_bounds__(256) void k_fnorm(const float* __restrict__ rq2,
    const float* __restrict__ rk2, float* __restrict__ rq, float* __restrict__ rk)
{
    int i = blockIdx.x * 256 + threadIdx.x;
    if (i < 768) rq[i] = 1.f / fmaxf(sqrtf(rq2[i]), 1e-12f);
    else if (i < 1536) rk[i - 768] = 1.f / fmaxf(sqrtf(rk2[i - 768]), 1e-12f);
}

// ---------------- QK^T via MFMA ----------------
__global__ __launch_bounds__(256) void k_qk_mfma(const unsigned short* __restrict__ q,
    const unsigned short* __restrict__ kv, float* __restrict__ pS)
{
    __shared__ float red[4][2304];
    int slice = blockIdx.x, bh = blockIdx.y;
    int b = bh >> 2, h = bh & 3;
    int wv = threadIdx.x >> 6, lane = threadIdx.x & 63;
    int r = lane & 15, koct = lane >> 4;
    const unsigned short* qb = q + (size_t)(b * CCH + h * 48) * HWSZ;
    const unsigned short* kb = kv + (size_t)(b * 384 + h * 48) * HWSZ;
    int n0 = slice * 1024 + wv * 256 + koct * 8;
    f32x4 z = {0.f, 0.f, 0.f, 0.f};
    f32x4 acc[3][3];
#pragma unroll
    for (int i = 0; i < 3; ++i)
#pragma unroll
        for (int j = 0; j < 3; ++j) acc[i][j] = z;
#pragma unroll
    for (int step = 0; step < 8; ++step) {
        int n = n0 + step * 32;
        v8s qf[3], kf[3];
#pragma unroll
        for (int i = 0; i < 3; ++i) {
            qf[i] = *(const v8s*)(qb + (size_t)(16 * i + r) * HWSZ + n);
            kf[i] = *(const v8s*)(kb + (size_t)(16 * i + r) * HWSZ + n);
        }
#pragma unroll
        for (int i = 0; i < 3; ++i)
#pragma unroll
            for (int j = 0; j < 3; ++j)
                acc[i][j] = __builtin_amdgcn_mfma_f32_16x16x32_bf16(qf[i], kf[j], acc[i][j], 0, 0, 0);
    }
#pragma unroll
    for (int i = 0; i < 3; ++i)
#pragma unroll
        for (int j = 0; j < 3; ++j)
#pragma unroll
            for (int jj = 0; jj < 4; ++jj)
                red[wv][(16 * i + koct * 4 + jj) * 48 + 16 * j + r] = acc[i][j][jj];
    __syncthreads();
    float* ps = pS + (size_t)(slice * 16 + bh) * 2304;
    for (int e = threadIdx.x; e < 2304; e += 256)
        ps[e] = red[0][e] + red[1][e] + red[2][e] + red[3][e];
}

// ---------------- reduce partials, scale, softmax ----------------
__global__ __launch_bounds__(256) void k_attn_soft(const float* __restrict__ pS,
    const float* __restrict__ rq, const float* __restrict__ rk,
    const float* __restrict__ temp, float* __restrict__ attnw)
{
    int bh = blockIdx.x; int b = bh >> 2, h = bh & 3;
    __shared__ float S[48][49];
    int tid = threadIdx.x, dt = tid >> 4, et = tid & 15;
    float tv = temp[h];
#pragma unroll
    for (int i = 0; i < 3; ++i) {
#pragma unroll
        for (int j = 0; j < 3; ++j) {
            int d = dt + 16 * i, e = et + 16 * j;
            float s = 0.f;
            for (int sl = 0; sl < 16; ++sl)
                s += pS[(size_t)(sl * 16 + bh) * 2304 + d * 48 + e];
            S[d][e] = s * tv * rq[b * CCH + h * 48 + d] * rk[b * CCH + h * 48 + e];
        }
    }
    __syncthreads();
    if (tid < 48) {
        float mx = -1e30f;
        for (int e = 0; e < 48; ++e) mx = fmaxf(mx, S[tid][e]);
        float sum = 0.f;
        for (int e = 0; e < 48; ++e) sum += expf(S[tid][e] - mx);
        float inv = 1.f / sum;
        for (int e = 0; e < 48; ++e)
            attnw[((size_t)bh * 48 + tid) * 48 + e] = expf(S[tid][e] - mx) * inv;
    }
}

// ---------------- fuse Wattn @ blockdiag(attn) ----------------
__global__ __launch_bounds__(192) void k_wfuse(const float* __restrict__ wattn,
    const float* __restrict__ attnw, unsigned short* __restrict__ wf)
{
    int co = blockIdx.x, b = blockIdx.y;
    int ce = threadIdx.x;
    int h = ce / 48, e = ce - h * 48;
    const float* wrow = wattn + (size_t)co * 192 + h * 48;
    const float* arow = attnw + ((size_t)(b * 4 + h) * 48) * 48 + e;
    float acc = 0.f;
#pragma unroll 8
    for (int d = 0; d < 48; ++d)
        acc += wrow[d] * arow[(size_t)d * 48];
    wf[((size_t)b * 192 + co) * 192 + ce] = f2b(acc);
}

// ---------------- launcher ----------------
extern "C" void kernel_launch(void* const* d_in, const int* in_sizes, int n_in,
                              void* d_out, int out_size, void* d_ws, size_t ws_size,
                              hipStream_t stream)
{
    const float* x     = (const float*)d_in[0];
    const float* ln1g  = (const float*)d_in[1];
    const float* ln1b  = (const float*)d_in[2];
    const float* ln2g  = (const float*)d_in[3];
    const float* ln2b  = (const float*)d_in[4];
    const float* temp  = (const float*)d_in[5];
    const float* wqkv  = (const float*)d_in[6];
    const float* wqkvd = (const float*)d_in[7];
    const float* w5    = (const float*)d_in[8];
    const float* w7    = (const float*)d_in[9];
    const float* w9    = (const float*)d_in[10];
    const float* wattn = (const float*)d_in[11];
    const float* wffni = (const float*)d_in[12];
    const float* wffnd = (const float*)d_in[13];
    const float* wffno = (const float*)d_in[14];
    float* out = (float*)d_out;

    char* ws = (char*)d_ws;
    unsigned short* xnT = (unsigned short*)(ws + 0);              // 25.2MB (later xn2T)
    unsigned short* xnb = (unsigned short*)(ws + 25165824);       // 25.2MB (later vT/y12)
    unsigned short* q = (unsigned short*)(ws + 75497472);         // 25.2MB
    unsigned short* kvb = (unsigned short*)(ws + 100663296);      // 50.3MB
    unsigned short* bfilt = (unsigned short*)(ws + 100663296);    // bf16 (dead before kvb)
    unsigned short* rowbuf = (unsigned short*)(ws + 154189824);   // 27MB bf16, 72-padded
    unsigned short* kvtmp384 = (unsigned short*)(ws + 154189824); // 50.3MB (rowbuf dead)
    const size_t SM = 226492416;
    float* rq2   = (float*)(ws + SM);
    float* rk2   = (float*)(ws + SM + 4096);
    float* rq    = (float*)(ws + SM + 8192);
    float* rk    = (float*)(ws + SM + 12288);
    float* pS    = (float*)(ws + SM + 16384);                     // aliased by attnw
    float* attnw = pS;
    unsigned short* wq_b  = (unsigned short*)(ws + SM + 2375680);
    unsigned short* wfi_b = (unsigned short*)(ws + SM + 2523136); // [y1ck0|y2ck0|y1ck1|y2ck1]
    unsigned short* wfo_b = (unsigned short*)(ws + SM + 2916352);
    unsigned short* wf_b  = (unsigned short*)(ws + SM + 3112960);
    const size_t NEED = SM + 3407872;
    if (ws_size < NEED) return;

    unsigned short* vT   = xnb;
    unsigned short* y12  = (unsigned short*)(ws + 25165824);
    unsigned short* gg   = (unsigned short*)(ws + 92274688);
    unsigned short* gTb  = (unsigned short*)(ws + 125829120);     // [b][px][512]

    dim3 blk(256);

    // 0. weights -> bf16; zero norm accumulators
    hipMemsetAsync(ws + SM, 0, 8192, stream);
    k_wconv<<<288, blk, 0, stream>>>(wqkv, wq_b, 384, 192, 192, 73728);
    k_wconv<<<192, blk, 0, stream>>>(wffni, wfi_b, 256, 192, 192, 49152);
    k_wconv<<<192, blk, 0, stream>>>(wffni + (size_t)510 * 192, wfi_b + 256 * 192, 256, 192, 192, 49152);
    k_wconv<<<192, blk, 0, stream>>>(wffni + (size_t)256 * 192, wfi_b + 512 * 192, 254, 192, 192, 49152);
    k_wconv<<<192, blk, 0, stream>>>(wffni + (size_t)766 * 192, wfi_b + 768 * 192, 254, 192, 192, 49152);
    k_wconv<<<384, blk, 0, stream>>>(wffno, wfo_b, 192, 510, 512, 98304);

    // 1. LN1 -> xnb bf16 spatial + xnT bf16 transposed
    k_ln<1><<<256, blk, 0, stream>>>(x, ln1g, ln1b, xnb, xnT);

    // 2. SSL
    k_dwt_row<<<768, blk, 0, stream>>>(xnb, rowbuf);
    k_dwt_colconv<<<dim3(2, CCH, BB), blk, 0, stream>>>(rowbuf, w5, w7, w9, bfilt);
    k_idwt2<<<dim3(8, CCH, BB), blk, 0, stream>>>(bfilt, q, rq2);

    // 3. kv = dw3x3(conv1x1(xn, w_qkv))
    k_gemmW<1, 0, 192, 192><<<dim3(6, 64, BB), blk, 0, stream>>>(xnT, wq_b, kvtmp384, nullptr, 384, 0);
    k_dw8<1><<<dim3(8, 192, BB), blk, 0, stream>>>(kvtmp384, wqkvd, kvb, rk2, 384, 0, 384, 0);
    k_dw8<0><<<dim3(8, 192, BB), blk, 0, stream>>>(kvtmp384, wqkvd + 192 * 9, kvb, nullptr, 384, 192, 384, 192);

    // 4. attention weights + fused output weight
    k_fnorm<<<6, blk, 0, stream>>>(rq2, rk2, rq, rk);
    k_qk_mfma<<<dim3(16, 16), blk, 0, stream>>>(q, kvb, pS);
    k_attn_soft<<<16, blk, 0, stream>>>(pS, rq, rk, temp, attnw);
    k_wfuse<<<dim3(192, 4), 192, 0, stream>>>(wattn, attnw, wf_b);

    // 5. d_out = x + (Wattn @ BDattn) @ V
    k_transT<192><<<dim3(256, 1, BB), blk, 0, stream>>>(kvb, vT, 384, 192, 192, 0);
    k_gemmW<0, 1, 192, 192><<<dim3(3, 64, BB), blk, 0, stream>>>(vT, wf_b, out, x, 192, 36864);

    // 6. xn2T = LN2(d_out)
    k_ln<0><<<256, blk, 0, stream>>>(out, ln2g, ln2b, nullptr, xnT);

    // 7. GDFN
    for (int ck = 0; ck < 2; ++ck) {
        int validc = (ck == 0) ? 256 : 254;
        k_gemmW<1, 0, 192, 192><<<dim3(8, 64, BB), blk, 0, stream>>>(xnT, wfi_b + (size_t)(ck * 512) * 192,
                                                                     y12, nullptr, 512, 0);
        k_dw8gate<<<dim3(8, 256, BB), blk, 0, stream>>>(y12, wffnd + (size_t)(ck * 256) * 9,
                                                        wffnd + (size_t)(510 + ck * 256) * 9, gg, validc);
        k_transT<256><<<dim3(256, 1, BB), blk, 0, stream>>>(gg, gTb, 256, 0, 512, ck * 256);
    }
    k_gemmW<0, 1, 512, 512><<<dim3(3, 64, BB), blk, 0, stream>>>(gTb, wfo_b, out, out, 192, 0);
}

// Round 11
// 523.452 us; speedup vs baseline: 1.3263x; 1.2251x over previous
//
#include <hip/hip_runtime.h>
#include <math.h>

#define HWSZ 16384
#define WID 128
#define HEI 128
#define CCH 192
#define BB 4

typedef short v8s __attribute__((ext_vector_type(8)));
typedef float f32x4 __attribute__((ext_vector_type(4)));

__device__ __constant__ float c_lo[6] = {0.035226291882100656f, -0.08544127388224149f, -0.13501102001039084f,
                                         0.4598775021193313f, 0.8068915093133388f, 0.3326705529509569f};
__device__ __constant__ float c_hi[6] = {-0.3326705529509569f, 0.8068915093133388f, -0.4598775021193313f,
                                         -0.13501102001039084f, 0.08544127388224149f, 0.035226291882100656f};

__device__ __forceinline__ float b2f(unsigned short h) { return __uint_as_float(((unsigned int)h) << 16); }
__device__ __forceinline__ unsigned short f2b(float f) {
    unsigned int u = __float_as_uint(f);
    return (unsigned short)((u + 0x7fffu + ((u >> 16) & 1u)) >> 16);
}
__device__ __forceinline__ unsigned int pk2(float a, float b) {
    return (unsigned int)f2b(a) | ((unsigned int)f2b(b) << 16);
}

// async global->LDS, 16B per lane; LDS dest is wave-uniform base + lane*16
__device__ __forceinline__ void gl2lds16(const void* g, void* l) {
    __builtin_amdgcn_global_load_lds((const __attribute__((address_space(1))) unsigned int*)g,
                                     (__attribute__((address_space(3))) unsigned int*)l, 16, 0, 0);
}

// ---------------- weight fp32 -> bf16 with row/col zero-pad ----------------
__global__ __launch_bounds__(256) void k_wconv(const float* __restrict__ src,
    unsigned short* __restrict__ dst, int rows, int cols, int dcols, int total)
{
    int i = blockIdx.x * 256 + threadIdx.x;
    if (i >= total) return;
    int r = i / dcols, c = i - r * dcols;
    float v = (c < cols && r < rows) ? src[r * cols + c] : 0.f;
    dst[i] = f2b(v);
}

// ---------------- LayerNorm over channel dim ----------------
template<int WRITE_SP>
__global__ __launch_bounds__(256) void k_ln(const float* __restrict__ x,
    const float* __restrict__ g, const float* __restrict__ bta,
    unsigned short* __restrict__ xsp, unsigned short* __restrict__ xT)
{
    int pg = blockIdx.x * 256 + threadIdx.x;
    int b = pg >> 14, p = pg & 16383;
    const float* xp = x + (size_t)b * CCH * HWSZ + p;
    float s = 0.f, s2 = 0.f;
    for (int c = 0; c < CCH; ++c) {
        float v = xp[(size_t)c * HWSZ];
        s += v; s2 += v * v;
    }
    float mu = s * (1.f / CCH);
    float var = s2 * (1.f / CCH) - mu * mu;
    float rs = rsqrtf(var + 1e-5f);
    unsigned short* tr = xT + ((size_t)b * HWSZ + p) * CCH;
    unsigned short* sp = xsp + (size_t)b * CCH * HWSZ + p;
    for (int c0 = 0; c0 < CCH; c0 += 8) {
        float vv[8];
#pragma unroll
        for (int i = 0; i < 8; ++i) {
            float v = xp[(size_t)(c0 + i) * HWSZ];
            v = (v - mu) * rs * g[c0 + i] + bta[c0 + i];
            vv[i] = v;
            if (WRITE_SP) sp[(size_t)(c0 + i) * HWSZ] = f2b(v);
        }
        uint4 u;
        u.x = pk2(vv[0], vv[1]); u.y = pk2(vv[2], vv[3]);
        u.z = pk2(vv[4], vv[5]); u.w = pk2(vv[6], vv[7]);
        *(uint4*)(tr + c0) = u;
    }
}

// ---------------- LDS-staged GEMM (m97 structure): tile BM co x 128 px, BK=64 ----------------
// 4 waves 2x2: wave = (BM/2 co) x (64 px). W [M][LDW] bf16 (+per-batch stride); X [b][px][K] bf16.
template<int OUT_BF16, int ADD, int K, int LDW, int BM>
__global__ __launch_bounds__(256) void k_gemmT(
    const unsigned short* __restrict__ X, const unsigned short* __restrict__ W,
    void* __restrict__ outp, const float* __restrict__ addsrc,
    int Mtot, int wstrideB)
{
    constexpr int FI = BM / 32;   // a-frags per wave; also W stage-calls per wave
    constexpr int CO = BM / 2;
    __shared__ char smem[BM * 128 + 16384];
    unsigned short* Wt = (unsigned short*)smem;
    unsigned short* Xt = Wt + BM * 64;
    float* epi = (float*)smem;    // reused after K-loop

    int lane = threadIdx.x & 63, wv = threadIdx.x >> 6;
    int wr = wv >> 1, wc = wv & 1;
    int r = lane & 15, koct = lane >> 4;
    int lr = lane >> 3, lc = lane & 7;
    int b = blockIdx.z;
    int pxb = blockIdx.x * 128;
    int co0 = blockIdx.y * BM;

    const unsigned short* Wbase = W + (size_t)b * wstrideB;
    const unsigned short* Xbase = X + (size_t)b * HWSZ * K;

    f32x4 z = {0.f, 0.f, 0.f, 0.f};
    f32x4 acc[FI][4];
#pragma unroll
    for (int i = 0; i < FI; ++i)
#pragma unroll
        for (int j = 0; j < 4; ++j) acc[i][j] = z;

    for (int kt = 0; kt < K / 64; ++kt) {
        int k0 = kt * 64;
#pragma unroll
        for (int m = 0; m < FI; ++m) {
            int rowb = (wv * FI + m) * 8;
            gl2lds16(Wbase + (size_t)(co0 + rowb + lr) * LDW + k0 + lc * 8, Wt + rowb * 64);
        }
#pragma unroll
        for (int m = 0; m < 4; ++m) {
            int rowb = (wv * 4 + m) * 8;
            gl2lds16(Xbase + (size_t)(pxb + rowb + lr) * K + k0 + lc * 8, Xt + rowb * 64);
        }
        __syncthreads();
#pragma unroll
        for (int ks = 0; ks < 2; ++ks) {
            v8s bfr[4];
#pragma unroll
            for (int j = 0; j < 4; ++j)
                bfr[j] = *(const v8s*)(Xt + (wc * 64 + j * 16 + r) * 64 + ks * 32 + koct * 8);
#pragma unroll
            for (int i = 0; i < FI; ++i) {
                v8s af = *(const v8s*)(Wt + (wr * CO + i * 16 + r) * 64 + ks * 32 + koct * 8);
#pragma unroll
                for (int j = 0; j < 4; ++j)
                    acc[i][j] = __builtin_amdgcn_mfma_f32_16x16x32_bf16(af, bfr[j], acc[i][j], 0, 0, 0);
            }
        }
        __syncthreads();
    }

    // epilogue: per-wave [32co][36] f32 buffer, vectorized stores
    int cl = lane >> 3, p4 = lc * 4;
    float* ew = epi + wv * 1152;
#pragma unroll
    for (int ig = 0; ig < FI / 2; ++ig) {
#pragma unroll
        for (int p = 0; p < 2; ++p) {
            __syncthreads();
#pragma unroll
            for (int f = 0; f < 2; ++f)
#pragma unroll
                for (int jh = 0; jh < 2; ++jh)
#pragma unroll
                    for (int jj = 0; jj < 4; ++jj)
                        ew[(f * 16 + koct * 4 + jj) * 36 + jh * 16 + r] = acc[ig * 2 + f][p * 2 + jh][jj];
            __syncthreads();
#pragma unroll
            for (int cg = 0; cg < 4; ++cg) {
                int co_l = cg * 8 + cl;
                const float* lrow = ew + co_l * 36 + p4;
                float v0 = lrow[0], v1 = lrow[1], v2 = lrow[2], v3 = lrow[3];
                int co = co0 + wr * CO + ig * 32 + co_l;
                size_t oi = ((size_t)b * Mtot + co) * HWSZ + pxb + wc * 64 + p * 32 + p4;
                if (ADD) {
                    float4 a = *(const float4*)(addsrc + oi);
                    v0 += a.x; v1 += a.y; v2 += a.z; v3 += a.w;
                }
                if (OUT_BF16) {
                    uint2 u;
                    u.x = pk2(v0, v1); u.y = pk2(v2, v3);
                    *(uint2*)((unsigned short*)outp + oi) = u;
                } else {
                    float4 f4 = {v0, v1, v2, v3};
                    *(float4*)((float*)outp + oi) = f4;
                }
            }
        }
    }
}

// ---------------- depthwise helpers ----------------
__device__ __forceinline__ void dw_load_tile(const unsigned short* __restrict__ ip,
    int r0, float (&tile)[18][132], int tid)
{
    for (int e = tid; e < 576; e += 256) {
        int r = e >> 5, q4 = e & 31;
        int gr = r0 - 1 + r;
        float v0 = 0.f, v1 = 0.f, v2 = 0.f, v3 = 0.f;
        if (gr >= 0 && gr < HEI) {
            uint2 u = *(const uint2*)(ip + gr * WID + q4 * 4);
            const unsigned short* pu = (const unsigned short*)&u;
            v0 = b2f(pu[0]); v1 = b2f(pu[1]); v2 = b2f(pu[2]); v3 = b2f(pu[3]);
        }
        int cb = 1 + q4 * 4;
        tile[r][cb] = v0; tile[r][cb + 1] = v1; tile[r][cb + 2] = v2; tile[r][cb + 3] = v3;
    }
    if (tid < 18) { tile[tid][0] = 0.f; tile[tid][129] = 0.f; }
}

__device__ __forceinline__ void dw_compute8(const float (&tile)[18][132],
    const float* wr, int rl, int px0, float (&o)[8])
{
    float r0[10], r1[10], r2[10];
#pragma unroll
    for (int i = 0; i < 10; ++i) {
        r0[i] = tile[rl][px0 + i];
        r1[i] = tile[rl + 1][px0 + i];
        r2[i] = tile[rl + 2][px0 + i];
    }
#pragma unroll
    for (int j = 0; j < 8; ++j) {
        o[j] = r0[j] * wr[0] + r0[j + 1] * wr[1] + r0[j + 2] * wr[2]
             + r1[j] * wr[3] + r1[j + 1] * wr[4] + r1[j + 2] * wr[5]
             + r2[j] * wr[6] + r2[j + 1] * wr[7] + r2[j + 2] * wr[8];
    }
}

// ---------------- depthwise 3x3 bf16; opt k^2 reduce ----------------
template<int REDUCE>
__global__ __launch_bounds__(256) void k_dw8(const unsigned short* __restrict__ in,
    const float* __restrict__ w, unsigned short* __restrict__ out, float* __restrict__ red,
    int inCtot, int inCoff, int outCtot, int outCoff)
{
    __shared__ float tile[18][132];
    int g = blockIdx.x, c = blockIdx.y, b = blockIdx.z;
    int tid = threadIdx.x;
    const unsigned short* ip = in + (size_t)(b * inCtot + inCoff + c) * HWSZ;
    dw_load_tile(ip, g * 16, tile, tid);
    float wr[9];
#pragma unroll
    for (int j = 0; j < 9; ++j) wr[j] = w[c * 9 + j];
    __syncthreads();
    int rl = tid >> 4, px0 = (tid & 15) * 8;
    float o[8];
    dw_compute8(tile, wr, rl, px0, o);
    unsigned short* op = out + (size_t)(b * outCtot + outCoff + c) * HWSZ + (g * 16 + rl) * WID + px0;
    uint4 u;
    u.x = pk2(o[0], o[1]); u.y = pk2(o[2], o[3]); u.z = pk2(o[4], o[5]); u.w = pk2(o[6], o[7]);
    *(uint4*)op = u;
    if (REDUCE) {
        float s = 0.f;
#pragma unroll
        for (int j = 0; j < 8; ++j) s += o[j] * o[j];
        for (int off = 32; off; off >>= 1) s += __shfl_down(s, off, 64);
        __shared__ float w4[4];
        if ((tid & 63) == 0) w4[tid >> 6] = s;
        __syncthreads();
        if (tid == 0) atomicAdd(red + b * CCH + c, w4[0] + w4[1] + w4[2] + w4[3]);
    }
}

// ---------------- fused FFN: dw3x3(y1), dw3x3(y2), gelu(a)*b ----------------
__global__ __launch_bounds__(256) void k_dw8gate(const unsigned short* __restrict__ y12,
    const float* __restrict__ w1, const float* __restrict__ w2,
    unsigned short* __restrict__ out, int validc)
{
    __shared__ float t1[18][132];
    __shared__ float t2[18][132];
    int g = blockIdx.x, c = blockIdx.y, b = blockIdx.z;
    int tid = threadIdx.x;
    const unsigned short* i1 = y12 + (size_t)(b * 512 + c) * HWSZ;
    const unsigned short* i2 = y12 + (size_t)(b * 512 + 256 + c) * HWSZ;
    dw_load_tile(i1, g * 16, t1, tid);
    dw_load_tile(i2, g * 16, t2, tid);
    bool vc = (c < validc);
    float wr1[9], wr2[9];
#pragma unroll
    for (int j = 0; j < 9; ++j) {
        wr1[j] = vc ? w1[c * 9 + j] : 0.f;
        wr2[j] = vc ? w2[c * 9 + j] : 0.f;
    }
    __syncthreads();
    int rl = tid >> 4, px0 = (tid & 15) * 8;
    float a[8], bg[8];
    dw_compute8(t1, wr1, rl, px0, a);
    dw_compute8(t2, wr2, rl, px0, bg);
    float o[8];
#pragma unroll
    for (int j = 0; j < 8; ++j)
        o[j] = 0.5f * a[j] * (1.f + erff(a[j] * 0.70710678118654752f)) * bg[j];
    unsigned short* op = out + (size_t)(b * 256 + c) * HWSZ + (g * 16 + rl) * WID + px0;
    uint4 u;
    u.x = pk2(o[0], o[1]); u.y = pk2(o[2], o[3]); u.z = pk2(o[4], o[5]); u.w = pk2(o[6], o[7]);
    *(uint4*)op = u;
}

// ---------------- transpose [b][*][HW] -> [b][px][ldo] bf16, XOR swizzle ----------------
template<int CT>
__global__ __launch_bounds__(256) void k_transT(const unsigned short* __restrict__ in,
    unsigned short* __restrict__ outT, int inCtot, int inCoff, int ldo, int coff)
{
    __shared__ unsigned short lt[64 * CT];
    const int NG = CT / 8;
    int px0 = blockIdx.x * 64, b = blockIdx.z;
    for (int idx = threadIdx.x; idx < 8 * CT; idx += 256) {
        int ch = idx >> 3, chunk = idx & 7;
        uint4 u = *(const uint4*)(in + ((size_t)(b * inCtot + inCoff + ch)) * HWSZ + px0 + chunk * 8);
        const unsigned short* pu = (const unsigned short*)&u;
        int gq = ch >> 3, j = ch & 7;
#pragma unroll
        for (int i = 0; i < 8; ++i) {
            int row = chunk * 8 + i;
            int gs = gq ^ (row >> 3);
            lt[row * CT + gs * 8 + j] = pu[i];
        }
    }
    __syncthreads();
    for (int idx = threadIdx.x; idx < 8 * CT; idx += 256) {
        int px = idx / NG, cc = idx - px * NG;
        int gs = cc ^ (px >> 3);
        uint4 v = *(const uint4*)&lt[px * CT + gs * 8];
        *(uint4*)(outT + ((size_t)b * HWSZ + px0 + px) * ldo + coff + cc * 8) = v;
    }
}

// ---------------- DWT row pass (bf16 in/out, 72-padded rows) ----------------
__global__ __launch_bounds__(256) void k_dwt_row(const unsigned short* __restrict__ xnb,
    unsigned short* __restrict__ rowbuf)
{
    int bc = blockIdx.x;
    const unsigned short* ip = xnb + (size_t)bc * HWSZ;
    unsigned short* lo = rowbuf + (size_t)bc * 9216;
    unsigned short* hi = rowbuf + (size_t)(768 + bc) * 9216;
    for (int idx = threadIdx.x; idx < 128 * 66; idx += 256) {
        int row = idx / 66, ow = idx - row * 66;
        const unsigned short* rp = ip + row * 128;
        int base = 2 * ow - 4;
        float v[6];
#pragma unroll
        for (int j = 0; j < 6; ++j) {
            int iw = base + j;
            v[j] = (iw >= 0 && iw < 128) ? b2f(rp[iw]) : 0.f;
        }
        float lv = 0.f, hv = 0.f;
#pragma unroll
        for (int j = 0; j < 6; ++j) {
            lv += v[j] * c_lo[5 - j];
            hv += v[j] * c_hi[5 - j];
        }
        lo[row * 72 + ow] = f2b(lv); hi[row * 72 + ow] = f2b(hv);
    }
}

// ---------------- DWT col pass + band 3x3 dwconv ----------------
__global__ __launch_bounds__(256) void k_dwt_colconv(const unsigned short* __restrict__ rowbuf,
    const float* __restrict__ w5, const float* __restrict__ w7, const float* __restrict__ w9,
    unsigned short* __restrict__ bfilt)
{
    __shared__ unsigned short rb[136][72];
    __shared__ float bnd[68][68];
    int h = blockIdx.x, c = blockIdx.y, b = blockIdx.z;
    int tid = threadIdx.x;
    int bc = b * CCH + c;
    const unsigned short* src = rowbuf + (size_t)(h * 768 + bc) * 9216;
    for (int e = tid; e < 1224; e += 256) {
        int r = e / 9, qd = e - r * 9;
        int gr = r - 4;
        uint4 u = make_uint4(0, 0, 0, 0);
        if (gr >= 0 && gr < 128) u = *(const uint4*)(src + gr * 72 + qd * 8);
        *(uint4*)&rb[r][qd * 8] = u;
    }
    for (int e = tid; e < 268; e += 256) {
        int rr, cc;
        if (e < 68) { rr = 0; cc = e; }
        else if (e < 136) { rr = 67; cc = e - 68; }
        else if (e < 202) { rr = e - 135; cc = 0; }
        else { rr = e - 201; cc = 67; }
        bnd[rr][cc] = 0.f;
    }
    __syncthreads();
    for (int fs = 0; fs < 2; ++fs) {
        int band = fs * 2 + h;
        const float* fa = fs ? c_hi : c_lo;
        float f5[6];
#pragma unroll
        for (int j = 0; j < 6; ++j) f5[j] = fa[5 - j];
        for (int i = tid; i < 4356; i += 256) {
            int oh = i / 66, ow = i - oh * 66;
            float a = 0.f;
#pragma unroll
            for (int ki = 0; ki < 6; ++ki)
                a += f5[ki] * b2f(rb[oh * 2 + ki][ow]);
            bnd[oh + 1][ow + 1] = a;
        }
        __syncthreads();
        const float* wsel = (band < 2) ? w5 : (band == 2 ? w7 : w9);
        float wr[9];
#pragma unroll
        for (int j = 0; j < 9; ++j) wr[j] = wsel[c * 9 + j];
        unsigned short* op = bfilt + ((size_t)bc * 4 + band) * 4356;
        for (int i = tid; i < 2178; i += 256) {
            int oh = i / 33, p2 = i - oh * 33;
            int ow0 = p2 * 2;
            float t[3][4];
#pragma unroll
            for (int dy = 0; dy < 3; ++dy)
#pragma unroll
                for (int dx = 0; dx < 4; ++dx)
                    t[dy][dx] = bnd[oh + dy][ow0 + dx];
            float o0 = t[0][0] * wr[0] + t[0][1] * wr[1] + t[0][2] * wr[2]
                     + t[1][0] * wr[3] + t[1][1] * wr[4] + t[1][2] * wr[5]
                     + t[2][0] * wr[6] + t[2][1] * wr[7] + t[2][2] * wr[8];
            float o1 = t[0][1] * wr[0] + t[0][2] * wr[1] + t[0][3] * wr[2]
                     + t[1][1] * wr[3] + t[1][2] * wr[4] + t[1][3] * wr[5]
                     + t[2][1] * wr[6] + t[2][2] * wr[7] + t[2][3] * wr[8];
            *(unsigned int*)(op + oh * 66 + ow0) = pk2(o0, o1);
        }
        __syncthreads();
    }
}

// ---------------- fused IDWT over 4 bands + q^2 reduce ----------------
__global__ __launch_bounds__(256) void k_idwt2(const unsigned short* __restrict__ bfilt,
    unsigned short* __restrict__ q, float* __restrict__ rq2)
{
    __shared__ float L[4][10][68];
    __shared__ float w4[4];
    int g = blockIdx.x;
    int c = blockIdx.y, b = blockIdx.z;
    int tid = threadIdx.x;
    int bc = b * CCH + c;
    const unsigned short* bp = bfilt + (size_t)bc * 4 * 4356;
    for (int e = tid; e < 1320; e += 256) {
        int idx = e * 2;
        int band = idx / 660, rem = idx - band * 660;
        int rr = rem / 66, cc = rem - rr * 66;
        unsigned int u = *(const unsigned int*)(bp + band * 4356 + (8 * g + rr) * 66 + cc);
        L[band][rr][cc] = b2f((unsigned short)(u & 0xffffu));
        L[band][rr][cc + 1] = b2f((unsigned short)(u >> 16));
    }
    __syncthreads();
    int rl = tid >> 4, px0 = (tid & 15) * 8;
    int oh = 16 * g + rl;
    int Tl = rl >> 1, pr = rl & 1;
    int mb = px0 >> 1;
    float acc[8];
#pragma unroll
    for (int j = 0; j < 8; ++j) acc[j] = 0.f;
#pragma unroll
    for (int band = 0; band < 4; ++band) {
        const float* fv = (band < 2) ? c_lo : c_hi;
        const float* fh = (band & 1) ? c_hi : c_lo;
        float fv3[3] = {fv[1 - pr], fv[3 - pr], fv[5 - pr]};
        float fhe[3] = {fh[1], fh[3], fh[5]};
        float fho[3] = {fh[0], fh[2], fh[4]};
#pragma unroll
        for (int i = 0; i < 3; ++i) {
            float r6[6];
#pragma unroll
            for (int m = 0; m < 6; ++m) r6[m] = L[band][Tl + i][mb + m];
#pragma unroll
            for (int jj = 0; jj < 4; ++jj) {
                float se = fhe[0] * r6[jj] + fhe[1] * r6[jj + 1] + fhe[2] * r6[jj + 2];
                float so = fho[0] * r6[jj] + fho[1] * r6[jj + 1] + fho[2] * r6[jj + 2];
                acc[2 * jj]     += fv3[i] * se;
                acc[2 * jj + 1] += fv3[i] * so;
            }
        }
    }
    unsigned short* op = q + (size_t)bc * HWSZ + oh * WID + px0;
    uint4 u;
    u.x = pk2(acc[0], acc[1]); u.y = pk2(acc[2], acc[3]);
    u.z = pk2(acc[4], acc[5]); u.w = pk2(acc[6], acc[7]);
    *(uint4*)op = u;
    float s = 0.f;
#pragma unroll
    for (int j = 0; j < 8; ++j) s += acc[j] * acc[j];
    for (int off = 32; off; off >>= 1) s += __shfl_down(s, off, 64);
    if ((tid & 63) == 0) w4[tid >> 6] = s;
    __syncthreads();
    if (tid == 0) atomicAdd(rq2 + bc, w4[0] + w4[1] + w4[2] + w4[3]);
}

// ---------------- finalize norms ----------------
__global__ __launch_bounds__(256) void k_fnorm(const float* __restrict__ rq2,
    const float* __restrict__ rk2, float* __restrict__ rq, float* __restrict__ rk)
{
    int i = blockIdx.x * 256 + threadIdx.x;
    if (i < 768) rq[i] = 1.f / fmaxf(sqrtf(rq2[i]), 1e-12f);
    else if (i < 1536) rk[i - 768] = 1.f / fmaxf(sqrtf(rk2[i - 768]), 1e-12f);
}

// ---------------- QK^T via MFMA ----------------
__global__ __launch_bounds__(256) void k_qk_mfma(const unsigned short* __restrict__ q,
    const unsigned short* __restrict__ kv, float* __restrict__ pS)
{
    __shared__ float red[4][2304];
    int slice = blockIdx.x, bh = blockIdx.y;
    int b = bh >> 2, h = bh & 3;
    int wv = threadIdx.x >> 6, lane = threadIdx.x & 63;
    int r = lane & 15, koct = lane >> 4;
    const unsigned short* qb = q + (size_t)(b * CCH + h * 48) * HWSZ;
    const unsigned short* kb = kv + (size_t)(b * 384 + h * 48) * HWSZ;
    int n0 = slice * 1024 + wv * 256 + koct * 8;
    f32x4 z = {0.f, 0.f, 0.f, 0.f};
    f32x4 acc[3][3];
#pragma unroll
    for (int i = 0; i < 3; ++i)
#pragma unroll
        for (int j = 0; j < 3; ++j) acc[i][j] = z;
#pragma unroll
    for (int step = 0; step < 8; ++step) {
        int n = n0 + step * 32;
        v8s qf[3], kf[3];
#pragma unroll
        for (int i = 0; i < 3; ++i) {
            qf[i] = *(const v8s*)(qb + (size_t)(16 * i + r) * HWSZ + n);
            kf[i] = *(const v8s*)(kb + (size_t)(16 * i + r) * HWSZ + n);
        }
#pragma unroll
        for (int i = 0; i < 3; ++i)
#pragma unroll
            for (int j = 0; j < 3; ++j)
                acc[i][j] = __builtin_amdgcn_mfma_f32_16x16x32_bf16(qf[i], kf[j], acc[i][j], 0, 0, 0);
    }
#pragma unroll
    for (int i = 0; i < 3; ++i)
#pragma unroll
        for (int j = 0; j < 3; ++j)
#pragma unroll
            for (int jj = 0; jj < 4; ++jj)
                red[wv][(16 * i + koct * 4 + jj) * 48 + 16 * j + r] = acc[i][j][jj];
    __syncthreads();
    float* ps = pS + (size_t)(slice * 16 + bh) * 2304;
    for (int e = threadIdx.x; e < 2304; e += 256)
        ps[e] = red[0][e] + red[1][e] + red[2][e] + red[3][e];
}

// ---------------- reduce partials, scale, softmax ----------------
__global__ __launch_bounds__(256) void k_attn_soft(const float* __restrict__ pS,
    const float* __restrict__ rq, const float* __restrict__ rk,
    const float* __restrict__ temp, float* __restrict__ attnw)
{
    int bh = blockIdx.x; int b = bh >> 2, h = bh & 3;
    __shared__ float S[48][49];
    int tid = threadIdx.x, dt = tid >> 4, et = tid & 15;
    float tv = temp[h];
#pragma unroll
    for (int i = 0; i < 3; ++i) {
#pragma unroll
        for (int j = 0; j < 3; ++j) {
            int d = dt + 16 * i, e = et + 16 * j;
            float s = 0.f;
            for (int sl = 0; sl < 16; ++sl)
                s += pS[(size_t)(sl * 16 + bh) * 2304 + d * 48 + e];
            S[d][e] = s * tv * rq[b * CCH + h * 48 + d] * rk[b * CCH + h * 48 + e];
        }
    }
    __syncthreads();
    if (tid < 48) {
        float mx = -1e30f;
        for (int e = 0; e < 48; ++e) mx = fmaxf(mx, S[tid][e]);
        float sum = 0.f;
        for (int e = 0; e < 48; ++e) sum += expf(S[tid][e] - mx);
        float inv = 1.f / sum;
        for (int e = 0; e < 48; ++e)
            attnw[((size_t)bh * 48 + tid) * 48 + e] = expf(S[tid][e] - mx) * inv;
    }
}

// ---------------- fuse Wattn @ blockdiag(attn) ----------------
__global__ __launch_bounds__(192) void k_wfuse(const float* __restrict__ wattn,
    const float* __restrict__ attnw, unsigned short* __restrict__ wf)
{
    int co = blockIdx.x, b = blockIdx.y;
    int ce = threadIdx.x;
    int h = ce / 48, e = ce - h * 48;
    const float* wrow = wattn + (size_t)co * 192 + h * 48;
    const float* arow = attnw + ((size_t)(b * 4 + h) * 48) * 48 + e;
    float acc = 0.f;
#pragma unroll 8
    for (int d = 0; d < 48; ++d)
        acc += wrow[d] * arow[(size_t)d * 48];
    wf[((size_t)b * 192 + co) * 192 + ce] = f2b(acc);
}

// ---------------- launcher ----------------
extern "C" void kernel_launch(void* const* d_in, const int* in_sizes, int n_in,
                              void* d_out, int out_size, void* d_ws, size_t ws_size,
                              hipStream_t stream)
{
    const float* x     = (const float*)d_in[0];
    const float* ln1g  = (const float*)d_in[1];
    const float* ln1b  = (const float*)d_in[2];
    const float* ln2g  = (const float*)d_in[3];
    const float* ln2b  = (const float*)d_in[4];
    const float* temp  = (const float*)d_in[5];
    const float* wqkv  = (const float*)d_in[6];
    const float* wqkvd = (const float*)d_in[7];
    const float* w5    = (const float*)d_in[8];
    const float* w7    = (const float*)d_in[9];
    const float* w9    = (const float*)d_in[10];
    const float* wattn = (const float*)d_in[11];
    const float* wffni = (const float*)d_in[12];
    const float* wffnd = (const float*)d_in[13];
    const float* wffno = (const float*)d_in[14];
    float* out = (float*)d_out;

    char* ws = (char*)d_ws;
    unsigned short* xnT = (unsigned short*)(ws + 0);              // 25.2MB (later xn2T)
    unsigned short* xnb = (unsigned short*)(ws + 25165824);       // 25.2MB (later vT/y12)
    unsigned short* q = (unsigned short*)(ws + 75497472);         // 25.2MB
    unsigned short* kvb = (unsigned short*)(ws + 100663296);      // 50.3MB
    unsigned short* bfilt = (unsigned short*)(ws + 100663296);    // bf16 (dead before kvb)
    unsigned short* rowbuf = (unsigned short*)(ws + 154189824);   // 27MB bf16, 72-padded
    unsigned short* kvtmp384 = (unsigned short*)(ws + 154189824); // 50.3MB (rowbuf dead)
    const size_t SM = 226492416;
    float* rq2   = (float*)(ws + SM);
    float* rk2   = (float*)(ws + SM + 4096);
    float* rq    = (float*)(ws + SM + 8192);
    float* rk    = (float*)(ws + SM + 12288);
    float* pS    = (float*)(ws + SM + 16384);                     // aliased by attnw
    float* attnw = pS;
    unsigned short* wq_b  = (unsigned short*)(ws + SM + 2375680);
    unsigned short* wfi_b = (unsigned short*)(ws + SM + 2523136); // [y1ck0|y2ck0|y1ck1|y2ck1]
    unsigned short* wfo_b = (unsigned short*)(ws + SM + 2916352);
    unsigned short* wf_b  = (unsigned short*)(ws + SM + 3112960);
    const size_t NEED = SM + 3407872;
    if (ws_size < NEED) return;

    unsigned short* vT   = xnb;
    unsigned short* y12  = (unsigned short*)(ws + 25165824);
    unsigned short* gg   = (unsigned short*)(ws + 92274688);
    unsigned short* gTb  = (unsigned short*)(ws + 125829120);     // [b][px][512]

    dim3 blk(256);

    // 0. weights -> bf16; zero norm accumulators
    hipMemsetAsync(ws + SM, 0, 8192, stream);
    k_wconv<<<288, blk, 0, stream>>>(wqkv, wq_b, 384, 192, 192, 73728);
    k_wconv<<<192, blk, 0, stream>>>(wffni, wfi_b, 256, 192, 192, 49152);
    k_wconv<<<192, blk, 0, stream>>>(wffni + (size_t)510 * 192, wfi_b + 256 * 192, 256, 192, 192, 49152);
    k_wconv<<<192, blk, 0, stream>>>(wffni + (size_t)256 * 192, wfi_b + 512 * 192, 254, 192, 192, 49152);
    k_wconv<<<192, blk, 0, stream>>>(wffni + (size_t)766 * 192, wfi_b + 768 * 192, 254, 192, 192, 49152);
    k_wconv<<<384, blk, 0, stream>>>(wffno, wfo_b, 192, 510, 512, 98304);

    // 1. LN1 -> xnb bf16 spatial + xnT bf16 transposed
    k_ln<1><<<256, blk, 0, stream>>>(x, ln1g, ln1b, xnb, xnT);

    // 2. SSL
    k_dwt_row<<<768, blk, 0, stream>>>(xnb, rowbuf);
    k_dwt_colconv<<<dim3(2, CCH, BB), blk, 0, stream>>>(rowbuf, w5, w7, w9, bfilt);
    k_idwt2<<<dim3(8, CCH, BB), blk, 0, stream>>>(bfilt, q, rq2);

    // 3. kv = dw3x3(conv1x1(xn, w_qkv))
    k_gemmT<1, 0, 192, 192, 128><<<dim3(128, 3, BB), blk, 0, stream>>>(xnT, wq_b, kvtmp384, nullptr, 384, 0);
    k_dw8<1><<<dim3(8, 192, BB), blk, 0, stream>>>(kvtmp384, wqkvd, kvb, rk2, 384, 0, 384, 0);
    k_dw8<0><<<dim3(8, 192, BB), blk, 0, stream>>>(kvtmp384, wqkvd + 192 * 9, kvb, nullptr, 384, 192, 384, 192);

    // 4. attention weights + fused output weight
    k_fnorm<<<6, blk, 0, stream>>>(rq2, rk2, rq, rk);
    k_qk_mfma<<<dim3(16, 16), blk, 0, stream>>>(q, kvb, pS);
    k_attn_soft<<<16, blk, 0, stream>>>(pS, rq, rk, temp, attnw);
    k_wfuse<<<dim3(192, 4), 192, 0, stream>>>(wattn, attnw, wf_b);

    // 5. d_out = x + (Wattn @ BDattn) @ V
    k_transT<192><<<dim3(256, 1, BB), blk, 0, stream>>>(kvb, vT, 384, 192, 192, 0);
    k_gemmT<0, 1, 192, 192, 192><<<dim3(128, 1, BB), blk, 0, stream>>>(vT, wf_b, out, x, 192, 36864);

    // 6. xn2T = LN2(d_out)
    k_ln<0><<<256, blk, 0, stream>>>(out, ln2g, ln2b, nullptr, xnT);

    // 7. GDFN
    for (int ck = 0; ck < 2; ++ck) {
        int validc = (ck == 0) ? 256 : 254;
        k_gemmT<1, 0, 192, 192, 128><<<dim3(128, 4, BB), blk, 0, stream>>>(xnT, wfi_b + (size_t)(ck * 512) * 192,
                                                                           y12, nullptr, 512, 0);
        k_dw8gate<<<dim3(8, 256, BB), blk, 0, stream>>>(y12, wffnd + (size_t)(ck * 256) * 9,
                                                        wffnd + (size_t)(510 + ck * 256) * 9, gg, validc);
        k_transT<256><<<dim3(256, 1, BB), blk, 0, stream>>>(gg, gTb, 256, 0, 512, ck * 256);
    }
    k_gemmT<0, 1, 512, 512, 192><<<dim3(128, 1, BB), blk, 0, stream>>>(gTb, wfo_b, out, out, 192, 0);
}

// Round 12
// 468.932 us; speedup vs baseline: 1.4805x; 1.1163x over previous
//
#include <hip/hip_runtime.h>
#include <math.h>

#define HWSZ 16384
#define WID 128
#define HEI 128
#define CCH 192
#define BB 4

typedef short v8s __attribute__((ext_vector_type(8)));
typedef float f32x4 __attribute__((ext_vector_type(4)));

__device__ __constant__ float c_lo[6] = {0.035226291882100656f, -0.08544127388224149f, -0.13501102001039084f,
                                         0.4598775021193313f, 0.8068915093133388f, 0.3326705529509569f};
__device__ __constant__ float c_hi[6] = {-0.3326705529509569f, 0.8068915093133388f, -0.4598775021193313f,
                                         -0.13501102001039084f, 0.08544127388224149f, 0.035226291882100656f};

__device__ __forceinline__ float b2f(unsigned short h) { return __uint_as_float(((unsigned int)h) << 16); }
__device__ __forceinline__ unsigned short f2b(float f) {
    unsigned int u = __float_as_uint(f);
    return (unsigned short)((u + 0x7fffu + ((u >> 16) & 1u)) >> 16);
}
__device__ __forceinline__ unsigned int pk2(float a, float b) {
    return (unsigned int)f2b(a) | ((unsigned int)f2b(b) << 16);
}

// async global->LDS, 16B per lane; LDS dest is wave-uniform base + lane*16
__device__ __forceinline__ void gl2lds16(const void* g, void* l) {
    __builtin_amdgcn_global_load_lds((const __attribute__((address_space(1))) unsigned int*)g,
                                     (__attribute__((address_space(3))) unsigned int*)l, 16, 0, 0);
}

// ---------------- weight fp32 -> bf16 with row/col zero-pad ----------------
__global__ __launch_bounds__(256) void k_wconv(const float* __restrict__ src,
    unsigned short* __restrict__ dst, int rows, int cols, int dcols, int total)
{
    int i = blockIdx.x * 256 + threadIdx.x;
    if (i >= total) return;
    int r = i / dcols, c = i - r * dcols;
    float v = (c < cols && r < rows) ? src[r * cols + c] : 0.f;
    dst[i] = f2b(v);
}

// ---------------- LayerNorm v2: block = 64px, 4 ch-groups of 48; regs hold values ----------------
template<int WRITE_SP>
__global__ __launch_bounds__(256) void k_ln2(const float* __restrict__ x,
    const float* __restrict__ gw, const float* __restrict__ bta,
    unsigned short* __restrict__ xsp, unsigned short* __restrict__ xT)
{
    __shared__ float ps[2][4][64];
    int t = threadIdx.x;
    int pxl = t & 63, g = t >> 6;
    int blk = blockIdx.x;
    int b = blk >> 8;
    int px = ((blk & 255) << 6) + pxl;
    int c0 = g * 48;
    const float* xp = x + (size_t)b * CCH * HWSZ + px;
    float v[48];
    float s = 0.f, s2 = 0.f;
#pragma unroll
    for (int i = 0; i < 48; ++i) {
        float vv = xp[(size_t)(c0 + i) * HWSZ];
        v[i] = vv;
        s += vv; s2 += vv * vv;
    }
    ps[0][g][pxl] = s; ps[1][g][pxl] = s2;
    __syncthreads();
    float ts = ps[0][0][pxl] + ps[0][1][pxl] + ps[0][2][pxl] + ps[0][3][pxl];
    float ts2 = ps[1][0][pxl] + ps[1][1][pxl] + ps[1][2][pxl] + ps[1][3][pxl];
    float mu = ts * (1.f / CCH);
    float var = ts2 * (1.f / CCH) - mu * mu;
    float rs = rsqrtf(var + 1e-5f);
    unsigned short* sp = xsp + (size_t)b * CCH * HWSZ + px;
    unsigned short* tr = xT + ((size_t)b * HWSZ + px) * CCH + c0;
#pragma unroll
    for (int i = 0; i < 48; ++i) {
        float vv = (v[i] - mu) * rs * gw[c0 + i] + bta[c0 + i];
        v[i] = vv;
        if (WRITE_SP) sp[(size_t)(c0 + i) * HWSZ] = f2b(vv);
    }
#pragma unroll
    for (int q = 0; q < 6; ++q) {
        uint4 u;
        u.x = pk2(v[q * 8 + 0], v[q * 8 + 1]);
        u.y = pk2(v[q * 8 + 2], v[q * 8 + 3]);
        u.z = pk2(v[q * 8 + 4], v[q * 8 + 5]);
        u.w = pk2(v[q * 8 + 6], v[q * 8 + 7]);
        *(uint4*)(tr + q * 8) = u;
    }
}

// ---------------- LDS-staged GEMM (m97 structure): tile BM co x 128 px, BK=64 ----------------
template<int OUT_BF16, int ADD, int K, int LDW, int BM>
__global__ __launch_bounds__(256) void k_gemmT(
    const unsigned short* __restrict__ X, const unsigned short* __restrict__ W,
    void* __restrict__ outp, const float* __restrict__ addsrc,
    int Mtot, int wstrideB)
{
    constexpr int FI = BM / 32;
    constexpr int CO = BM / 2;
    __shared__ char smem[BM * 128 + 16384];
    unsigned short* Wt = (unsigned short*)smem;
    unsigned short* Xt = Wt + BM * 64;
    float* epi = (float*)smem;

    int lane = threadIdx.x & 63, wv = threadIdx.x >> 6;
    int wr = wv >> 1, wc = wv & 1;
    int r = lane & 15, koct = lane >> 4;
    int lr = lane >> 3, lc = lane & 7;
    int b = blockIdx.z;
    int pxb = blockIdx.x * 128;
    int co0 = blockIdx.y * BM;

    const unsigned short* Wbase = W + (size_t)b * wstrideB;
    const unsigned short* Xbase = X + (size_t)b * HWSZ * K;

    f32x4 z = {0.f, 0.f, 0.f, 0.f};
    f32x4 acc[FI][4];
#pragma unroll
    for (int i = 0; i < FI; ++i)
#pragma unroll
        for (int j = 0; j < 4; ++j) acc[i][j] = z;

    for (int kt = 0; kt < K / 64; ++kt) {
        int k0 = kt * 64;
#pragma unroll
        for (int m = 0; m < FI; ++m) {
            int rowb = (wv * FI + m) * 8;
            gl2lds16(Wbase + (size_t)(co0 + rowb + lr) * LDW + k0 + lc * 8, Wt + rowb * 64);
        }
#pragma unroll
        for (int m = 0; m < 4; ++m) {
            int rowb = (wv * 4 + m) * 8;
            gl2lds16(Xbase + (size_t)(pxb + rowb + lr) * K + k0 + lc * 8, Xt + rowb * 64);
        }
        __syncthreads();
#pragma unroll
        for (int ks = 0; ks < 2; ++ks) {
            v8s bfr[4];
#pragma unroll
            for (int j = 0; j < 4; ++j)
                bfr[j] = *(const v8s*)(Xt + (wc * 64 + j * 16 + r) * 64 + ks * 32 + koct * 8);
#pragma unroll
            for (int i = 0; i < FI; ++i) {
                v8s af = *(const v8s*)(Wt + (wr * CO + i * 16 + r) * 64 + ks * 32 + koct * 8);
#pragma unroll
                for (int j = 0; j < 4; ++j)
                    acc[i][j] = __builtin_amdgcn_mfma_f32_16x16x32_bf16(af, bfr[j], acc[i][j], 0, 0, 0);
            }
        }
        __syncthreads();
    }

    int cl = lane >> 3, p4 = lc * 4;
    float* ew = epi + wv * 1152;
#pragma unroll
    for (int ig = 0; ig < FI / 2; ++ig) {
#pragma unroll
        for (int p = 0; p < 2; ++p) {
            __syncthreads();
#pragma unroll
            for (int f = 0; f < 2; ++f)
#pragma unroll
                for (int jh = 0; jh < 2; ++jh)
#pragma unroll
                    for (int jj = 0; jj < 4; ++jj)
                        ew[(f * 16 + koct * 4 + jj) * 36 + jh * 16 + r] = acc[ig * 2 + f][p * 2 + jh][jj];
            __syncthreads();
#pragma unroll
            for (int cg = 0; cg < 4; ++cg) {
                int co_l = cg * 8 + cl;
                const float* lrow = ew + co_l * 36 + p4;
                float v0 = lrow[0], v1 = lrow[1], v2 = lrow[2], v3 = lrow[3];
                int co = co0 + wr * CO + ig * 32 + co_l;
                size_t oi = ((size_t)b * Mtot + co) * HWSZ + pxb + wc * 64 + p * 32 + p4;
                if (ADD) {
                    float4 a = *(const float4*)(addsrc + oi);
                    v0 += a.x; v1 += a.y; v2 += a.z; v3 += a.w;
                }
                if (OUT_BF16) {
                    uint2 u;
                    u.x = pk2(v0, v1); u.y = pk2(v2, v3);
                    *(uint2*)((unsigned short*)outp + oi) = u;
                } else {
                    float4 f4 = {v0, v1, v2, v3};
                    *(float4*)((float*)outp + oi) = f4;
                }
            }
        }
    }
}

// ---------------- depthwise helpers ----------------
__device__ __forceinline__ void dw_load_tile(const unsigned short* __restrict__ ip,
    int r0, float (&tile)[18][132], int tid)
{
    for (int e = tid; e < 576; e += 256) {
        int r = e >> 5, q4 = e & 31;
        int gr = r0 - 1 + r;
        float v0 = 0.f, v1 = 0.f, v2 = 0.f, v3 = 0.f;
        if (gr >= 0 && gr < HEI) {
            uint2 u = *(const uint2*)(ip + gr * WID + q4 * 4);
            const unsigned short* pu = (const unsigned short*)&u;
            v0 = b2f(pu[0]); v1 = b2f(pu[1]); v2 = b2f(pu[2]); v3 = b2f(pu[3]);
        }
        int cb = 1 + q4 * 4;
        tile[r][cb] = v0; tile[r][cb + 1] = v1; tile[r][cb + 2] = v2; tile[r][cb + 3] = v3;
    }
    if (tid < 18) { tile[tid][0] = 0.f; tile[tid][129] = 0.f; }
}

__device__ __forceinline__ void dw_compute8(const float (&tile)[18][132],
    const float* wr, int rl, int px0, float (&o)[8])
{
    float r0[10], r1[10], r2[10];
#pragma unroll
    for (int i = 0; i < 10; ++i) {
        r0[i] = tile[rl][px0 + i];
        r1[i] = tile[rl + 1][px0 + i];
        r2[i] = tile[rl + 2][px0 + i];
    }
#pragma unroll
    for (int j = 0; j < 8; ++j) {
        o[j] = r0[j] * wr[0] + r0[j + 1] * wr[1] + r0[j + 2] * wr[2]
             + r1[j] * wr[3] + r1[j + 1] * wr[4] + r1[j + 2] * wr[5]
             + r2[j] * wr[6] + r2[j + 1] * wr[7] + r2[j + 2] * wr[8];
    }
}

// ---------------- depthwise 3x3 bf16; opt k^2 reduce ----------------
template<int REDUCE>
__global__ __launch_bounds__(256) void k_dw8(const unsigned short* __restrict__ in,
    const float* __restrict__ w, unsigned short* __restrict__ out, float* __restrict__ red,
    int inCtot, int inCoff, int outCtot, int outCoff)
{
    __shared__ float tile[18][132];
    int g = blockIdx.x, c = blockIdx.y, b = blockIdx.z;
    int tid = threadIdx.x;
    const unsigned short* ip = in + (size_t)(b * inCtot + inCoff + c) * HWSZ;
    dw_load_tile(ip, g * 16, tile, tid);
    float wr[9];
#pragma unroll
    for (int j = 0; j < 9; ++j) wr[j] = w[c * 9 + j];
    __syncthreads();
    int rl = tid >> 4, px0 = (tid & 15) * 8;
    float o[8];
    dw_compute8(tile, wr, rl, px0, o);
    unsigned short* op = out + (size_t)(b * outCtot + outCoff + c) * HWSZ + (g * 16 + rl) * WID + px0;
    uint4 u;
    u.x = pk2(o[0], o[1]); u.y = pk2(o[2], o[3]); u.z = pk2(o[4], o[5]); u.w = pk2(o[6], o[7]);
    *(uint4*)op = u;
    if (REDUCE) {
        float s = 0.f;
#pragma unroll
        for (int j = 0; j < 8; ++j) s += o[j] * o[j];
        for (int off = 32; off; off >>= 1) s += __shfl_down(s, off, 64);
        __shared__ float w4[4];
        if ((tid & 63) == 0) w4[tid >> 6] = s;
        __syncthreads();
        if (tid == 0) atomicAdd(red + b * CCH + c, w4[0] + w4[1] + w4[2] + w4[3]);
    }
}

// ---------------- fused FFN: dw3x3(y1), dw3x3(y2), gelu(a)*b ----------------
__global__ __launch_bounds__(256) void k_dw8gate(const unsigned short* __restrict__ y12,
    const float* __restrict__ w1, const float* __restrict__ w2,
    unsigned short* __restrict__ out, int validc)
{
    __shared__ float t1[18][132];
    __shared__ float t2[18][132];
    int g = blockIdx.x, c = blockIdx.y, b = blockIdx.z;
    int tid = threadIdx.x;
    const unsigned short* i1 = y12 + (size_t)(b * 512 + c) * HWSZ;
    const unsigned short* i2 = y12 + (size_t)(b * 512 + 256 + c) * HWSZ;
    dw_load_tile(i1, g * 16, t1, tid);
    dw_load_tile(i2, g * 16, t2, tid);
    bool vc = (c < validc);
    float wr1[9], wr2[9];
#pragma unroll
    for (int j = 0; j < 9; ++j) {
        wr1[j] = vc ? w1[c * 9 + j] : 0.f;
        wr2[j] = vc ? w2[c * 9 + j] : 0.f;
    }
    __syncthreads();
    int rl = tid >> 4, px0 = (tid & 15) * 8;
    float a[8], bg[8];
    dw_compute8(t1, wr1, rl, px0, a);
    dw_compute8(t2, wr2, rl, px0, bg);
    float o[8];
#pragma unroll
    for (int j = 0; j < 8; ++j)
        o[j] = 0.5f * a[j] * (1.f + erff(a[j] * 0.70710678118654752f)) * bg[j];
    unsigned short* op = out + (size_t)(b * 256 + c) * HWSZ + (g * 16 + rl) * WID + px0;
    uint4 u;
    u.x = pk2(o[0], o[1]); u.y = pk2(o[2], o[3]); u.z = pk2(o[4], o[5]); u.w = pk2(o[6], o[7]);
    *(uint4*)op = u;
}

// ---------------- transpose [b][*][HW] -> [b][px][ldo] bf16, XOR swizzle ----------------
template<int CT>
__global__ __launch_bounds__(256) void k_transT(const unsigned short* __restrict__ in,
    unsigned short* __restrict__ outT, int inCtot, int inCoff, int ldo, int coff)
{
    __shared__ unsigned short lt[64 * CT];
    const int NG = CT / 8;
    int px0 = blockIdx.x * 64, b = blockIdx.z;
    for (int idx = threadIdx.x; idx < 8 * CT; idx += 256) {
        int ch = idx >> 3, chunk = idx & 7;
        uint4 u = *(const uint4*)(in + ((size_t)(b * inCtot + inCoff + ch)) * HWSZ + px0 + chunk * 8);
        const unsigned short* pu = (const unsigned short*)&u;
        int gq = ch >> 3, j = ch & 7;
#pragma unroll
        for (int i = 0; i < 8; ++i) {
            int row = chunk * 8 + i;
            int gs = gq ^ (row >> 3);
            lt[row * CT + gs * 8 + j] = pu[i];
        }
    }
    __syncthreads();
    for (int idx = threadIdx.x; idx < 8 * CT; idx += 256) {
        int px = idx / NG, cc = idx - px * NG;
        int gs = cc ^ (px >> 3);
        uint4 v = *(const uint4*)&lt[px * CT + gs * 8];
        *(uint4*)(outT + ((size_t)b * HWSZ + px0 + px) * ldo + coff + cc * 8) = v;
    }
}

// ---------------- DWT row pass (bf16 in/out, 72-padded rows) ----------------
__global__ __launch_bounds__(256) void k_dwt_row(const unsigned short* __restrict__ xnb,
    unsigned short* __restrict__ rowbuf)
{
    int bc = blockIdx.x;
    const unsigned short* ip = xnb + (size_t)bc * HWSZ;
    unsigned short* lo = rowbuf + (size_t)bc * 9216;
    unsigned short* hi = rowbuf + (size_t)(768 + bc) * 9216;
    for (int idx = threadIdx.x; idx < 128 * 66; idx += 256) {
        int row = idx / 66, ow = idx - row * 66;
        const unsigned short* rp = ip + row * 128;
        int base = 2 * ow - 4;
        float v[6];
#pragma unroll
        for (int j = 0; j < 6; ++j) {
            int iw = base + j;
            v[j] = (iw >= 0 && iw < 128) ? b2f(rp[iw]) : 0.f;
        }
        float lv = 0.f, hv = 0.f;
#pragma unroll
        for (int j = 0; j < 6; ++j) {
            lv += v[j] * c_lo[5 - j];
            hv += v[j] * c_hi[5 - j];
        }
        lo[row * 72 + ow] = f2b(lv); hi[row * 72 + ow] = f2b(hv);
    }
}

// ---------------- DWT col pass + band 3x3 dwconv ----------------
__global__ __launch_bounds__(256) void k_dwt_colconv(const unsigned short* __restrict__ rowbuf,
    const float* __restrict__ w5, const float* __restrict__ w7, const float* __restrict__ w9,
    unsigned short* __restrict__ bfilt)
{
    __shared__ unsigned short rb[136][72];
    __shared__ float bnd[68][68];
    int h = blockIdx.x, c = blockIdx.y, b = blockIdx.z;
    int tid = threadIdx.x;
    int bc = b * CCH + c;
    const unsigned short* src = rowbuf + (size_t)(h * 768 + bc) * 9216;
    for (int e = tid; e < 1224; e += 256) {
        int r = e / 9, qd = e - r * 9;
        int gr = r - 4;
        uint4 u = make_uint4(0, 0, 0, 0);
        if (gr >= 0 && gr < 128) u = *(const uint4*)(src + gr * 72 + qd * 8);
        *(uint4*)&rb[r][qd * 8] = u;
    }
    for (int e = tid; e < 268; e += 256) {
        int rr, cc;
        if (e < 68) { rr = 0; cc = e; }
        else if (e < 136) { rr = 67; cc = e - 68; }
        else if (e < 202) { rr = e - 135; cc = 0; }
        else { rr = e - 201; cc = 67; }
        bnd[rr][cc] = 0.f;
    }
    __syncthreads();
    for (int fs = 0; fs < 2; ++fs) {
        int band = fs * 2 + h;
        const float* fa = fs ? c_hi : c_lo;
        float f5[6];
#pragma unroll
        for (int j = 0; j < 6; ++j) f5[j] = fa[5 - j];
        for (int i = tid; i < 4356; i += 256) {
            int oh = i / 66, ow = i - oh * 66;
            float a = 0.f;
#pragma unroll
            for (int ki = 0; ki < 6; ++ki)
                a += f5[ki] * b2f(rb[oh * 2 + ki][ow]);
            bnd[oh + 1][ow + 1] = a;
        }
        __syncthreads();
        const float* wsel = (band < 2) ? w5 : (band == 2 ? w7 : w9);
        float wr[9];
#pragma unroll
        for (int j = 0; j < 9; ++j) wr[j] = wsel[c * 9 + j];
        unsigned short* op = bfilt + ((size_t)bc * 4 + band) * 4356;
        for (int i = tid; i < 2178; i += 256) {
            int oh = i / 33, p2 = i - oh * 33;
            int ow0 = p2 * 2;
            float t[3][4];
#pragma unroll
            for (int dy = 0; dy < 3; ++dy)
#pragma unroll
                for (int dx = 0; dx < 4; ++dx)
                    t[dy][dx] = bnd[oh + dy][ow0 + dx];
            float o0 = t[0][0] * wr[0] + t[0][1] * wr[1] + t[0][2] * wr[2]
                     + t[1][0] * wr[3] + t[1][1] * wr[4] + t[1][2] * wr[5]
                     + t[2][0] * wr[6] + t[2][1] * wr[7] + t[2][2] * wr[8];
            float o1 = t[0][1] * wr[0] + t[0][2] * wr[1] + t[0][3] * wr[2]
                     + t[1][1] * wr[3] + t[1][2] * wr[4] + t[1][3] * wr[5]
                     + t[2][1] * wr[6] + t[2][2] * wr[7] + t[2][3] * wr[8];
            *(unsigned int*)(op + oh * 66 + ow0) = pk2(o0, o1);
        }
        __syncthreads();
    }
}

// ---------------- fused IDWT over 4 bands + q^2 reduce ----------------
__global__ __launch_bounds__(256) void k_idwt2(const unsigned short* __restrict__ bfilt,
    unsigned short* __restrict__ q, float* __restrict__ rq2)
{
    __shared__ float L[4][10][68];
    __shared__ float w4[4];
    int g = blockIdx.x;
    int c = blockIdx.y, b = blockIdx.z;
    int tid = threadIdx.x;
    int bc = b * CCH + c;
    const unsigned short* bp = bfilt + (size_t)bc * 4 * 4356;
    for (int e = tid; e < 1320; e += 256) {
        int idx = e * 2;
        int band = idx / 660, rem = idx - band * 660;
        int rr = rem / 66, cc = rem - rr * 66;
        unsigned int u = *(const unsigned int*)(bp + band * 4356 + (8 * g + rr) * 66 + cc);
        L[band][rr][cc] = b2f((unsigned short)(u & 0xffffu));
        L[band][rr][cc + 1] = b2f((unsigned short)(u >> 16));
    }
    __syncthreads();
    int rl = tid >> 4, px0 = (tid & 15) * 8;
    int oh = 16 * g + rl;
    int Tl = rl >> 1, pr = rl & 1;
    int mb = px0 >> 1;
    float acc[8];
#pragma unroll
    for (int j = 0; j < 8; ++j) acc[j] = 0.f;
#pragma unroll
    for (int band = 0; band < 4; ++band) {
        const float* fv = (band < 2) ? c_lo : c_hi;
        const float* fh = (band & 1) ? c_hi : c_lo;
        float fv3[3] = {fv[1 - pr], fv[3 - pr], fv[5 - pr]};
        float fhe[3] = {fh[1], fh[3], fh[5]};
        float fho[3] = {fh[0], fh[2], fh[4]};
#pragma unroll
        for (int i = 0; i < 3; ++i) {
            float r6[6];
#pragma unroll
            for (int m = 0; m < 6; ++m) r6[m] = L[band][Tl + i][mb + m];
#pragma unroll
            for (int jj = 0; jj < 4; ++jj) {
                float se = fhe[0] * r6[jj] + fhe[1] * r6[jj + 1] + fhe[2] * r6[jj + 2];
                float so = fho[0] * r6[jj] + fho[1] * r6[jj + 1] + fho[2] * r6[jj + 2];
                acc[2 * jj]     += fv3[i] * se;
                acc[2 * jj + 1] += fv3[i] * so;
            }
        }
    }
    unsigned short* op = q + (size_t)bc * HWSZ + oh * WID + px0;
    uint4 u;
    u.x = pk2(acc[0], acc[1]); u.y = pk2(acc[2], acc[3]);
    u.z = pk2(acc[4], acc[5]); u.w = pk2(acc[6], acc[7]);
    *(uint4*)op = u;
    float s = 0.f;
#pragma unroll
    for (int j = 0; j < 8; ++j) s += acc[j] * acc[j];
    for (int off = 32; off; off >>= 1) s += __shfl_down(s, off, 64);
    if ((tid & 63) == 0) w4[tid >> 6] = s;
    __syncthreads();
    if (tid == 0) atomicAdd(rq2 + bc, w4[0] + w4[1] + w4[2] + w4[3]);
}

// ---------------- finalize norms ----------------
__global__ __launch_bounds__(256) void k_fnorm(const float* __restrict__ rq2,
    const float* __restrict__ rk2, float* __restrict__ rq, float* __restrict__ rk)
{
    int i = blockIdx.x * 256 + threadIdx.x;
    if (i < 768) rq[i] = 1.f / fmaxf(sqrtf(rq2[i]), 1e-12f);
    else if (i < 1536) rk[i - 768] = 1.f / fmaxf(sqrtf(rk2[i - 768]), 1e-12f);
}

// ---------------- QK^T via MFMA ----------------
__global__ __launch_bounds__(256) void k_qk_mfma(const unsigned short* __restrict__ q,
    const unsigned short* __restrict__ kv, float* __restrict__ pS)
{
    __shared__ float red[4][2304];
    int slice = blockIdx.x, bh = blockIdx.y;
    int b = bh >> 2, h = bh & 3;
    int wv = threadIdx.x >> 6, lane = threadIdx.x & 63;
    int r = lane & 15, koct = lane >> 4;
    const unsigned short* qb = q + (size_t)(b * CCH + h * 48) * HWSZ;
    const unsigned short* kb = kv + (size_t)(b * 384 + h * 48) * HWSZ;
    int n0 = slice * 1024 + wv * 256 + koct * 8;
    f32x4 z = {0.f, 0.f, 0.f, 0.f};
    f32x4 acc[3][3];
#pragma unroll
    for (int i = 0; i < 3; ++i)
#pragma unroll
        for (int j = 0; j < 3; ++j) acc[i][j] = z;
#pragma unroll
    for (int step = 0; step < 8; ++step) {
        int n = n0 + step * 32;
        v8s qf[3], kf[3];
#pragma unroll
        for (int i = 0; i < 3; ++i) {
            qf[i] = *(const v8s*)(qb + (size_t)(16 * i + r) * HWSZ + n);
            kf[i] = *(const v8s*)(kb + (size_t)(16 * i + r) * HWSZ + n);
        }
#pragma unroll
        for (int i = 0; i < 3; ++i)
#pragma unroll
            for (int j = 0; j < 3; ++j)
                acc[i][j] = __builtin_amdgcn_mfma_f32_16x16x32_bf16(qf[i], kf[j], acc[i][j], 0, 0, 0);
    }
#pragma unroll
    for (int i = 0; i < 3; ++i)
#pragma unroll
        for (int j = 0; j < 3; ++j)
#pragma unroll
            for (int jj = 0; jj < 4; ++jj)
                red[wv][(16 * i + koct * 4 + jj) * 48 + 16 * j + r] = acc[i][j][jj];
    __syncthreads();
    float* ps = pS + (size_t)(slice * 16 + bh) * 2304;
    for (int e = threadIdx.x; e < 2304; e += 256)
        ps[e] = red[0][e] + red[1][e] + red[2][e] + red[3][e];
}

// ---------------- reduce partials, scale, softmax ----------------
__global__ __launch_bounds__(256) void k_attn_soft(const float* __restrict__ pS,
    const float* __restrict__ rq, const float* __restrict__ rk,
    const float* __restrict__ temp, float* __restrict__ attnw)
{
    int bh = blockIdx.x; int b = bh >> 2, h = bh & 3;
    __shared__ float S[48][49];
    int tid = threadIdx.x, dt = tid >> 4, et = tid & 15;
    float tv = temp[h];
#pragma unroll
    for (int i = 0; i < 3; ++i) {
#pragma unroll
        for (int j = 0; j < 3; ++j) {
            int d = dt + 16 * i, e = et + 16 * j;
            float s = 0.f;
            for (int sl = 0; sl < 16; ++sl)
                s += pS[(size_t)(sl * 16 + bh) * 2304 + d * 48 + e];
            S[d][e] = s * tv * rq[b * CCH + h * 48 + d] * rk[b * CCH + h * 48 + e];
        }
    }
    __syncthreads();
    if (tid < 48) {
        float mx = -1e30f;
        for (int e = 0; e < 48; ++e) mx = fmaxf(mx, S[tid][e]);
        float sum = 0.f;
        for (int e = 0; e < 48; ++e) sum += expf(S[tid][e] - mx);
        float inv = 1.f / sum;
        for (int e = 0; e < 48; ++e)
            attnw[((size_t)bh * 48 + tid) * 48 + e] = expf(S[tid][e] - mx) * inv;
    }
}

// ---------------- fuse Wattn @ blockdiag(attn) ----------------
__global__ __launch_bounds__(192) void k_wfuse(const float* __restrict__ wattn,
    const float* __restrict__ attnw, unsigned short* __restrict__ wf)
{
    int co = blockIdx.x, b = blockIdx.y;
    int ce = threadIdx.x;
    int h = ce / 48, e = ce - h * 48;
    const float* wrow = wattn + (size_t)co * 192 + h * 48;
    const float* arow = attnw + ((size_t)(b * 4 + h) * 48) * 48 + e;
    float acc = 0.f;
#pragma unroll 8
    for (int d = 0; d < 48; ++d)
        acc += wrow[d] * arow[(size_t)d * 48];
    wf[((size_t)b * 192 + co) * 192 + ce] = f2b(acc);
}

// ---------------- launcher ----------------
extern "C" void kernel_launch(void* const* d_in, const int* in_sizes, int n_in,
                              void* d_out, int out_size, void* d_ws, size_t ws_size,
                              hipStream_t stream)
{
    const float* x     = (const float*)d_in[0];
    const float* ln1g  = (const float*)d_in[1];
    const float* ln1b  = (const float*)d_in[2];
    const float* ln2g  = (const float*)d_in[3];
    const float* ln2b  = (const float*)d_in[4];
    const float* temp  = (const float*)d_in[5];
    const float* wqkv  = (const float*)d_in[6];
    const float* wqkvd = (const float*)d_in[7];
    const float* w5    = (const float*)d_in[8];
    const float* w7    = (const float*)d_in[9];
    const float* w9    = (const float*)d_in[10];
    const float* wattn = (const float*)d_in[11];
    const float* wffni = (const float*)d_in[12];
    const float* wffnd = (const float*)d_in[13];
    const float* wffno = (const float*)d_in[14];
    float* out = (float*)d_out;

    char* ws = (char*)d_ws;
    unsigned short* xnT = (unsigned short*)(ws + 0);              // 25.2MB (later xn2T)
    unsigned short* xnb = (unsigned short*)(ws + 25165824);       // 25.2MB (later vT/y12)
    unsigned short* q = (unsigned short*)(ws + 75497472);         // 25.2MB
    unsigned short* kvb = (unsigned short*)(ws + 100663296);      // 50.3MB
    unsigned short* bfilt = (unsigned short*)(ws + 100663296);    // bf16 (dead before kvb)
    unsigned short* rowbuf = (unsigned short*)(ws + 154189824);   // 27MB bf16, 72-padded
    unsigned short* kvtmp384 = (unsigned short*)(ws + 154189824); // 50.3MB (rowbuf dead)
    const size_t SM = 226492416;
    float* rq2   = (float*)(ws + SM);
    float* rk2   = (float*)(ws + SM + 4096);
    float* rq    = (float*)(ws + SM + 8192);
    float* rk    = (float*)(ws + SM + 12288);
    float* pS    = (float*)(ws + SM + 16384);                     // aliased by attnw
    float* attnw = pS;
    unsigned short* wq_b  = (unsigned short*)(ws + SM + 2375680);
    unsigned short* wfi_b = (unsigned short*)(ws + SM + 2523136); // [y1ck0|y2ck0|y1ck1|y2ck1]
    unsigned short* wfo_b = (unsigned short*)(ws + SM + 2916352);
    unsigned short* wf_b  = (unsigned short*)(ws + SM + 3112960);
    const size_t NEED = SM + 3407872;
    if (ws_size < NEED) return;

    unsigned short* vT   = xnb;
    unsigned short* y12  = (unsigned short*)(ws + 25165824);
    unsigned short* gg   = (unsigned short*)(ws + 92274688);
    unsigned short* gTb  = (unsigned short*)(ws + 125829120);     // [b][px][512]

    dim3 blk(256);

    // 0. weights -> bf16; zero norm accumulators
    hipMemsetAsync(ws + SM, 0, 8192, stream);
    k_wconv<<<288, blk, 0, stream>>>(wqkv, wq_b, 384, 192, 192, 73728);
    k_wconv<<<192, blk, 0, stream>>>(wffni, wfi_b, 256, 192, 192, 49152);
    k_wconv<<<192, blk, 0, stream>>>(wffni + (size_t)510 * 192, wfi_b + 256 * 192, 256, 192, 192, 49152);
    k_wconv<<<192, blk, 0, stream>>>(wffni + (size_t)256 * 192, wfi_b + 512 * 192, 254, 192, 192, 49152);
    k_wconv<<<192, blk, 0, stream>>>(wffni + (size_t)766 * 192, wfi_b + 768 * 192, 254, 192, 192, 49152);
    k_wconv<<<384, blk, 0, stream>>>(wffno, wfo_b, 192, 510, 512, 98304);

    // 1. LN1 -> xnb bf16 spatial + xnT bf16 transposed
    k_ln2<1><<<1024, blk, 0, stream>>>(x, ln1g, ln1b, xnb, xnT);

    // 2. SSL
    k_dwt_row<<<768, blk, 0, stream>>>(xnb, rowbuf);
    k_dwt_colconv<<<dim3(2, CCH, BB), blk, 0, stream>>>(rowbuf, w5, w7, w9, bfilt);
    k_idwt2<<<dim3(8, CCH, BB), blk, 0, stream>>>(bfilt, q, rq2);

    // 3. kv = dw3x3(conv1x1(xn, w_qkv))
    k_gemmT<1, 0, 192, 192, 128><<<dim3(128, 3, BB), blk, 0, stream>>>(xnT, wq_b, kvtmp384, nullptr, 384, 0);
    k_dw8<1><<<dim3(8, 192, BB), blk, 0, stream>>>(kvtmp384, wqkvd, kvb, rk2, 384, 0, 384, 0);
    k_dw8<0><<<dim3(8, 192, BB), blk, 0, stream>>>(kvtmp384, wqkvd + 192 * 9, kvb, nullptr, 384, 192, 384, 192);

    // 4. attention weights + fused output weight
    k_fnorm<<<6, blk, 0, stream>>>(rq2, rk2, rq, rk);
    k_qk_mfma<<<dim3(16, 16), blk, 0, stream>>>(q, kvb, pS);
    k_attn_soft<<<16, blk, 0, stream>>>(pS, rq, rk, temp, attnw);
    k_wfuse<<<dim3(192, 4), 192, 0, stream>>>(wattn, attnw, wf_b);

    // 5. d_out = x + (Wattn @ BDattn) @ V
    k_transT<192><<<dim3(256, 1, BB), blk, 0, stream>>>(kvb, vT, 384, 192, 192, 0);
    k_gemmT<0, 1, 192, 192, 192><<<dim3(128, 1, BB), blk, 0, stream>>>(vT, wf_b, out, x, 192, 36864);

    // 6. xn2T = LN2(d_out)
    k_ln2<0><<<1024, blk, 0, stream>>>(out, ln2g, ln2b, nullptr, xnT);

    // 7. GDFN
    for (int ck = 0; ck < 2; ++ck) {
        int validc = (ck == 0) ? 256 : 254;
        k_gemmT<1, 0, 192, 192, 128><<<dim3(128, 4, BB), blk, 0, stream>>>(xnT, wfi_b + (size_t)(ck * 512) * 192,
                                                                           y12, nullptr, 512, 0);
        k_dw8gate<<<dim3(8, 256, BB), blk, 0, stream>>>(y12, wffnd + (size_t)(ck * 256) * 9,
                                                        wffnd + (size_t)(510 + ck * 256) * 9, gg, validc);
        k_transT<256><<<dim3(256, 1, BB), blk, 0, stream>>>(gg, gTb, 256, 0, 512, ck * 256);
    }
    k_gemmT<0, 1, 512, 512, 192><<<dim3(128, 1, BB), blk, 0, stream>>>(gTb, wfo_b, out, out, 192, 0);
}

// Round 13
// 443.657 us; speedup vs baseline: 1.5649x; 1.0570x over previous
//
#include <hip/hip_runtime.h>
#include <math.h>

#define HWSZ 16384
#define WID 128
#define HEI 128
#define CCH 192
#define BB 4

typedef short v8s __attribute__((ext_vector_type(8)));
typedef float f32x4 __attribute__((ext_vector_type(4)));

__device__ __constant__ float c_lo[6] = {0.035226291882100656f, -0.08544127388224149f, -0.13501102001039084f,
                                         0.4598775021193313f, 0.8068915093133388f, 0.3326705529509569f};
__device__ __constant__ float c_hi[6] = {-0.3326705529509569f, 0.8068915093133388f, -0.4598775021193313f,
                                         -0.13501102001039084f, 0.08544127388224149f, 0.035226291882100656f};

__device__ __forceinline__ float b2f(unsigned short h) { return __uint_as_float(((unsigned int)h) << 16); }
__device__ __forceinline__ unsigned short f2b(float f) {
    unsigned int u = __float_as_uint(f);
    return (unsigned short)((u + 0x7fffu + ((u >> 16) & 1u)) >> 16);
}
__device__ __forceinline__ unsigned int pk2(float a, float b) {
    return (unsigned int)f2b(a) | ((unsigned int)f2b(b) << 16);
}

// async global->LDS, 16B per lane; LDS dest is wave-uniform base + lane*16
__device__ __forceinline__ void gl2lds16(const void* g, void* l) {
    __builtin_amdgcn_global_load_lds((const __attribute__((address_space(1))) unsigned int*)g,
                                     (__attribute__((address_space(3))) unsigned int*)l, 16, 0, 0);
}

// ---------------- weight fp32 -> bf16 with row/col zero-pad ----------------
__global__ __launch_bounds__(256) void k_wconv(const float* __restrict__ src,
    unsigned short* __restrict__ dst, int rows, int cols, int dcols, int total)
{
    int i = blockIdx.x * 256 + threadIdx.x;
    if (i >= total) return;
    int r = i / dcols, c = i - r * dcols;
    float v = (c < cols && r < rows) ? src[r * cols + c] : 0.f;
    dst[i] = f2b(v);
}

// ---------------- LayerNorm v2: block = 64px, 4 ch-groups of 48 ----------------
template<int WRITE_SP>
__global__ __launch_bounds__(256) void k_ln2(const float* __restrict__ x,
    const float* __restrict__ gw, const float* __restrict__ bta,
    unsigned short* __restrict__ xsp, unsigned short* __restrict__ xT)
{
    __shared__ float ps[2][4][64];
    int t = threadIdx.x;
    int pxl = t & 63, g = t >> 6;
    int blk = blockIdx.x;
    int b = blk >> 8;
    int px = ((blk & 255) << 6) + pxl;
    int c0 = g * 48;
    const float* xp = x + (size_t)b * CCH * HWSZ + px;
    float v[48];
    float s = 0.f, s2 = 0.f;
#pragma unroll
    for (int i = 0; i < 48; ++i) {
        float vv = xp[(size_t)(c0 + i) * HWSZ];
        v[i] = vv;
        s += vv; s2 += vv * vv;
    }
    ps[0][g][pxl] = s; ps[1][g][pxl] = s2;
    __syncthreads();
    float ts = ps[0][0][pxl] + ps[0][1][pxl] + ps[0][2][pxl] + ps[0][3][pxl];
    float ts2 = ps[1][0][pxl] + ps[1][1][pxl] + ps[1][2][pxl] + ps[1][3][pxl];
    float mu = ts * (1.f / CCH);
    float var = ts2 * (1.f / CCH) - mu * mu;
    float rs = rsqrtf(var + 1e-5f);
    unsigned short* sp = xsp + (size_t)b * CCH * HWSZ + px;
    unsigned short* tr = xT + ((size_t)b * HWSZ + px) * CCH + c0;
#pragma unroll
    for (int i = 0; i < 48; ++i) {
        float vv = (v[i] - mu) * rs * gw[c0 + i] + bta[c0 + i];
        v[i] = vv;
        if (WRITE_SP) sp[(size_t)(c0 + i) * HWSZ] = f2b(vv);
    }
#pragma unroll
    for (int q = 0; q < 6; ++q) {
        uint4 u;
        u.x = pk2(v[q * 8 + 0], v[q * 8 + 1]);
        u.y = pk2(v[q * 8 + 2], v[q * 8 + 3]);
        u.z = pk2(v[q * 8 + 4], v[q * 8 + 5]);
        u.w = pk2(v[q * 8 + 6], v[q * 8 + 7]);
        *(uint4*)(tr + q * 8) = u;
    }
}

// ---------------- LDS-staged GEMM (m97 structure + T2 swizzle): tile BM co x 128 px, BK=64 ----------------
// Swizzle (rule #21): linear LDS dest, inverse-swizzled global SOURCE, swizzled READ.
// LDS slot (row, granule g) holds global granule g ^ (row&7); read granule = gk ^ (row&7).
template<int OUT_BF16, int ADD, int K, int LDW, int BM>
__global__ __launch_bounds__(256) void k_gemmT(
    const unsigned short* __restrict__ X, const unsigned short* __restrict__ W,
    void* __restrict__ outp, const float* __restrict__ addsrc,
    int Mtot, int wstrideB)
{
    constexpr int FI = BM / 32;
    constexpr int CO = BM / 2;
    __shared__ char smem[BM * 128 + 16384];
    unsigned short* Wt = (unsigned short*)smem;
    unsigned short* Xt = Wt + BM * 64;
    float* epi = (float*)smem;

    int lane = threadIdx.x & 63, wv = threadIdx.x >> 6;
    int wr = wv >> 1, wc = wv & 1;
    int r = lane & 15, koct = lane >> 4;
    int lr = lane >> 3, lc = lane & 7;
    int b = blockIdx.z;
    int pxb = blockIdx.x * 128;
    int co0 = blockIdx.y * BM;

    const unsigned short* Wbase = W + (size_t)b * wstrideB;
    const unsigned short* Xbase = X + (size_t)b * HWSZ * K;

    f32x4 z = {0.f, 0.f, 0.f, 0.f};
    f32x4 acc[FI][4];
#pragma unroll
    for (int i = 0; i < FI; ++i)
#pragma unroll
        for (int j = 0; j < 4; ++j) acc[i][j] = z;

    int sg = (lc ^ lr) * 8;   // inverse-swizzled source granule
    for (int kt = 0; kt < K / 64; ++kt) {
        int k0 = kt * 64;
#pragma unroll
        for (int m = 0; m < FI; ++m) {
            int rowb = (wv * FI + m) * 8;
            gl2lds16(Wbase + (size_t)(co0 + rowb + lr) * LDW + k0 + sg, Wt + rowb * 64);
        }
#pragma unroll
        for (int m = 0; m < 4; ++m) {
            int rowb = (wv * 4 + m) * 8;
            gl2lds16(Xbase + (size_t)(pxb + rowb + lr) * K + k0 + sg, Xt + rowb * 64);
        }
        __syncthreads();
#pragma unroll
        for (int ks = 0; ks < 2; ++ks) {
            int rg = ((ks * 4 + koct) ^ (r & 7)) * 8;   // swizzled read granule
            v8s bfr[4];
#pragma unroll
            for (int j = 0; j < 4; ++j)
                bfr[j] = *(const v8s*)(Xt + (wc * 64 + j * 16 + r) * 64 + rg);
#pragma unroll
            for (int i = 0; i < FI; ++i) {
                v8s af = *(const v8s*)(Wt + (wr * CO + i * 16 + r) * 64 + rg);
#pragma unroll
                for (int j = 0; j < 4; ++j)
                    acc[i][j] = __builtin_amdgcn_mfma_f32_16x16x32_bf16(af, bfr[j], acc[i][j], 0, 0, 0);
            }
        }
        __syncthreads();
    }

    int cl = lane >> 3, p4 = lc * 4;
    float* ew = epi + wv * 1152;
#pragma unroll
    for (int ig = 0; ig < FI / 2; ++ig) {
#pragma unroll
        for (int p = 0; p < 2; ++p) {
            __syncthreads();
#pragma unroll
            for (int f = 0; f < 2; ++f)
#pragma unroll
                for (int jh = 0; jh < 2; ++jh)
#pragma unroll
                    for (int jj = 0; jj < 4; ++jj)
                        ew[(f * 16 + koct * 4 + jj) * 36 + jh * 16 + r] = acc[ig * 2 + f][p * 2 + jh][jj];
            __syncthreads();
#pragma unroll
            for (int cg = 0; cg < 4; ++cg) {
                int co_l = cg * 8 + cl;
                const float* lrow = ew + co_l * 36 + p4;
                float v0 = lrow[0], v1 = lrow[1], v2 = lrow[2], v3 = lrow[3];
                int co = co0 + wr * CO + ig * 32 + co_l;
                size_t oi = ((size_t)b * Mtot + co) * HWSZ + pxb + wc * 64 + p * 32 + p4;
                if (ADD) {
                    float4 a = *(const float4*)(addsrc + oi);
                    v0 += a.x; v1 += a.y; v2 += a.z; v3 += a.w;
                }
                if (OUT_BF16) {
                    uint2 u;
                    u.x = pk2(v0, v1); u.y = pk2(v2, v3);
                    *(uint2*)((unsigned short*)outp + oi) = u;
                } else {
                    float4 f4 = {v0, v1, v2, v3};
                    *(float4*)((float*)outp + oi) = f4;
                }
            }
        }
    }
}

// ---------------- depthwise helpers ----------------
__device__ __forceinline__ void dw_load_tile(const unsigned short* __restrict__ ip,
    int r0, float (&tile)[18][132], int tid)
{
    for (int e = tid; e < 576; e += 256) {
        int r = e >> 5, q4 = e & 31;
        int gr = r0 - 1 + r;
        float v0 = 0.f, v1 = 0.f, v2 = 0.f, v3 = 0.f;
        if (gr >= 0 && gr < HEI) {
            uint2 u = *(const uint2*)(ip + gr * WID + q4 * 4);
            const unsigned short* pu = (const unsigned short*)&u;
            v0 = b2f(pu[0]); v1 = b2f(pu[1]); v2 = b2f(pu[2]); v3 = b2f(pu[3]);
        }
        int cb = 1 + q4 * 4;
        tile[r][cb] = v0; tile[r][cb + 1] = v1; tile[r][cb + 2] = v2; tile[r][cb + 3] = v3;
    }
    if (tid < 18) { tile[tid][0] = 0.f; tile[tid][129] = 0.f; }
}

__device__ __forceinline__ void dw_compute8(const float (&tile)[18][132],
    const float* wr, int rl, int px0, float (&o)[8])
{
    float r0[10], r1[10], r2[10];
#pragma unroll
    for (int i = 0; i < 10; ++i) {
        r0[i] = tile[rl][px0 + i];
        r1[i] = tile[rl + 1][px0 + i];
        r2[i] = tile[rl + 2][px0 + i];
    }
#pragma unroll
    for (int j = 0; j < 8; ++j) {
        o[j] = r0[j] * wr[0] + r0[j + 1] * wr[1] + r0[j + 2] * wr[2]
             + r1[j] * wr[3] + r1[j + 1] * wr[4] + r1[j + 2] * wr[5]
             + r2[j] * wr[6] + r2[j + 1] * wr[7] + r2[j + 2] * wr[8];
    }
}

// ---------------- depthwise 3x3 bf16; opt k^2 reduce ----------------
template<int REDUCE>
__global__ __launch_bounds__(256) void k_dw8(const unsigned short* __restrict__ in,
    const float* __restrict__ w, unsigned short* __restrict__ out, float* __restrict__ red,
    int inCtot, int inCoff, int outCtot, int outCoff)
{
    __shared__ float tile[18][132];
    int g = blockIdx.x, c = blockIdx.y, b = blockIdx.z;
    int tid = threadIdx.x;
    const unsigned short* ip = in + (size_t)(b * inCtot + inCoff + c) * HWSZ;
    dw_load_tile(ip, g * 16, tile, tid);
    float wr[9];
#pragma unroll
    for (int j = 0; j < 9; ++j) wr[j] = w[c * 9 + j];
    __syncthreads();
    int rl = tid >> 4, px0 = (tid & 15) * 8;
    float o[8];
    dw_compute8(tile, wr, rl, px0, o);
    unsigned short* op = out + (size_t)(b * outCtot + outCoff + c) * HWSZ + (g * 16 + rl) * WID + px0;
    uint4 u;
    u.x = pk2(o[0], o[1]); u.y = pk2(o[2], o[3]); u.z = pk2(o[4], o[5]); u.w = pk2(o[6], o[7]);
    *(uint4*)op = u;
    if (REDUCE) {
        float s = 0.f;
#pragma unroll
        for (int j = 0; j < 8; ++j) s += o[j] * o[j];
        for (int off = 32; off; off >>= 1) s += __shfl_down(s, off, 64);
        __shared__ float w4[4];
        if ((tid & 63) == 0) w4[tid >> 6] = s;
        __syncthreads();
        if (tid == 0) atomicAdd(red + b * CCH + c, w4[0] + w4[1] + w4[2] + w4[3]);
    }
}

// ---------------- fused FFN: dw3x3(y1), dw3x3(y2), gelu(a)*b (tanh-form gelu) ----------------
__global__ __launch_bounds__(256) void k_dw8gate(const unsigned short* __restrict__ y12,
    const float* __restrict__ w1, const float* __restrict__ w2,
    unsigned short* __restrict__ out, int validc)
{
    __shared__ float t1[18][132];
    __shared__ float t2[18][132];
    int g = blockIdx.x, c = blockIdx.y, b = blockIdx.z;
    int tid = threadIdx.x;
    const unsigned short* i1 = y12 + (size_t)(b * 512 + c) * HWSZ;
    const unsigned short* i2 = y12 + (size_t)(b * 512 + 256 + c) * HWSZ;
    dw_load_tile(i1, g * 16, t1, tid);
    dw_load_tile(i2, g * 16, t2, tid);
    bool vc = (c < validc);
    float wr1[9], wr2[9];
#pragma unroll
    for (int j = 0; j < 9; ++j) {
        wr1[j] = vc ? w1[c * 9 + j] : 0.f;
        wr2[j] = vc ? w2[c * 9 + j] : 0.f;
    }
    __syncthreads();
    int rl = tid >> 4, px0 = (tid & 15) * 8;
    float a[8], bg[8];
    dw_compute8(t1, wr1, rl, px0, a);
    dw_compute8(t2, wr2, rl, px0, bg);
    float o[8];
#pragma unroll
    for (int j = 0; j < 8; ++j) {
        float xx = a[j];
        float zz = 1.5957691216f * (xx + 0.044715f * xx * xx * xx);
        float sg = 1.f / (1.f + __expf(-zz));
        o[j] = xx * sg * bg[j];
    }
    unsigned short* op = out + (size_t)(b * 256 + c) * HWSZ + (g * 16 + rl) * WID + px0;
    uint4 u;
    u.x = pk2(o[0], o[1]); u.y = pk2(o[2], o[3]); u.z = pk2(o[4], o[5]); u.w = pk2(o[6], o[7]);
    *(uint4*)op = u;
}

// ---------------- transpose [b][*][HW] -> [b][px][ldo] bf16, XOR swizzle ----------------
template<int CT>
__global__ __launch_bounds__(256) void k_transT(const unsigned short* __restrict__ in,
    unsigned short* __restrict__ outT, int inCtot, int inCoff, int ldo, int coff)
{
    __shared__ unsigned short lt[64 * CT];
    const int NG = CT / 8;
    int px0 = blockIdx.x * 64, b = blockIdx.z;
    for (int idx = threadIdx.x; idx < 8 * CT; idx += 256) {
        int ch = idx >> 3, chunk = idx & 7;
        uint4 u = *(const uint4*)(in + ((size_t)(b * inCtot + inCoff + ch)) * HWSZ + px0 + chunk * 8);
        const unsigned short* pu = (const unsigned short*)&u;
        int gq = ch >> 3, j = ch & 7;
#pragma unroll
        for (int i = 0; i < 8; ++i) {
            int row = chunk * 8 + i;
            int gs = gq ^ (row >> 3);
            lt[row * CT + gs * 8 + j] = pu[i];
        }
    }
    __syncthreads();
    for (int idx = threadIdx.x; idx < 8 * CT; idx += 256) {
        int px = idx / NG, cc = idx - px * NG;
        int gs = cc ^ (px >> 3);
        uint4 v = *(const uint4*)&lt[px * CT + gs * 8];
        *(uint4*)(outT + ((size_t)b * HWSZ + px0 + px) * ldo + coff + cc * 8) = v;
    }
}

// ---------------- DWT row pass (bf16 in/out, 72-padded rows) ----------------
__global__ __launch_bounds__(256) void k_dwt_row(const unsigned short* __restrict__ xnb,
    unsigned short* __restrict__ rowbuf)
{
    int bc = blockIdx.x;
    const unsigned short* ip = xnb + (size_t)bc * HWSZ;
    unsigned short* lo = rowbuf + (size_t)bc * 9216;
    unsigned short* hi = rowbuf + (size_t)(768 + bc) * 9216;
    for (int idx = threadIdx.x; idx < 128 * 66; idx += 256) {
        int row = idx / 66, ow = idx - row * 66;
        const unsigned short* rp = ip + row * 128;
        int base = 2 * ow - 4;
        float v[6];
#pragma unroll
        for (int j = 0; j < 6; ++j) {
            int iw = base + j;
            v[j] = (iw >= 0 && iw < 128) ? b2f(rp[iw]) : 0.f;
        }
        float lv = 0.f, hv = 0.f;
#pragma unroll
        for (int j = 0; j < 6; ++j) {
            lv += v[j] * c_lo[5 - j];
            hv += v[j] * c_hi[5 - j];
        }
        lo[row * 72 + ow] = f2b(lv); hi[row * 72 + ow] = f2b(hv);
    }
}

// ---------------- DWT col pass + band 3x3 dwconv ----------------
__global__ __launch_bounds__(256) void k_dwt_colconv(const unsigned short* __restrict__ rowbuf,
    const float* __restrict__ w5, const float* __restrict__ w7, const float* __restrict__ w9,
    unsigned short* __restrict__ bfilt)
{
    __shared__ unsigned short rb[136][72];
    __shared__ float bnd[68][68];
    int h = blockIdx.x, c = blockIdx.y, b = blockIdx.z;
    int tid = threadIdx.x;
    int bc = b * CCH + c;
    const unsigned short* src = rowbuf + (size_t)(h * 768 + bc) * 9216;
    for (int e = tid; e < 1224; e += 256) {
        int r = e / 9, qd = e - r * 9;
        int gr = r - 4;
        uint4 u = make_uint4(0, 0, 0, 0);
        if (gr >= 0 && gr < 128) u = *(const uint4*)(src + gr * 72 + qd * 8);
        *(uint4*)&rb[r][qd * 8] = u;
    }
    for (int e = tid; e < 268; e += 256) {
        int rr, cc;
        if (e < 68) { rr = 0; cc = e; }
        else if (e < 136) { rr = 67; cc = e - 68; }
        else if (e < 202) { rr = e - 135; cc = 0; }
        else { rr = e - 201; cc = 67; }
        bnd[rr][cc] = 0.f;
    }
    __syncthreads();
    for (int fs = 0; fs < 2; ++fs) {
        int band = fs * 2 + h;
        const float* fa = fs ? c_hi : c_lo;
        float f5[6];
#pragma unroll
        for (int j = 0; j < 6; ++j) f5[j] = fa[5 - j];
        for (int i = tid; i < 4356; i += 256) {
            int oh = i / 66, ow = i - oh * 66;
            float a = 0.f;
#pragma unroll
            for (int ki = 0; ki < 6; ++ki)
                a += f5[ki] * b2f(rb[oh * 2 + ki][ow]);
            bnd[oh + 1][ow + 1] = a;
        }
        __syncthreads();
        const float* wsel = (band < 2) ? w5 : (band == 2 ? w7 : w9);
        float wr[9];
#pragma unroll
        for (int j = 0; j < 9; ++j) wr[j] = wsel[c * 9 + j];
        unsigned short* op = bfilt + ((size_t)bc * 4 + band) * 4356;
        for (int i = tid; i < 2178; i += 256) {
            int oh = i / 33, p2 = i - oh * 33;
            int ow0 = p2 * 2;
            float t[3][4];
#pragma unroll
            for (int dy = 0; dy < 3; ++dy)
#pragma unroll
                for (int dx = 0; dx < 4; ++dx)
                    t[dy][dx] = bnd[oh + dy][ow0 + dx];
            float o0 = t[0][0] * wr[0] + t[0][1] * wr[1] + t[0][2] * wr[2]
                     + t[1][0] * wr[3] + t[1][1] * wr[4] + t[1][2] * wr[5]
                     + t[2][0] * wr[6] + t[2][1] * wr[7] + t[2][2] * wr[8];
            float o1 = t[0][1] * wr[0] + t[0][2] * wr[1] + t[0][3] * wr[2]
                     + t[1][1] * wr[3] + t[1][2] * wr[4] + t[1][3] * wr[5]
                     + t[2][1] * wr[6] + t[2][2] * wr[7] + t[2][3] * wr[8];
            *(unsigned int*)(op + oh * 66 + ow0) = pk2(o0, o1);
        }
        __syncthreads();
    }
}

// ---------------- fused IDWT over 4 bands + q^2 reduce ----------------
__global__ __launch_bounds__(256) void k_idwt2(const unsigned short* __restrict__ bfilt,
    unsigned short* __restrict__ q, float* __restrict__ rq2)
{
    __shared__ float L[4][10][68];
    __shared__ float w4[4];
    int g = blockIdx.x;
    int c = blockIdx.y, b = blockIdx.z;
    int tid = threadIdx.x;
    int bc = b * CCH + c;
    const unsigned short* bp = bfilt + (size_t)bc * 4 * 4356;
    for (int e = tid; e < 1320; e += 256) {
        int idx = e * 2;
        int band = idx / 660, rem = idx - band * 660;
        int rr = rem / 66, cc = rem - rr * 66;
        unsigned int u = *(const unsigned int*)(bp + band * 4356 + (8 * g + rr) * 66 + cc);
        L[band][rr][cc] = b2f((unsigned short)(u & 0xffffu));
        L[band][rr][cc + 1] = b2f((unsigned short)(u >> 16));
    }
    __syncthreads();
    int rl = tid >> 4, px0 = (tid & 15) * 8;
    int oh = 16 * g + rl;
    int Tl = rl >> 1, pr = rl & 1;
    int mb = px0 >> 1;
    float acc[8];
#pragma unroll
    for (int j = 0; j < 8; ++j) acc[j] = 0.f;
#pragma unroll
    for (int band = 0; band < 4; ++band) {
        const float* fv = (band < 2) ? c_lo : c_hi;
        const float* fh = (band & 1) ? c_hi : c_lo;
        float fv3[3] = {fv[1 - pr], fv[3 - pr], fv[5 - pr]};
        float fhe[3] = {fh[1], fh[3], fh[5]};
        float fho[3] = {fh[0], fh[2], fh[4]};
#pragma unroll
        for (int i = 0; i < 3; ++i) {
            float r6[6];
#pragma unroll
            for (int m = 0; m < 6; ++m) r6[m] = L[band][Tl + i][mb + m];
#pragma unroll
            for (int jj = 0; jj < 4; ++jj) {
                float se = fhe[0] * r6[jj] + fhe[1] * r6[jj + 1] + fhe[2] * r6[jj + 2];
                float so = fho[0] * r6[jj] + fho[1] * r6[jj + 1] + fho[2] * r6[jj + 2];
                acc[2 * jj]     += fv3[i] * se;
                acc[2 * jj + 1] += fv3[i] * so;
            }
        }
    }
    unsigned short* op = q + (size_t)bc * HWSZ + oh * WID + px0;
    uint4 u;
    u.x = pk2(acc[0], acc[1]); u.y = pk2(acc[2], acc[3]);
    u.z = pk2(acc[4], acc[5]); u.w = pk2(acc[6], acc[7]);
    *(uint4*)op = u;
    float s = 0.f;
#pragma unroll
    for (int j = 0; j < 8; ++j) s += acc[j] * acc[j];
    for (int off = 32; off; off >>= 1) s += __shfl_down(s, off, 64);
    if ((tid & 63) == 0) w4[tid >> 6] = s;
    __syncthreads();
    if (tid == 0) atomicAdd(rq2 + bc, w4[0] + w4[1] + w4[2] + w4[3]);
}

// ---------------- finalize norms ----------------
__global__ __launch_bounds__(256) void k_fnorm(const float* __restrict__ rq2,
    const float* __restrict__ rk2, float* __restrict__ rq, float* __restrict__ rk)
{
    int i = blockIdx.x * 256 + threadIdx.x;
    if (i < 768) rq[i] = 1.f / fmaxf(sqrtf(rq2[i]), 1e-12f);
    else if (i < 1536) rk[i - 768] = 1.f / fmaxf(sqrtf(rk2[i - 768]), 1e-12f);
}

// ---------------- QK^T via MFMA ----------------
__global__ __launch_bounds__(256) void k_qk_mfma(const unsigned short* __restrict__ q,
    const unsigned short* __restrict__ kv, float* __restrict__ pS)
{
    __shared__ float red[4][2304];
    int slice = blockIdx.x, bh = blockIdx.y;
    int b = bh >> 2, h = bh & 3;
    int wv = threadIdx.x >> 6, lane = threadIdx.x & 63;
    int r = lane & 15, koct = lane >> 4;
    const unsigned short* qb = q + (size_t)(b * CCH + h * 48) * HWSZ;
    const unsigned short* kb = kv + (size_t)(b * 384 + h * 48) * HWSZ;
    int n0 = slice * 1024 + wv * 256 + koct * 8;
    f32x4 z = {0.f, 0.f, 0.f, 0.f};
    f32x4 acc[3][3];
#pragma unroll
    for (int i = 0; i < 3; ++i)
#pragma unroll
        for (int j = 0; j < 3; ++j) acc[i][j] = z;
#pragma unroll
    for (int step = 0; step < 8; ++step) {
        int n = n0 + step * 32;
        v8s qf[3], kf[3];
#pragma unroll
        for (int i = 0; i < 3; ++i) {
            qf[i] = *(const v8s*)(qb + (size_t)(16 * i + r) * HWSZ + n);
            kf[i] = *(const v8s*)(kb + (size_t)(16 * i + r) * HWSZ + n);
        }
#pragma unroll
        for (int i = 0; i < 3; ++i)
#pragma unroll
            for (int j = 0; j < 3; ++j)
                acc[i][j] = __builtin_amdgcn_mfma_f32_16x16x32_bf16(qf[i], kf[j], acc[i][j], 0, 0, 0);
    }
#pragma unroll
    for (int i = 0; i < 3; ++i)
#pragma unroll
        for (int j = 0; j < 3; ++j)
#pragma unroll
            for (int jj = 0; jj < 4; ++jj)
                red[wv][(16 * i + koct * 4 + jj) * 48 + 16 * j + r] = acc[i][j][jj];
    __syncthreads();
    float* ps = pS + (size_t)(slice * 16 + bh) * 2304;
    for (int e = threadIdx.x; e < 2304; e += 256)
        ps[e] = red[0][e] + red[1][e] + red[2][e] + red[3][e];
}

// ---------------- reduce partials, scale, softmax ----------------
__global__ __launch_bounds__(256) void k_attn_soft(const float* __restrict__ pS,
    const float* __restrict__ rq, const float* __restrict__ rk,
    const float* __restrict__ temp, float* __restrict__ attnw)
{
    int bh = blockIdx.x; int b = bh >> 2, h = bh & 3;
    __shared__ float S[48][49];
    int tid = threadIdx.x, dt = tid >> 4, et = tid & 15;
    float tv = temp[h];
#pragma unroll
    for (int i = 0; i < 3; ++i) {
#pragma unroll
        for (int j = 0; j < 3; ++j) {
            int d = dt + 16 * i, e = et + 16 * j;
            float s = 0.f;
            for (int sl = 0; sl < 16; ++sl)
                s += pS[(size_t)(sl * 16 + bh) * 2304 + d * 48 + e];
            S[d][e] = s * tv * rq[b * CCH + h * 48 + d] * rk[b * CCH + h * 48 + e];
        }
    }
    __syncthreads();
    if (tid < 48) {
        float mx = -1e30f;
        for (int e = 0; e < 48; ++e) mx = fmaxf(mx, S[tid][e]);
        float sum = 0.f;
        for (int e = 0; e < 48; ++e) sum += expf(S[tid][e] - mx);
        float inv = 1.f / sum;
        for (int e = 0; e < 48; ++e)
            attnw[((size_t)bh * 48 + tid) * 48 + e] = expf(S[tid][e] - mx) * inv;
    }
}

// ---------------- fuse Wattn @ blockdiag(attn) ----------------
__global__ __launch_bounds__(192) void k_wfuse(const float* __restrict__ wattn,
    const float* __restrict__ attnw, unsigned short* __restrict__ wf)
{
    int co = blockIdx.x, b = blockIdx.y;
    int ce = threadIdx.x;
    int h = ce / 48, e = ce - h * 48;
    const float* wrow = wattn + (size_t)co * 192 + h * 48;
    const float* arow = attnw + ((size_t)(b * 4 + h) * 48) * 48 + e;
    float acc = 0.f;
#pragma unroll 8
    for (int d = 0; d < 48; ++d)
        acc += wrow[d] * arow[(size_t)d * 48];
    wf[((size_t)b * 192 + co) * 192 + ce] = f2b(acc);
}

// ---------------- launcher ----------------
extern "C" void kernel_launch(void* const* d_in, const int* in_sizes, int n_in,
                              void* d_out, int out_size, void* d_ws, size_t ws_size,
                              hipStream_t stream)
{
    const float* x     = (const float*)d_in[0];
    const float* ln1g  = (const float*)d_in[1];
    const float* ln1b  = (const float*)d_in[2];
    const float* ln2g  = (const float*)d_in[3];
    const float* ln2b  = (const float*)d_in[4];
    const float* temp  = (const float*)d_in[5];
    const float* wqkv  = (const float*)d_in[6];
    const float* wqkvd = (const float*)d_in[7];
    const float* w5    = (const float*)d_in[8];
    const float* w7    = (const float*)d_in[9];
    const float* w9    = (const float*)d_in[10];
    const float* wattn = (const float*)d_in[11];
    const float* wffni = (const float*)d_in[12];
    const float* wffnd = (const float*)d_in[13];
    const float* wffno = (const float*)d_in[14];
    float* out = (float*)d_out;

    char* ws = (char*)d_ws;
    unsigned short* xnT = (unsigned short*)(ws + 0);
    unsigned short* xnb = (unsigned short*)(ws + 25165824);
    unsigned short* q = (unsigned short*)(ws + 75497472);
    unsigned short* kvb = (unsigned short*)(ws + 100663296);
    unsigned short* bfilt = (unsigned short*)(ws + 100663296);
    unsigned short* rowbuf = (unsigned short*)(ws + 154189824);
    unsigned short* kvtmp384 = (unsigned short*)(ws + 154189824);
    const size_t SM = 226492416;
    float* rq2   = (float*)(ws + SM);
    float* rk2   = (float*)(ws + SM + 4096);
    float* rq    = (float*)(ws + SM + 8192);
    float* rk    = (float*)(ws + SM + 12288);
    float* pS    = (float*)(ws + SM + 16384);
    float* attnw = pS;
    unsigned short* wq_b  = (unsigned short*)(ws + SM + 2375680);
    unsigned short* wfi_b = (unsigned short*)(ws + SM + 2523136);
    unsigned short* wfo_b = (unsigned short*)(ws + SM + 2916352);
    unsigned short* wf_b  = (unsigned short*)(ws + SM + 3112960);
    const size_t NEED = SM + 3407872;
    if (ws_size < NEED) return;

    unsigned short* vT   = xnb;
    unsigned short* y12  = (unsigned short*)(ws + 25165824);
    unsigned short* gg   = (unsigned short*)(ws + 92274688);
    unsigned short* gTb  = (unsigned short*)(ws + 125829120);

    dim3 blk(256);

    // 0. weights -> bf16; zero norm accumulators
    hipMemsetAsync(ws + SM, 0, 8192, stream);
    k_wconv<<<288, blk, 0, stream>>>(wqkv, wq_b, 384, 192, 192, 73728);
    k_wconv<<<192, blk, 0, stream>>>(wffni, wfi_b, 256, 192, 192, 49152);
    k_wconv<<<192, blk, 0, stream>>>(wffni + (size_t)510 * 192, wfi_b + 256 * 192, 256, 192, 192, 49152);
    k_wconv<<<192, blk, 0, stream>>>(wffni + (size_t)256 * 192, wfi_b + 512 * 192, 254, 192, 192, 49152);
    k_wconv<<<192, blk, 0, stream>>>(wffni + (size_t)766 * 192, wfi_b + 768 * 192, 254, 192, 192, 49152);
    k_wconv<<<384, blk, 0, stream>>>(wffno, wfo_b, 192, 510, 512, 98304);

    // 1. LN1 -> xnb bf16 spatial + xnT bf16 transposed
    k_ln2<1><<<1024, blk, 0, stream>>>(x, ln1g, ln1b, xnb, xnT);

    // 2. SSL
    k_dwt_row<<<768, blk, 0, stream>>>(xnb, rowbuf);
    k_dwt_colconv<<<dim3(2, CCH, BB), blk, 0, stream>>>(rowbuf, w5, w7, w9, bfilt);
    k_idwt2<<<dim3(8, CCH, BB), blk, 0, stream>>>(bfilt, q, rq2);

    // 3. kv = dw3x3(conv1x1(xn, w_qkv))
    k_gemmT<1, 0, 192, 192, 128><<<dim3(128, 3, BB), blk, 0, stream>>>(xnT, wq_b, kvtmp384, nullptr, 384, 0);
    k_dw8<1><<<dim3(8, 192, BB), blk, 0, stream>>>(kvtmp384, wqkvd, kvb, rk2, 384, 0, 384, 0);
    k_dw8<0><<<dim3(8, 192, BB), blk, 0, stream>>>(kvtmp384, wqkvd + 192 * 9, kvb, nullptr, 384, 192, 384, 192);

    // 4. attention weights + fused output weight
    k_fnorm<<<6, blk, 0, stream>>>(rq2, rk2, rq, rk);
    k_qk_mfma<<<dim3(16, 16), blk, 0, stream>>>(q, kvb, pS);
    k_attn_soft<<<16, blk, 0, stream>>>(pS, rq, rk, temp, attnw);
    k_wfuse<<<dim3(192, 4), 192, 0, stream>>>(wattn, attnw, wf_b);

    // 5. d_out = x + (Wattn @ BDattn) @ V
    k_transT<192><<<dim3(256, 1, BB), blk, 0, stream>>>(kvb, vT, 384, 192, 192, 0);
    k_gemmT<0, 1, 192, 192, 192><<<dim3(128, 1, BB), blk, 0, stream>>>(vT, wf_b, out, x, 192, 36864);

    // 6. xn2T = LN2(d_out)
    k_ln2<0><<<1024, blk, 0, stream>>>(out, ln2g, ln2b, nullptr, xnT);

    // 7. GDFN
    for (int ck = 0; ck < 2; ++ck) {
        int validc = (ck == 0) ? 256 : 254;
        k_gemmT<1, 0, 192, 192, 128><<<dim3(128, 4, BB), blk, 0, stream>>>(xnT, wfi_b + (size_t)(ck * 512) * 192,
                                                                           y12, nullptr, 512, 0);
        k_dw8gate<<<dim3(8, 256, BB), blk, 0, stream>>>(y12, wffnd + (size_t)(ck * 256) * 9,
                                                        wffnd + (size_t)(510 + ck * 256) * 9, gg, validc);
        k_transT<256><<<dim3(256, 1, BB), blk, 0, stream>>>(gg, gTb, 256, 0, 512, ck * 256);
    }
    k_gemmT<0, 1, 512, 512, 192><<<dim3(128, 1, BB), blk, 0, stream>>>(gTb, wfo_b, out, out, 192, 0);
}

// Round 14
// 433.050 us; speedup vs baseline: 1.6032x; 1.0245x over previous
//
#include <hip/hip_runtime.h>
#include <math.h>

#define HWSZ 16384
#define WID 128
#define HEI 128
#define CCH 192
#define BB 4

typedef short v8s __attribute__((ext_vector_type(8)));
typedef float f32x4 __attribute__((ext_vector_type(4)));

__device__ __constant__ float c_lo[6] = {0.035226291882100656f, -0.08544127388224149f, -0.13501102001039084f,
                                         0.4598775021193313f, 0.8068915093133388f, 0.3326705529509569f};
__device__ __constant__ float c_hi[6] = {-0.3326705529509569f, 0.8068915093133388f, -0.4598775021193313f,
                                         -0.13501102001039084f, 0.08544127388224149f, 0.035226291882100656f};

__device__ __forceinline__ float b2f(unsigned short h) { return __uint_as_float(((unsigned int)h) << 16); }
__device__ __forceinline__ unsigned short f2b(float f) {
    unsigned int u = __float_as_uint(f);
    return (unsigned short)((u + 0x7fffu + ((u >> 16) & 1u)) >> 16);
}
__device__ __forceinline__ unsigned int pk2(float a, float b) {
    return (unsigned int)f2b(a) | ((unsigned int)f2b(b) << 16);
}

// async global->LDS, 16B per lane; LDS dest is wave-uniform base + lane*16
__device__ __forceinline__ void gl2lds16(const void* g, void* l) {
    __builtin_amdgcn_global_load_lds((const __attribute__((address_space(1))) unsigned int*)g,
                                     (__attribute__((address_space(3))) unsigned int*)l, 16, 0, 0);
}

// ---------------- weight fp32 -> bf16 with row/col zero-pad ----------------
__global__ __launch_bounds__(256) void k_wconv(const float* __restrict__ src,
    unsigned short* __restrict__ dst, int rows, int cols, int dcols, int total)
{
    int i = blockIdx.x * 256 + threadIdx.x;
    if (i >= total) return;
    int r = i / dcols, c = i - r * dcols;
    float v = (c < cols && r < rows) ? src[r * cols + c] : 0.f;
    dst[i] = f2b(v);
}

// ---------------- LayerNorm v2: block = 64px, 4 ch-groups of 48 ----------------
template<int WRITE_SP>
__global__ __launch_bounds__(256) void k_ln2(const float* __restrict__ x,
    const float* __restrict__ gw, const float* __restrict__ bta,
    unsigned short* __restrict__ xsp, unsigned short* __restrict__ xT)
{
    __shared__ float ps[2][4][64];
    int t = threadIdx.x;
    int pxl = t & 63, g = t >> 6;
    int blk = blockIdx.x;
    int b = blk >> 8;
    int px = ((blk & 255) << 6) + pxl;
    int c0 = g * 48;
    const float* xp = x + (size_t)b * CCH * HWSZ + px;
    float v[48];
    float s = 0.f, s2 = 0.f;
#pragma unroll
    for (int i = 0; i < 48; ++i) {
        float vv = xp[(size_t)(c0 + i) * HWSZ];
        v[i] = vv;
        s += vv; s2 += vv * vv;
    }
    ps[0][g][pxl] = s; ps[1][g][pxl] = s2;
    __syncthreads();
    float ts = ps[0][0][pxl] + ps[0][1][pxl] + ps[0][2][pxl] + ps[0][3][pxl];
    float ts2 = ps[1][0][pxl] + ps[1][1][pxl] + ps[1][2][pxl] + ps[1][3][pxl];
    float mu = ts * (1.f / CCH);
    float var = ts2 * (1.f / CCH) - mu * mu;
    float rs = rsqrtf(var + 1e-5f);
    unsigned short* sp = xsp + (size_t)b * CCH * HWSZ + px;
    unsigned short* tr = xT + ((size_t)b * HWSZ + px) * CCH + c0;
#pragma unroll
    for (int i = 0; i < 48; ++i) {
        float vv = (v[i] - mu) * rs * gw[c0 + i] + bta[c0 + i];
        v[i] = vv;
        if (WRITE_SP) sp[(size_t)(c0 + i) * HWSZ] = f2b(vv);
    }
#pragma unroll
    for (int q = 0; q < 6; ++q) {
        uint4 u;
        u.x = pk2(v[q * 8 + 0], v[q * 8 + 1]);
        u.y = pk2(v[q * 8 + 2], v[q * 8 + 3]);
        u.z = pk2(v[q * 8 + 4], v[q * 8 + 5]);
        u.w = pk2(v[q * 8 + 6], v[q * 8 + 7]);
        *(uint4*)(tr + q * 8) = u;
    }
}

// ---------------- LDS-staged GEMM: tile BM co x 128 px, BK=64, T2 swizzle ----------------
template<int OUT_BF16, int ADD, int K, int LDW, int BM>
__global__ __launch_bounds__(256) void k_gemmT(
    const unsigned short* __restrict__ X, const unsigned short* __restrict__ W,
    void* __restrict__ outp, const float* __restrict__ addsrc,
    int Mtot, int wstrideB)
{
    constexpr int FI = BM / 32;
    constexpr int CO = BM / 2;
    __shared__ char smem[BM * 128 + 16384];
    unsigned short* Wt = (unsigned short*)smem;
    unsigned short* Xt = Wt + BM * 64;
    float* epi = (float*)smem;

    int lane = threadIdx.x & 63, wv = threadIdx.x >> 6;
    int wr = wv >> 1, wc = wv & 1;
    int r = lane & 15, koct = lane >> 4;
    int lr = lane >> 3, lc = lane & 7;
    int b = blockIdx.z;
    int pxb = blockIdx.x * 128;
    int co0 = blockIdx.y * BM;

    const unsigned short* Wbase = W + (size_t)b * wstrideB;
    const unsigned short* Xbase = X + (size_t)b * HWSZ * K;

    f32x4 z = {0.f, 0.f, 0.f, 0.f};
    f32x4 acc[FI][4];
#pragma unroll
    for (int i = 0; i < FI; ++i)
#pragma unroll
        for (int j = 0; j < 4; ++j) acc[i][j] = z;

    int sg = (lc ^ lr) * 8;
    for (int kt = 0; kt < K / 64; ++kt) {
        int k0 = kt * 64;
#pragma unroll
        for (int m = 0; m < FI; ++m) {
            int rowb = (wv * FI + m) * 8;
            gl2lds16(Wbase + (size_t)(co0 + rowb + lr) * LDW + k0 + sg, Wt + rowb * 64);
        }
#pragma unroll
        for (int m = 0; m < 4; ++m) {
            int rowb = (wv * 4 + m) * 8;
            gl2lds16(Xbase + (size_t)(pxb + rowb + lr) * K + k0 + sg, Xt + rowb * 64);
        }
        __syncthreads();
#pragma unroll
        for (int ks = 0; ks < 2; ++ks) {
            int rg = ((ks * 4 + koct) ^ (r & 7)) * 8;
            v8s bfr[4];
#pragma unroll
            for (int j = 0; j < 4; ++j)
                bfr[j] = *(const v8s*)(Xt + (wc * 64 + j * 16 + r) * 64 + rg);
#pragma unroll
            for (int i = 0; i < FI; ++i) {
                v8s af = *(const v8s*)(Wt + (wr * CO + i * 16 + r) * 64 + rg);
#pragma unroll
                for (int j = 0; j < 4; ++j)
                    acc[i][j] = __builtin_amdgcn_mfma_f32_16x16x32_bf16(af, bfr[j], acc[i][j], 0, 0, 0);
            }
        }
        __syncthreads();
    }

    int cl = lane >> 3, p4 = lc * 4;
    float* ew = epi + wv * 1152;
#pragma unroll
    for (int ig = 0; ig < FI / 2; ++ig) {
#pragma unroll
        for (int p = 0; p < 2; ++p) {
            __syncthreads();
#pragma unroll
            for (int f = 0; f < 2; ++f)
#pragma unroll
                for (int jh = 0; jh < 2; ++jh)
#pragma unroll
                    for (int jj = 0; jj < 4; ++jj)
                        ew[(f * 16 + koct * 4 + jj) * 36 + jh * 16 + r] = acc[ig * 2 + f][p * 2 + jh][jj];
            __syncthreads();
#pragma unroll
            for (int cg = 0; cg < 4; ++cg) {
                int co_l = cg * 8 + cl;
                const float* lrow = ew + co_l * 36 + p4;
                float v0 = lrow[0], v1 = lrow[1], v2 = lrow[2], v3 = lrow[3];
                int co = co0 + wr * CO + ig * 32 + co_l;
                size_t oi = ((size_t)b * Mtot + co) * HWSZ + pxb + wc * 64 + p * 32 + p4;
                if (ADD) {
                    float4 a = *(const float4*)(addsrc + oi);
                    v0 += a.x; v1 += a.y; v2 += a.z; v3 += a.w;
                }
                if (OUT_BF16) {
                    uint2 u;
                    u.x = pk2(v0, v1); u.y = pk2(v2, v3);
                    *(uint2*)((unsigned short*)outp + oi) = u;
                } else {
                    float4 f4 = {v0, v1, v2, v3};
                    *(float4*)((float*)outp + oi) = f4;
                }
            }
        }
    }
}

// ---------------- GEMM variant U: M=192, 64-px tile (grid 256,1,B), waves 2x2 = 96co x 32px ----------------
template<int OUT_BF16, int ADD, int K>
__global__ __launch_bounds__(256) void k_gemmU(
    const unsigned short* __restrict__ X, const unsigned short* __restrict__ W,
    void* __restrict__ outp, const float* __restrict__ addsrc, int wstrideB)
{
    __shared__ char smem[32768];
    unsigned short* Wt = (unsigned short*)smem;        // 192 x 64 = 24576B
    unsigned short* Xt = Wt + 192 * 64;                // 64 x 64 = 8192B
    float* epi = (float*)smem;

    int lane = threadIdx.x & 63, wv = threadIdx.x >> 6;
    int wr = wv >> 1, wc = wv & 1;
    int r = lane & 15, koct = lane >> 4;
    int lr = lane >> 3, lc = lane & 7;
    int b = blockIdx.z;
    int pxb = blockIdx.x * 64;

    const unsigned short* Wbase = W + (size_t)b * wstrideB;
    const unsigned short* Xbase = X + (size_t)b * HWSZ * K;

    f32x4 z = {0.f, 0.f, 0.f, 0.f};
    f32x4 acc[6][2];
#pragma unroll
    for (int i = 0; i < 6; ++i) { acc[i][0] = z; acc[i][1] = z; }

    int sg = (lc ^ lr) * 8;
    for (int kt = 0; kt < K / 64; ++kt) {
        int k0 = kt * 64;
#pragma unroll
        for (int m = 0; m < 6; ++m) {
            int rowb = (wv * 6 + m) * 8;
            gl2lds16(Wbase + (size_t)(rowb + lr) * K + k0 + sg, Wt + rowb * 64);
        }
#pragma unroll
        for (int m = 0; m < 2; ++m) {
            int rowb = (wv * 2 + m) * 8;
            gl2lds16(Xbase + (size_t)(pxb + rowb + lr) * K + k0 + sg, Xt + rowb * 64);
        }
        __syncthreads();
#pragma unroll
        for (int ks = 0; ks < 2; ++ks) {
            int rg = ((ks * 4 + koct) ^ (r & 7)) * 8;
            v8s b0 = *(const v8s*)(Xt + (wc * 32 + r) * 64 + rg);
            v8s b1 = *(const v8s*)(Xt + (wc * 32 + 16 + r) * 64 + rg);
#pragma unroll
            for (int i = 0; i < 6; ++i) {
                v8s af = *(const v8s*)(Wt + (wr * 96 + i * 16 + r) * 64 + rg);
                acc[i][0] = __builtin_amdgcn_mfma_f32_16x16x32_bf16(af, b0, acc[i][0], 0, 0, 0);
                acc[i][1] = __builtin_amdgcn_mfma_f32_16x16x32_bf16(af, b1, acc[i][1], 0, 0, 0);
            }
        }
        __syncthreads();
    }

    int cl = lane >> 3, p4 = lc * 4;
    float* ew = epi + wv * 1152;
#pragma unroll
    for (int ig = 0; ig < 3; ++ig) {
        __syncthreads();
#pragma unroll
        for (int f = 0; f < 2; ++f)
#pragma unroll
            for (int jh = 0; jh < 2; ++jh)
#pragma unroll
                for (int jj = 0; jj < 4; ++jj)
                    ew[(f * 16 + koct * 4 + jj) * 36 + jh * 16 + r] = acc[ig * 2 + f][jh][jj];
        __syncthreads();
#pragma unroll
        for (int cg = 0; cg < 4; ++cg) {
            int co_l = cg * 8 + cl;
            const float* lrow = ew + co_l * 36 + p4;
            float v0 = lrow[0], v1 = lrow[1], v2 = lrow[2], v3 = lrow[3];
            int co = wr * 96 + ig * 32 + co_l;
            size_t oi = ((size_t)b * 192 + co) * HWSZ + pxb + wc * 32 + p4;
            if (ADD) {
                float4 a = *(const float4*)(addsrc + oi);
                v0 += a.x; v1 += a.y; v2 += a.z; v3 += a.w;
            }
            if (OUT_BF16) {
                uint2 u;
                u.x = pk2(v0, v1); u.y = pk2(v2, v3);
                *(uint2*)((unsigned short*)outp + oi) = u;
            } else {
                float4 f4 = {v0, v1, v2, v3};
                *(float4*)((float*)outp + oi) = f4;
            }
        }
    }
}

// ---------------- depthwise helpers ----------------
__device__ __forceinline__ void dw_load_tile(const unsigned short* __restrict__ ip,
    int r0, float (&tile)[18][132], int tid)
{
    for (int e = tid; e < 576; e += 256) {
        int r = e >> 5, q4 = e & 31;
        int gr = r0 - 1 + r;
        float v0 = 0.f, v1 = 0.f, v2 = 0.f, v3 = 0.f;
        if (gr >= 0 && gr < HEI) {
            uint2 u = *(const uint2*)(ip + gr * WID + q4 * 4);
            const unsigned short* pu = (const unsigned short*)&u;
            v0 = b2f(pu[0]); v1 = b2f(pu[1]); v2 = b2f(pu[2]); v3 = b2f(pu[3]);
        }
        int cb = 1 + q4 * 4;
        tile[r][cb] = v0; tile[r][cb + 1] = v1; tile[r][cb + 2] = v2; tile[r][cb + 3] = v3;
    }
    if (tid < 18) { tile[tid][0] = 0.f; tile[tid][129] = 0.f; }
}

__device__ __forceinline__ void dw_compute8(const float (&tile)[18][132],
    const float* wr, int rl, int px0, float (&o)[8])
{
    float r0[10], r1[10], r2[10];
#pragma unroll
    for (int i = 0; i < 10; ++i) {
        r0[i] = tile[rl][px0 + i];
        r1[i] = tile[rl + 1][px0 + i];
        r2[i] = tile[rl + 2][px0 + i];
    }
#pragma unroll
    for (int j = 0; j < 8; ++j) {
        o[j] = r0[j] * wr[0] + r0[j + 1] * wr[1] + r0[j + 2] * wr[2]
             + r1[j] * wr[3] + r1[j + 1] * wr[4] + r1[j + 2] * wr[5]
             + r2[j] * wr[6] + r2[j + 1] * wr[7] + r2[j + 2] * wr[8];
    }
}

// ---------------- depthwise 3x3 bf16; opt k^2 reduce ----------------
template<int REDUCE>
__global__ __launch_bounds__(256) void k_dw8(const unsigned short* __restrict__ in,
    const float* __restrict__ w, unsigned short* __restrict__ out, float* __restrict__ red,
    int inCtot, int inCoff, int outCtot, int outCoff)
{
    __shared__ float tile[18][132];
    int g = blockIdx.x, c = blockIdx.y, b = blockIdx.z;
    int tid = threadIdx.x;
    const unsigned short* ip = in + (size_t)(b * inCtot + inCoff + c) * HWSZ;
    dw_load_tile(ip, g * 16, tile, tid);
    float wr[9];
#pragma unroll
    for (int j = 0; j < 9; ++j) wr[j] = w[c * 9 + j];
    __syncthreads();
    int rl = tid >> 4, px0 = (tid & 15) * 8;
    float o[8];
    dw_compute8(tile, wr, rl, px0, o);
    unsigned short* op = out + (size_t)(b * outCtot + outCoff + c) * HWSZ + (g * 16 + rl) * WID + px0;
    uint4 u;
    u.x = pk2(o[0], o[1]); u.y = pk2(o[2], o[3]); u.z = pk2(o[4], o[5]); u.w = pk2(o[6], o[7]);
    *(uint4*)op = u;
    if (REDUCE) {
        float s = 0.f;
#pragma unroll
        for (int j = 0; j < 8; ++j) s += o[j] * o[j];
        for (int off = 32; off; off >>= 1) s += __shfl_down(s, off, 64);
        __shared__ float w4[4];
        if ((tid & 63) == 0) w4[tid >> 6] = s;
        __syncthreads();
        if (tid == 0) atomicAdd(red + b * CCH + c, w4[0] + w4[1] + w4[2] + w4[3]);
    }
}

// ---------------- fused FFN: dw3x3(y1), dw3x3(y2), gelu(a)*b (tanh-form) ----------------
__global__ __launch_bounds__(256) void k_dw8gate(const unsigned short* __restrict__ y12,
    const float* __restrict__ w1, const float* __restrict__ w2,
    unsigned short* __restrict__ out, int validc)
{
    __shared__ float t1[18][132];
    __shared__ float t2[18][132];
    int g = blockIdx.x, c = blockIdx.y, b = blockIdx.z;
    int tid = threadIdx.x;
    const unsigned short* i1 = y12 + (size_t)(b * 512 + c) * HWSZ;
    const unsigned short* i2 = y12 + (size_t)(b * 512 + 256 + c) * HWSZ;
    dw_load_tile(i1, g * 16, t1, tid);
    dw_load_tile(i2, g * 16, t2, tid);
    bool vc = (c < validc);
    float wr1[9], wr2[9];
#pragma unroll
    for (int j = 0; j < 9; ++j) {
        wr1[j] = vc ? w1[c * 9 + j] : 0.f;
        wr2[j] = vc ? w2[c * 9 + j] : 0.f;
    }
    __syncthreads();
    int rl = tid >> 4, px0 = (tid & 15) * 8;
    float a[8], bg[8];
    dw_compute8(t1, wr1, rl, px0, a);
    dw_compute8(t2, wr2, rl, px0, bg);
    float o[8];
#pragma unroll
    for (int j = 0; j < 8; ++j) {
        float xx = a[j];
        float zz = 1.5957691216f * (xx + 0.044715f * xx * xx * xx);
        float sg = 1.f / (1.f + __expf(-zz));
        o[j] = xx * sg * bg[j];
    }
    unsigned short* op = out + (size_t)(b * 256 + c) * HWSZ + (g * 16 + rl) * WID + px0;
    uint4 u;
    u.x = pk2(o[0], o[1]); u.y = pk2(o[2], o[3]); u.z = pk2(o[4], o[5]); u.w = pk2(o[6], o[7]);
    *(uint4*)op = u;
}

// ---------------- transpose [b][*][HW] -> [b][px][ldo] bf16, XOR swizzle ----------------
template<int CT>
__global__ __launch_bounds__(256) void k_transT(const unsigned short* __restrict__ in,
    unsigned short* __restrict__ outT, int inCtot, int inCoff, int ldo, int coff)
{
    __shared__ unsigned short lt[64 * CT];
    const int NG = CT / 8;
    int px0 = blockIdx.x * 64, b = blockIdx.z;
    for (int idx = threadIdx.x; idx < 8 * CT; idx += 256) {
        int ch = idx >> 3, chunk = idx & 7;
        uint4 u = *(const uint4*)(in + ((size_t)(b * inCtot + inCoff + ch)) * HWSZ + px0 + chunk * 8);
        const unsigned short* pu = (const unsigned short*)&u;
        int gq = ch >> 3, j = ch & 7;
#pragma unroll
        for (int i = 0; i < 8; ++i) {
            int row = chunk * 8 + i;
            int gs = gq ^ (row >> 3);
            lt[row * CT + gs * 8 + j] = pu[i];
        }
    }
    __syncthreads();
    for (int idx = threadIdx.x; idx < 8 * CT; idx += 256) {
        int px = idx / NG, cc = idx - px * NG;
        int gs = cc ^ (px >> 3);
        uint4 v = *(const uint4*)&lt[px * CT + gs * 8];
        *(uint4*)(outT + ((size_t)b * HWSZ + px0 + px) * ldo + coff + cc * 8) = v;
    }
}

// ---------------- DWT row pass (bf16 in/out, 72-padded rows) ----------------
__global__ __launch_bounds__(256) void k_dwt_row(const unsigned short* __restrict__ xnb,
    unsigned short* __restrict__ rowbuf)
{
    int bc = blockIdx.x;
    const unsigned short* ip = xnb + (size_t)bc * HWSZ;
    unsigned short* lo = rowbuf + (size_t)bc * 9216;
    unsigned short* hi = rowbuf + (size_t)(768 + bc) * 9216;
    for (int idx = threadIdx.x; idx < 128 * 66; idx += 256) {
        int row = idx / 66, ow = idx - row * 66;
        const unsigned short* rp = ip + row * 128;
        int base = 2 * ow - 4;
        float v[6];
#pragma unroll
        for (int j = 0; j < 6; ++j) {
            int iw = base + j;
            v[j] = (iw >= 0 && iw < 128) ? b2f(rp[iw]) : 0.f;
        }
        float lv = 0.f, hv = 0.f;
#pragma unroll
        for (int j = 0; j < 6; ++j) {
            lv += v[j] * c_lo[5 - j];
            hv += v[j] * c_hi[5 - j];
        }
        lo[row * 72 + ow] = f2b(lv); hi[row * 72 + ow] = f2b(hv);
    }
}

// ---------------- DWT col pass + band 3x3 dwconv ----------------
__global__ __launch_bounds__(256) void k_dwt_colconv(const unsigned short* __restrict__ rowbuf,
    const float* __restrict__ w5, const float* __restrict__ w7, const float* __restrict__ w9,
    unsigned short* __restrict__ bfilt)
{
    __shared__ unsigned short rb[136][72];
    __shared__ float bnd[68][68];
    int h = blockIdx.x, c = blockIdx.y, b = blockIdx.z;
    int tid = threadIdx.x;
    int bc = b * CCH + c;
    const unsigned short* src = rowbuf + (size_t)(h * 768 + bc) * 9216;
    for (int e = tid; e < 1224; e += 256) {
        int r = e / 9, qd = e - r * 9;
        int gr = r - 4;
        uint4 u = make_uint4(0, 0, 0, 0);
        if (gr >= 0 && gr < 128) u = *(const uint4*)(src + gr * 72 + qd * 8);
        *(uint4*)&rb[r][qd * 8] = u;
    }
    for (int e = tid; e < 268; e += 256) {
        int rr, cc;
        if (e < 68) { rr = 0; cc = e; }
        else if (e < 136) { rr = 67; cc = e - 68; }
        else if (e < 202) { rr = e - 135; cc = 0; }
        else { rr = e - 201; cc = 67; }
        bnd[rr][cc] = 0.f;
    }
    __syncthreads();
    for (int fs = 0; fs < 2; ++fs) {
        int band = fs * 2 + h;
        const float* fa = fs ? c_hi : c_lo;
        float f5[6];
#pragma unroll
        for (int j = 0; j < 6; ++j) f5[j] = fa[5 - j];
        for (int i = tid; i < 4356; i += 256) {
            int oh = i / 66, ow = i - oh * 66;
            float a = 0.f;
#pragma unroll
            for (int ki = 0; ki < 6; ++ki)
                a += f5[ki] * b2f(rb[oh * 2 + ki][ow]);
            bnd[oh + 1][ow + 1] = a;
        }
        __syncthreads();
        const float* wsel = (band < 2) ? w5 : (band == 2 ? w7 : w9);
        float wr[9];
#pragma unroll
        for (int j = 0; j < 9; ++j) wr[j] = wsel[c * 9 + j];
        unsigned short* op = bfilt + ((size_t)bc * 4 + band) * 4356;
        for (int i = tid; i < 2178; i += 256) {
            int oh = i / 33, p2 = i - oh * 33;
            int ow0 = p2 * 2;
            float t[3][4];
#pragma unroll
            for (int dy = 0; dy < 3; ++dy)
#pragma unroll
                for (int dx = 0; dx < 4; ++dx)
                    t[dy][dx] = bnd[oh + dy][ow0 + dx];
            float o0 = t[0][0] * wr[0] + t[0][1] * wr[1] + t[0][2] * wr[2]
                     + t[1][0] * wr[3] + t[1][1] * wr[4] + t[1][2] * wr[5]
                     + t[2][0] * wr[6] + t[2][1] * wr[7] + t[2][2] * wr[8];
            float o1 = t[0][1] * wr[0] + t[0][2] * wr[1] + t[0][3] * wr[2]
                     + t[1][1] * wr[3] + t[1][2] * wr[4] + t[1][3] * wr[5]
                     + t[2][1] * wr[6] + t[2][2] * wr[7] + t[2][3] * wr[8];
            *(unsigned int*)(op + oh * 66 + ow0) = pk2(o0, o1);
        }
        __syncthreads();
    }
}

// ---------------- fused IDWT over 4 bands + q^2 reduce ----------------
__global__ __launch_bounds__(256) void k_idwt2(const unsigned short* __restrict__ bfilt,
    unsigned short* __restrict__ q, float* __restrict__ rq2)
{
    __shared__ float L[4][10][68];
    __shared__ float w4[4];
    int g = blockIdx.x;
    int c = blockIdx.y, b = blockIdx.z;
    int tid = threadIdx.x;
    int bc = b * CCH + c;
    const unsigned short* bp = bfilt + (size_t)bc * 4 * 4356;
    for (int e = tid; e < 1320; e += 256) {
        int idx = e * 2;
        int band = idx / 660, rem = idx - band * 660;
        int rr = rem / 66, cc = rem - rr * 66;
        unsigned int u = *(const unsigned int*)(bp + band * 4356 + (8 * g + rr) * 66 + cc);
        L[band][rr][cc] = b2f((unsigned short)(u & 0xffffu));
        L[band][rr][cc + 1] = b2f((unsigned short)(u >> 16));
    }
    __syncthreads();
    int rl = tid >> 4, px0 = (tid & 15) * 8;
    int oh = 16 * g + rl;
    int Tl = rl >> 1, pr = rl & 1;
    int mb = px0 >> 1;
    float acc[8];
#pragma unroll
    for (int j = 0; j < 8; ++j) acc[j] = 0.f;
#pragma unroll
    for (int band = 0; band < 4; ++band) {
        const float* fv = (band < 2) ? c_lo : c_hi;
        const float* fh = (band & 1) ? c_hi : c_lo;
        float fv3[3] = {fv[1 - pr], fv[3 - pr], fv[5 - pr]};
        float fhe[3] = {fh[1], fh[3], fh[5]};
        float fho[3] = {fh[0], fh[2], fh[4]};
#pragma unroll
        for (int i = 0; i < 3; ++i) {
            float r6[6];
#pragma unroll
            for (int m = 0; m < 6; ++m) r6[m] = L[band][Tl + i][mb + m];
#pragma unroll
            for (int jj = 0; jj < 4; ++jj) {
                float se = fhe[0] * r6[jj] + fhe[1] * r6[jj + 1] + fhe[2] * r6[jj + 2];
                float so = fho[0] * r6[jj] + fho[1] * r6[jj + 1] + fho[2] * r6[jj + 2];
                acc[2 * jj]     += fv3[i] * se;
                acc[2 * jj + 1] += fv3[i] * so;
            }
        }
    }
    unsigned short* op = q + (size_t)bc * HWSZ + oh * WID + px0;
    uint4 u;
    u.x = pk2(acc[0], acc[1]); u.y = pk2(acc[2], acc[3]);
    u.z = pk2(acc[4], acc[5]); u.w = pk2(acc[6], acc[7]);
    *(uint4*)op = u;
    float s = 0.f;
#pragma unroll
    for (int j = 0; j < 8; ++j) s += acc[j] * acc[j];
    for (int off = 32; off; off >>= 1) s += __shfl_down(s, off, 64);
    if ((tid & 63) == 0) w4[tid >> 6] = s;
    __syncthreads();
    if (tid == 0) atomicAdd(rq2 + bc, w4[0] + w4[1] + w4[2] + w4[3]);
}

// ---------------- finalize norms ----------------
__global__ __launch_bounds__(256) void k_fnorm(const float* __restrict__ rq2,
    const float* __restrict__ rk2, float* __restrict__ rq, float* __restrict__ rk)
{
    int i = blockIdx.x * 256 + threadIdx.x;
    if (i < 768) rq[i] = 1.f / fmaxf(sqrtf(rq2[i]), 1e-12f);
    else if (i < 1536) rk[i - 768] = 1.f / fmaxf(sqrtf(rk2[i - 768]), 1e-12f);
}

// ---------------- QK^T via MFMA ----------------
__global__ __launch_bounds__(256) void k_qk_mfma(const unsigned short* __restrict__ q,
    const unsigned short* __restrict__ kv, float* __restrict__ pS)
{
    __shared__ float red[4][2304];
    int slice = blockIdx.x, bh = blockIdx.y;
    int b = bh >> 2, h = bh & 3;
    int wv = threadIdx.x >> 6, lane = threadIdx.x & 63;
    int r = lane & 15, koct = lane >> 4;
    const unsigned short* qb = q + (size_t)(b * CCH + h * 48) * HWSZ;
    const unsigned short* kb = kv + (size_t)(b * 384 + h * 48) * HWSZ;
    int n0 = slice * 1024 + wv * 256 + koct * 8;
    f32x4 z = {0.f, 0.f, 0.f, 0.f};
    f32x4 acc[3][3];
#pragma unroll
    for (int i = 0; i < 3; ++i)
#pragma unroll
        for (int j = 0; j < 3; ++j) acc[i][j] = z;
#pragma unroll
    for (int step = 0; step < 8; ++step) {
        int n = n0 + step * 32;
        v8s qf[3], kf[3];
#pragma unroll
        for (int i = 0; i < 3; ++i) {
            qf[i] = *(const v8s*)(qb + (size_t)(16 * i + r) * HWSZ + n);
            kf[i] = *(const v8s*)(kb + (size_t)(16 * i + r) * HWSZ + n);
        }
#pragma unroll
        for (int i = 0; i < 3; ++i)
#pragma unroll
            for (int j = 0; j < 3; ++j)
                acc[i][j] = __builtin_amdgcn_mfma_f32_16x16x32_bf16(qf[i], kf[j], acc[i][j], 0, 0, 0);
    }
#pragma unroll
    for (int i = 0; i < 3; ++i)
#pragma unroll
        for (int j = 0; j < 3; ++j)
#pragma unroll
            for (int jj = 0; jj < 4; ++jj)
                red[wv][(16 * i + koct * 4 + jj) * 48 + 16 * j + r] = acc[i][j][jj];
    __syncthreads();
    float* ps = pS + (size_t)(slice * 16 + bh) * 2304;
    for (int e = threadIdx.x; e < 2304; e += 256)
        ps[e] = red[0][e] + red[1][e] + red[2][e] + red[3][e];
}

// ---------------- reduce partials, scale, softmax ----------------
__global__ __launch_bounds__(256) void k_attn_soft(const float* __restrict__ pS,
    const float* __restrict__ rq, const float* __restrict__ rk,
    const float* __restrict__ temp, float* __restrict__ attnw)
{
    int bh = blockIdx.x; int b = bh >> 2, h = bh & 3;
    __shared__ float S[48][49];
    int tid = threadIdx.x, dt = tid >> 4, et = tid & 15;
    float tv = temp[h];
#pragma unroll
    for (int i = 0; i < 3; ++i) {
#pragma unroll
        for (int j = 0; j < 3; ++j) {
            int d = dt + 16 * i, e = et + 16 * j;
            float s = 0.f;
            for (int sl = 0; sl < 16; ++sl)
                s += pS[(size_t)(sl * 16 + bh) * 2304 + d * 48 + e];
            S[d][e] = s * tv * rq[b * CCH + h * 48 + d] * rk[b * CCH + h * 48 + e];
        }
    }
    __syncthreads();
    if (tid < 48) {
        float mx = -1e30f;
        for (int e = 0; e < 48; ++e) mx = fmaxf(mx, S[tid][e]);
        float sum = 0.f;
        for (int e = 0; e < 48; ++e) sum += expf(S[tid][e] - mx);
        float inv = 1.f / sum;
        for (int e = 0; e < 48; ++e)
            attnw[((size_t)bh * 48 + tid) * 48 + e] = expf(S[tid][e] - mx) * inv;
    }
}

// ---------------- fuse Wattn @ blockdiag(attn) ----------------
__global__ __launch_bounds__(192) void k_wfuse(const float* __restrict__ wattn,
    const float* __restrict__ attnw, unsigned short* __restrict__ wf)
{
    int co = blockIdx.x, b = blockIdx.y;
    int ce = threadIdx.x;
    int h = ce / 48, e = ce - h * 48;
    const float* wrow = wattn + (size_t)co * 192 + h * 48;
    const float* arow = attnw + ((size_t)(b * 4 + h) * 48) * 48 + e;
    float acc = 0.f;
#pragma unroll 8
    for (int d = 0; d < 48; ++d)
        acc += wrow[d] * arow[(size_t)d * 48];
    wf[((size_t)b * 192 + co) * 192 + ce] = f2b(acc);
}

// ---------------- launcher ----------------
extern "C" void kernel_launch(void* const* d_in, const int* in_sizes, int n_in,
                              void* d_out, int out_size, void* d_ws, size_t ws_size,
                              hipStream_t stream)
{
    const float* x     = (const float*)d_in[0];
    const float* ln1g  = (const float*)d_in[1];
    const float* ln1b  = (const float*)d_in[2];
    const float* ln2g  = (const float*)d_in[3];
    const float* ln2b  = (const float*)d_in[4];
    const float* temp  = (const float*)d_in[5];
    const float* wqkv  = (const float*)d_in[6];
    const float* wqkvd = (const float*)d_in[7];
    const float* w5    = (const float*)d_in[8];
    const float* w7    = (const float*)d_in[9];
    const float* w9    = (const float*)d_in[10];
    const float* wattn = (const float*)d_in[11];
    const float* wffni = (const float*)d_in[12];
    const float* wffnd = (const float*)d_in[13];
    const float* wffno = (const float*)d_in[14];
    float* out = (float*)d_out;

    char* ws = (char*)d_ws;
    unsigned short* xnT = (unsigned short*)(ws + 0);
    unsigned short* xnb = (unsigned short*)(ws + 25165824);
    unsigned short* q = (unsigned short*)(ws + 75497472);
    unsigned short* kvb = (unsigned short*)(ws + 100663296);
    unsigned short* bfilt = (unsigned short*)(ws + 100663296);
    unsigned short* rowbuf = (unsigned short*)(ws + 154189824);
    unsigned short* kvtmp384 = (unsigned short*)(ws + 154189824);
    const size_t SM = 226492416;
    float* rq2   = (float*)(ws + SM);
    float* rk2   = (float*)(ws + SM + 4096);
    float* rq    = (float*)(ws + SM + 8192);
    float* rk    = (float*)(ws + SM + 12288);
    float* pS    = (float*)(ws + SM + 16384);
    float* attnw = pS;
    unsigned short* wq_b  = (unsigned short*)(ws + SM + 2375680);
    unsigned short* wfi_b = (unsigned short*)(ws + SM + 2523136);
    unsigned short* wfo_b = (unsigned short*)(ws + SM + 2916352);
    unsigned short* wf_b  = (unsigned short*)(ws + SM + 3112960);
    const size_t NEED = SM + 3407872;
    if (ws_size < NEED) return;

    unsigned short* vT   = xnb;
    unsigned short* y12  = (unsigned short*)(ws + 25165824);
    unsigned short* gg   = (unsigned short*)(ws + 92274688);
    unsigned short* gTb  = (unsigned short*)(ws + 125829120);

    dim3 blk(256);

    // 0. weights -> bf16; zero norm accumulators
    hipMemsetAsync(ws + SM, 0, 8192, stream);
    k_wconv<<<288, blk, 0, stream>>>(wqkv, wq_b, 384, 192, 192, 73728);
    k_wconv<<<192, blk, 0, stream>>>(wffni, wfi_b, 256, 192, 192, 49152);
    k_wconv<<<192, blk, 0, stream>>>(wffni + (size_t)510 * 192, wfi_b + 256 * 192, 256, 192, 192, 49152);
    k_wconv<<<192, blk, 0, stream>>>(wffni + (size_t)256 * 192, wfi_b + 512 * 192, 254, 192, 192, 49152);
    k_wconv<<<192, blk, 0, stream>>>(wffni + (size_t)766 * 192, wfi_b + 768 * 192, 254, 192, 192, 49152);
    k_wconv<<<384, blk, 0, stream>>>(wffno, wfo_b, 192, 510, 512, 98304);

    // 1. LN1 -> xnb bf16 spatial + xnT bf16 transposed
    k_ln2<1><<<1024, blk, 0, stream>>>(x, ln1g, ln1b, xnb, xnT);

    // 2. SSL
    k_dwt_row<<<768, blk, 0, stream>>>(xnb, rowbuf);
    k_dwt_colconv<<<dim3(2, CCH, BB), blk, 0, stream>>>(rowbuf, w5, w7, w9, bfilt);
    k_idwt2<<<dim3(8, CCH, BB), blk, 0, stream>>>(bfilt, q, rq2);

    // 3. kv = dw3x3(conv1x1(xn, w_qkv))
    k_gemmT<1, 0, 192, 192, 128><<<dim3(128, 3, BB), blk, 0, stream>>>(xnT, wq_b, kvtmp384, nullptr, 384, 0);
    k_dw8<1><<<dim3(8, 192, BB), blk, 0, stream>>>(kvtmp384, wqkvd, kvb, rk2, 384, 0, 384, 0);
    k_dw8<0><<<dim3(8, 192, BB), blk, 0, stream>>>(kvtmp384, wqkvd + 192 * 9, kvb, nullptr, 384, 192, 384, 192);

    // 4. attention weights + fused output weight
    k_fnorm<<<6, blk, 0, stream>>>(rq2, rk2, rq, rk);
    k_qk_mfma<<<dim3(16, 16), blk, 0, stream>>>(q, kvb, pS);
    k_attn_soft<<<16, blk, 0, stream>>>(pS, rq, rk, temp, attnw);
    k_wfuse<<<dim3(192, 4), 192, 0, stream>>>(wattn, attnw, wf_b);

    // 5. d_out = x + (Wattn @ BDattn) @ V
    k_transT<192><<<dim3(256, 1, BB), blk, 0, stream>>>(kvb, vT, 384, 192, 192, 0);
    k_gemmU<0, 1, 192><<<dim3(256, 1, BB), blk, 0, stream>>>(vT, wf_b, out, x, 36864);

    // 6. xn2T = LN2(d_out)
    k_ln2<0><<<1024, blk, 0, stream>>>(out, ln2g, ln2b, nullptr, xnT);

    // 7. GDFN
    for (int ck = 0; ck < 2; ++ck) {
        int validc = (ck == 0) ? 256 : 254;
        k_gemmT<1, 0, 192, 192, 128><<<dim3(128, 4, BB), blk, 0, stream>>>(xnT, wfi_b + (size_t)(ck * 512) * 192,
                                                                           y12, nullptr, 512, 0);
        k_dw8gate<<<dim3(8, 256, BB), blk, 0, stream>>>(y12, wffnd + (size_t)(ck * 256) * 9,
                                                        wffnd + (size_t)(510 + ck * 256) * 9, gg, validc);
        k_transT<256><<<dim3(256, 1, BB), blk, 0, stream>>>(gg, gTb, 256, 0, 512, ck * 256);
    }
    k_gemmU<0, 1, 512><<<dim3(256, 1, BB), blk, 0, stream>>>(gTb, wfo_b, out, out, 0);
}